// Round 1
// baseline (5242.045 us; speedup 1.0000x reference)
//
#include <hip/hip_runtime.h>
#include <math.h>

__device__ __forceinline__ float lrelu_f(float x) { return x >= 0.f ? x : 0.01f * x; }

// ---------------------------------------------------------------------------
// Generic 3x3 conv, optional two-pointer channel concat input (inA||inB).
// One block: fixed (b, co), 256 threads over output pixels. Weights in LDS.
// ---------------------------------------------------------------------------
template<int STRIDE, bool LRELU>
__global__ void conv3x3_kernel(const float* __restrict__ inA, const float* __restrict__ inB,
    int CinA, int Cin, int Hin, int Win,
    const float* __restrict__ w, const float* __restrict__ bias,
    int Cout, int Hout, int Wout, int tilesPerMap,
    float* __restrict__ out)
{
    extern __shared__ float sw[]; // Cin*9
    int tile = blockIdx.x % tilesPerMap;
    int co   = (blockIdx.x / tilesPerMap) % Cout;
    int b    = blockIdx.x / (tilesPerMap * Cout);
    int tid  = threadIdx.x;
    for (int i = tid; i < Cin * 9; i += blockDim.x) sw[i] = w[(size_t)co * Cin * 9 + i];
    __syncthreads();
    int p = tile * 256 + tid;
    if (p >= Hout * Wout) return;
    int oy = p / Wout, ox = p % Wout;
    int iy0 = oy * STRIDE - 1, ix0 = ox * STRIDE - 1;
    float acc = bias[co];
    int CinB = Cin - CinA;
    for (int ci = 0; ci < Cin; ++ci) {
        const float* src = (ci < CinA)
            ? inA + ((size_t)(b * CinA + ci)) * Hin * Win
            : inB + ((size_t)(b * CinB + (ci - CinA))) * Hin * Win;
        const float* wr = &sw[ci * 9];
        #pragma unroll
        for (int ky = 0; ky < 3; ++ky) {
            int iy = iy0 + ky;
            if (iy < 0 || iy >= Hin) continue;
            const float* row = src + (size_t)iy * Win;
            #pragma unroll
            for (int kx = 0; kx < 3; ++kx) {
                int ix = ix0 + kx;
                if (ix < 0 || ix >= Win) continue;
                acc = fmaf(wr[ky * 3 + kx], row[ix], acc);
            }
        }
    }
    if (LRELU) acc = lrelu_f(acc);
    out[((size_t)(b * Cout + co)) * Hout * Wout + p] = acc;
}

// ---------------------------------------------------------------------------
// Fused 1x1 convs producing th/ph/g (each 64->32) from e (B,64,N).
// One thread per (b,n).
// ---------------------------------------------------------------------------
__global__ __launch_bounds__(256) void conv1x1x3_kernel(const float* __restrict__ e, int N,
    const float* __restrict__ tw, const float* __restrict__ tb,
    const float* __restrict__ pw, const float* __restrict__ pb,
    const float* __restrict__ gw, const float* __restrict__ gb,
    float* __restrict__ th, float* __restrict__ ph, float* __restrict__ g)
{
    __shared__ float sw[3 * 32 * 64];
    __shared__ float sb[96];
    int tid = threadIdx.x;
    for (int i = tid; i < 2048; i += 256) { sw[i] = tw[i]; sw[2048 + i] = pw[i]; sw[4096 + i] = gw[i]; }
    if (tid < 32) { sb[tid] = tb[tid]; sb[32 + tid] = pb[tid]; sb[64 + tid] = gb[tid]; }
    __syncthreads();
    int idx = blockIdx.x * 256 + tid;
    int n = idx % N, b = idx / N;
    float ein[64];
    const float* ep = e + (size_t)b * 64 * N + n;
    #pragma unroll
    for (int ci = 0; ci < 64; ++ci) ein[ci] = ep[(size_t)ci * N];
    float* outs[3] = { th, ph, g };
    #pragma unroll
    for (int j = 0; j < 3; ++j) {
        float* op = outs[j] + (size_t)b * 32 * N + n;
        for (int cc = 0; cc < 32; ++cc) {
            float acc = sb[j * 32 + cc];
            const float* wr = &sw[j * 2048 + cc * 64];
            #pragma unroll
            for (int ci = 0; ci < 64; ++ci) acc = fmaf(wr[ci], ein[ci], acc);
            op[(size_t)cc * N] = acc;
        }
    }
}

// ---------------------------------------------------------------------------
// Streaming attention: y[b,c,n] = sum_m softmax_m(th[:,n]·ph[:,m]) * g[c,m].
// One wave per row n. Two-pass (max, then exp/accumulate). No attn matrix.
// ---------------------------------------------------------------------------
__global__ __launch_bounds__(256) void attn_kernel(const float* __restrict__ th,
    const float* __restrict__ ph, const float* __restrict__ g,
    float* __restrict__ y, int N)
{
    int wave = blockIdx.x * 4 + (threadIdx.x >> 6);
    int lane = threadIdx.x & 63;
    int n = wave % N, b = wave / N;
    const float* thp = th + (size_t)b * 32 * N;
    const float* php = ph + (size_t)b * 32 * N;
    const float* gp  = g  + (size_t)b * 32 * N;
    float tn[32];
    #pragma unroll
    for (int c = 0; c < 32; ++c) tn[c] = thp[(size_t)c * N + n];
    float mx = -1e30f;
    for (int m = lane; m < N; m += 64) {
        float s = 0.f;
        #pragma unroll
        for (int c = 0; c < 32; ++c) s = fmaf(tn[c], php[(size_t)c * N + m], s);
        mx = fmaxf(mx, s);
    }
    #pragma unroll
    for (int off = 32; off >= 1; off >>= 1) mx = fmaxf(mx, __shfl_xor(mx, off));
    float sum = 0.f;
    float ya[32];
    #pragma unroll
    for (int c = 0; c < 32; ++c) ya[c] = 0.f;
    for (int m = lane; m < N; m += 64) {
        float s = 0.f;
        #pragma unroll
        for (int c = 0; c < 32; ++c) s = fmaf(tn[c], php[(size_t)c * N + m], s);
        float pv = __expf(s - mx);
        sum += pv;
        #pragma unroll
        for (int c = 0; c < 32; ++c) ya[c] = fmaf(pv, gp[(size_t)c * N + m], ya[c]);
    }
    #pragma unroll
    for (int off = 32; off >= 1; off >>= 1) sum += __shfl_xor(sum, off);
    #pragma unroll
    for (int c = 0; c < 32; ++c) {
        #pragma unroll
        for (int off = 32; off >= 1; off >>= 1) ya[c] += __shfl_xor(ya[c], off);
    }
    if (lane == 0) {
        float inv = 1.f / sum;
        float* yp = y + (size_t)b * 32 * N + n;
        #pragma unroll
        for (int c = 0; c < 32; ++c) yp[(size_t)c * N] = ya[c] * inv;
    }
}

// ---------------------------------------------------------------------------
// m = 2*e + conv1x1(y; ww,wb) [+ u]. One thread per (b,n), all 64 co.
// ---------------------------------------------------------------------------
__global__ __launch_bounds__(256) void nl_merge_kernel(const float* __restrict__ e,
    const float* __restrict__ yin, const float* __restrict__ u,
    const float* __restrict__ ww, const float* __restrict__ wb,
    float* __restrict__ out, int N)
{
    __shared__ float sw[64 * 32];
    __shared__ float sb[64];
    int tid = threadIdx.x;
    for (int i = tid; i < 2048; i += 256) sw[i] = ww[i];
    if (tid < 64) sb[tid] = wb[tid];
    __syncthreads();
    int idx = blockIdx.x * 256 + tid;
    int n = idx % N, b = idx / N;
    float yv[32];
    #pragma unroll
    for (int c = 0; c < 32; ++c) yv[c] = yin[(size_t)b * 32 * N + (size_t)c * N + n];
    for (int co = 0; co < 64; ++co) {
        float acc = sb[co];
        #pragma unroll
        for (int c = 0; c < 32; ++c) acc = fmaf(sw[co * 32 + c], yv[c], acc);
        size_t o = (size_t)b * 64 * N + (size_t)co * N + n;
        acc += 2.f * e[o];
        if (u) acc += u[o];
        out[o] = acc;
    }
}

// ---------------------------------------------------------------------------
// Transposed conv 3x3 stride 2, pad(1,2): out[oy,ox] gets taps where
// t=oy-1+ky is even and t/2 in range. Weight wt[o,i,ky,kx]=w[i,o,2-ky,2-kx].
// ---------------------------------------------------------------------------
__global__ __launch_bounds__(256) void deconv_kernel(const float* __restrict__ in,
    const float* __restrict__ w, const float* __restrict__ bias, float* __restrict__ out,
    int Cin, int Cout, int Hin, int Win, int tilesPerMap)
{
    __shared__ float sw[64 * 9];
    int tile = blockIdx.x % tilesPerMap;
    int o    = (blockIdx.x / tilesPerMap) % Cout;
    int b    = blockIdx.x / (tilesPerMap * Cout);
    int tid  = threadIdx.x;
    for (int idx = tid; idx < Cin * 9; idx += blockDim.x) {
        int i = idx / 9, r = idx % 9, ky = r / 3, kx = r % 3;
        sw[idx] = w[((size_t)i * Cout + o) * 9 + (2 - ky) * 3 + (2 - kx)];
    }
    __syncthreads();
    int Hout = Hin * 2, Wout = Win * 2;
    int p = tile * 256 + tid;
    if (p >= Hout * Wout) return;
    int oy = p / Wout, ox = p % Wout;
    bool vy[3], vx[3];
    int iy[3], ix[3];
    #pragma unroll
    for (int ky = 0; ky < 3; ++ky) {
        int t = oy - 1 + ky;
        vy[ky] = (t >= 0) && ((t & 1) == 0) && ((t >> 1) < Hin);
        iy[ky] = t >> 1;
    }
    #pragma unroll
    for (int kx = 0; kx < 3; ++kx) {
        int t = ox - 1 + kx;
        vx[kx] = (t >= 0) && ((t & 1) == 0) && ((t >> 1) < Win);
        ix[kx] = t >> 1;
    }
    float acc = bias[o];
    for (int i = 0; i < Cin; ++i) {
        const float* src = in + ((size_t)(b * Cin + i)) * Hin * Win;
        #pragma unroll
        for (int ky = 0; ky < 3; ++ky) {
            if (!vy[ky]) continue;
            #pragma unroll
            for (int kx = 0; kx < 3; ++kx) {
                if (!vx[kx]) continue;
                acc = fmaf(sw[i * 9 + ky * 3 + kx], src[(size_t)iy[ky] * Win + ix[kx]], acc);
            }
        }
    }
    out[((size_t)(b * Cout + o)) * Hout * Wout + p] = lrelu_f(acc);
}

// ---------------------------------------------------------------------------
// Deformable conv 3x3 as fused implicit GEMM.
// Block: one (b, 64-pixel tile). Stage sampled V (16-ch chunks = 144 rows) in
// LDS, then register-tiled GEMM: each thread 8co x 4px.
// ---------------------------------------------------------------------------
__global__ __launch_bounds__(256) void deform_kernel(const float* __restrict__ x,
    const float* __restrict__ est, const float* __restrict__ w,
    const float* __restrict__ bias, float* __restrict__ out)
{
    const int H = 128, W = 128, HW = H * W, C = 128;
    __shared__ float sV[144 * 64];
    __shared__ float spy[576], spx[576], smk[576];
    int tile = blockIdx.x % (HW / 64);
    int b    = blockIdx.x / (HW / 64);
    int p0   = tile * 64;
    int tid  = threadIdx.x;
    const float* eb = est + (size_t)b * 27 * HW;
    for (int i = tid; i < 576; i += 256) {
        int k = i >> 6, j = i & 63;
        int p = p0 + j;
        int yy = p / W, xx = p % W;
        float oy = eb[(size_t)(9 + 2 * k) * HW + p];
        float ox = eb[(size_t)(10 + 2 * k) * HW + p];
        float mv = eb[(size_t)k * HW + p];
        smk[i] = 1.f / (1.f + __expf(-mv));
        spy[i] = (float)(yy + (k / 3) - 1) + oy;
        spx[i] = (float)(xx + (k % 3) - 1) + ox;
    }
    int tpx = tid & 15, tco = tid >> 4;
    int px0 = tpx * 4, co0 = tco * 8;
    float acc[8][4];
    #pragma unroll
    for (int u = 0; u < 8; ++u)
        #pragma unroll
        for (int v = 0; v < 4; ++v) acc[u][v] = 0.f;

    for (int cc = 0; cc < C; cc += 16) {
        __syncthreads();
        for (int vi = tid; vi < 144 * 64; vi += 256) {
            int j  = vi & 63;
            int rk = vi >> 6;      // 0..143
            int k  = rk % 9, cl = rk / 9;
            int c  = cc + cl;
            int si = k * 64 + j;
            float py = spy[si], px = spx[si];
            float fy0 = floorf(py), fx0 = floorf(px);
            float wy = py - fy0, wx = px - fx0;
            int y0 = (int)fy0, x0 = (int)fx0;
            const float* src = x + ((size_t)(b * C + c)) * HW;
            float v = 0.f;
            float w00 = (1.f - wy) * (1.f - wx), w01 = (1.f - wy) * wx;
            float w10 = wy * (1.f - wx),         w11 = wy * wx;
            bool yv0 = (y0 >= 0) && (y0 < H), yv1 = (y0 + 1 >= 0) && (y0 + 1 < H);
            bool xv0 = (x0 >= 0) && (x0 < W), xv1 = (x0 + 1 >= 0) && (x0 + 1 < W);
            if (yv0 && xv0) v = fmaf(w00, src[(size_t)y0 * W + x0], v);
            if (yv0 && xv1) v = fmaf(w01, src[(size_t)y0 * W + x0 + 1], v);
            if (yv1 && xv0) v = fmaf(w10, src[(size_t)(y0 + 1) * W + x0], v);
            if (yv1 && xv1) v = fmaf(w11, src[(size_t)(y0 + 1) * W + x0 + 1], v);
            sV[vi] = v * smk[si];
        }
        __syncthreads();
        const float* wb0 = w + (size_t)cc * 9;
        for (int r = 0; r < 144; ++r) {
            float vv[4];
            #pragma unroll
            for (int v2 = 0; v2 < 4; ++v2) vv[v2] = sV[r * 64 + px0 + v2];
            #pragma unroll
            for (int u = 0; u < 8; ++u) {
                float wv = wb0[(size_t)(co0 + u) * 1152 + r];
                #pragma unroll
                for (int v2 = 0; v2 < 4; ++v2) acc[u][v2] = fmaf(wv, vv[v2], acc[u][v2]);
            }
        }
    }
    #pragma unroll
    for (int u = 0; u < 8; ++u) {
        float bb = bias[co0 + u];
        #pragma unroll
        for (int v2 = 0; v2 < 4; ++v2)
            out[((size_t)(b * C + co0 + u)) * HW + p0 + px0 + v2] = acc[u][v2] + bb;
    }
}

extern "C" void kernel_launch(void* const* d_in, const int* in_sizes, int n_in,
                              void* d_out, int out_size, void* d_ws, size_t ws_size,
                              hipStream_t stream)
{
    const float* x_all     = (const float*)d_in[0];
    const float* ms_fine   = (const float*)d_in[1];
    const float* ms_coarse = (const float*)d_in[2];
    const float* enc_w0 = (const float*)d_in[3];
    const float* enc_b0 = (const float*)d_in[4];
    const float* enc_w1 = (const float*)d_in[5];
    const float* enc_b1 = (const float*)d_in[6];
    const float* nl_tw[2] = { (const float*)d_in[7],  (const float*)d_in[15] };
    const float* nl_tb[2] = { (const float*)d_in[8],  (const float*)d_in[16] };
    const float* nl_pw[2] = { (const float*)d_in[9],  (const float*)d_in[17] };
    const float* nl_pb[2] = { (const float*)d_in[10], (const float*)d_in[18] };
    const float* nl_gw[2] = { (const float*)d_in[11], (const float*)d_in[19] };
    const float* nl_gb[2] = { (const float*)d_in[12], (const float*)d_in[20] };
    const float* nl_ww[2] = { (const float*)d_in[13], (const float*)d_in[21] };
    const float* nl_wb[2] = { (const float*)d_in[14], (const float*)d_in[22] };
    const float* dec_w0 = (const float*)d_in[23];
    const float* dec_b0 = (const float*)d_in[24];
    const float* dec_w1 = (const float*)d_in[25];
    const float* dec_b1 = (const float*)d_in[26];
    const float* off_w  = (const float*)d_in[27];
    const float* off_b  = (const float*)d_in[28];
    const float* dcn_w  = (const float*)d_in[29];
    const float* dcn_b  = (const float*)d_in[30];

    float* ws  = (float*)d_ws;
    float* e0  = ws;               // 131072
    float* th0 = e0 + 131072;      // 65536
    float* ph0 = th0 + 65536;
    float* g0  = ph0 + 65536;
    float* y0  = g0 + 65536;
    float* m0  = y0 + 65536;       // 131072
    float* u0  = m0 + 131072;      // 524288
    float* e1  = u0 + 524288;      // 524288
    float* th1 = e1 + 524288;      // 262144
    float* ph1 = th1 + 262144;
    float* g1  = ph1 + 262144;
    float* y1  = g1 + 262144;
    float* m1  = y1 + 262144;      // 524288
    float* mot = m1 + 524288;      // 2097152
    float* est = mot + 2097152;    // 884736  -> total ~6.13M floats (~24.5 MB)

    float* out = (float*)d_out;
    const size_t frame = (size_t)2 * 128 * 128 * 128; // B*C*H*W

    // aligned[0] = x_all[0]
    hipMemcpyAsync(out, x_all, frame * sizeof(float), hipMemcpyDeviceToDevice, stream);

    for (int s = 1; s < 3; ++s) {
        const float* pc = ms_coarse + (size_t)s * 2 * 256 * 64 * 64;
        const float* cc = ms_coarse;
        const float* pf = ms_fine + (size_t)s * frame;
        const float* cf = ms_fine;

        // e0 = lrelu(conv3x3 s2 (pc||cc; 512->64)) : (2,64,32,32)
        conv3x3_kernel<2, true><<<2 * 64 * 4, 256, 512 * 9 * 4, stream>>>(
            pc, cc, 256, 512, 64, 64, enc_w0, enc_b0, 64, 32, 32, 4, e0);
        // th/ph/g (N=1024)
        conv1x1x3_kernel<<<8, 256, 0, stream>>>(e0, 1024,
            nl_tw[0], nl_tb[0], nl_pw[0], nl_pb[0], nl_gw[0], nl_gb[0], th0, ph0, g0);
        attn_kernel<<<512, 256, 0, stream>>>(th0, ph0, g0, y0, 1024);
        // m0 = 2*e0 + conv1x1(y0)
        nl_merge_kernel<<<8, 256, 0, stream>>>(e0, y0, nullptr, nl_ww[0], nl_wb[0], m0, 1024);
        // u0 = lrelu(deconv(m0)) : (2,64,64,64)
        deconv_kernel<<<2 * 64 * 16, 256, 0, stream>>>(m0, dec_w0, dec_b0, u0, 64, 64, 32, 32, 16);

        // e1 = lrelu(conv3x3 s2 (pf||cf; 256->64)) : (2,64,64,64)
        conv3x3_kernel<2, true><<<2 * 64 * 16, 256, 256 * 9 * 4, stream>>>(
            pf, cf, 128, 256, 128, 128, enc_w1, enc_b1, 64, 64, 64, 16, e1);
        conv1x1x3_kernel<<<32, 256, 0, stream>>>(e1, 4096,
            nl_tw[1], nl_tb[1], nl_pw[1], nl_pb[1], nl_gw[1], nl_gb[1], th1, ph1, g1);
        attn_kernel<<<2048, 256, 0, stream>>>(th1, ph1, g1, y1, 4096);
        // m1 = 2*e1 + conv1x1(y1) + u0
        nl_merge_kernel<<<32, 256, 0, stream>>>(e1, y1, u0, nl_ww[1], nl_wb[1], m1, 4096);
        // mot = lrelu(deconv(m1)) : (2,64,128,128)
        deconv_kernel<<<2 * 64 * 64, 256, 0, stream>>>(m1, dec_w1, dec_b1, mot, 64, 64, 64, 64, 64);

        // est = conv3x3 s1 (mot; 64->27) : (2,27,128,128)
        conv3x3_kernel<1, false><<<2 * 27 * 64, 256, 64 * 9 * 4, stream>>>(
            mot, nullptr, 64, 64, 128, 128, off_w, off_b, 27, 128, 128, 64, est);

        // aligned[s] = deform_conv(x_all[s], offset, mask)
        deform_kernel<<<2 * 256, 256, 0, stream>>>(
            x_all + (size_t)s * frame, est, dcn_w, dcn_b, out + (size_t)s * frame);
    }
}

// Round 2
// 2836.254 us; speedup vs baseline: 1.8482x; 1.8482x over previous
//
#include <hip/hip_runtime.h>
#include <math.h>

__device__ __forceinline__ float lrelu_f(float x) { return x >= 0.f ? x : 0.01f * x; }

// ===========================================================================
// Register-tiled implicit-GEMM 3x3 conv.
// Block: 256 threads = 16 co-groups x 16 px-threads. Thread: TCO co x 4 px.
// Grid: b * tilesPerMap * ksplit. Each block covers Cspan input channels and
// writes raw partial sums; reduce_bias_act sums ksplit partials + bias + act.
// Input is (optionally) a channel-concat of two tensors (inA || inB).
// MASK=false for pre-padded inputs (deconv path): no bounds checks at all.
// ===========================================================================
#define CONV_CB 8

template<int STRIDE, int PAD, int TCO, bool MASK>
__global__ __launch_bounds__(256) void conv3x3_gemm(
    const float* __restrict__ inA, const float* __restrict__ inB, int CinA,
    int Hin, int Win, int Cin, int Cspan,
    const float* __restrict__ w, int Cout,
    int Hout, int Wout, int tilesPerMap, int ksplit,
    float* __restrict__ part)
{
    constexpr int CO = TCO * 16;
    __shared__ float sw[CONV_CB * 9 * CO];
    int tile = blockIdx.x % tilesPerMap;
    int ks   = (blockIdx.x / tilesPerMap) % ksplit;
    int b    = blockIdx.x / (tilesPerMap * ksplit);
    int tid  = threadIdx.x;
    int tpx  = tid & 15, tco = tid >> 4;
    int co0  = tco * TCO;
    int Npx  = Hout * Wout;

    int   off[4][9];
    float m[4][9];
    #pragma unroll
    for (int v = 0; v < 4; ++v) {
        int p = tile * 64 + tpx + v * 16;
        int oy = p / Wout, ox = p % Wout;
        #pragma unroll
        for (int ky = 0; ky < 3; ++ky) {
            int iy = oy * STRIDE - PAD + ky;
            bool vy = (iy >= 0) && (iy < Hin);
            int iyc = min(max(iy, 0), Hin - 1);
            #pragma unroll
            for (int kx = 0; kx < 3; ++kx) {
                int ix = ox * STRIDE - PAD + kx;
                bool vx = (ix >= 0) && (ix < Win);
                int ixc = min(max(ix, 0), Win - 1);
                off[v][ky * 3 + kx] = (iyc * Win + ixc) * 4;
                if (MASK) m[v][ky * 3 + kx] = (vy && vx) ? 1.f : 0.f;
            }
        }
    }

    float acc[TCO][4];
    #pragma unroll
    for (int u = 0; u < TCO; ++u)
        #pragma unroll
        for (int v = 0; v < 4; ++v) acc[u][v] = 0.f;

    int c0 = ks * Cspan;
    int CinB = Cin - CinA;
    for (int cc = 0; cc < Cspan; cc += CONV_CB) {
        __syncthreads();
        for (int i = tid; i < CONV_CB * 9 * CO; i += 256) {
            int co = i / (CONV_CB * 9);
            int r  = i % (CONV_CB * 9);
            int ci = r / 9, tap = r % 9;
            float wv = 0.f;
            if (co < Cout) wv = w[((size_t)co * Cin + (c0 + cc + ci)) * 9 + tap];
            sw[(ci * 9 + tap) * CO + co] = wv;
        }
        __syncthreads();
        #pragma unroll 1
        for (int ci = 0; ci < CONV_CB; ++ci) {
            int c = c0 + cc + ci;
            const float* src;
            if (c < CinA) src = inA + ((size_t)b * CinA + c) * (size_t)(Hin * Win);
            else          src = inB + ((size_t)b * CinB + (c - CinA)) * (size_t)(Hin * Win);
            const float* wrow = &sw[ci * 9 * CO];
            #pragma unroll
            for (int t = 0; t < 9; ++t) {
                float vals[4];
                #pragma unroll
                for (int v = 0; v < 4; ++v) {
                    float x = *(const float*)((const char*)src + off[v][t]);
                    vals[v] = MASK ? x * m[v][t] : x;
                }
                #pragma unroll
                for (int u = 0; u < TCO; ++u) {
                    float wv = wrow[t * CO + co0 + u];
                    #pragma unroll
                    for (int v = 0; v < 4; ++v)
                        acc[u][v] = fmaf(wv, vals[v], acc[u][v]);
                }
            }
        }
    }

    #pragma unroll
    for (int u = 0; u < TCO; ++u) {
        #pragma unroll
        for (int v = 0; v < 4; ++v) {
            int p = tile * 64 + tpx + v * 16;
            part[(((size_t)ks * 2 + b) * CO + co0 + u) * (size_t)Npx + p] = acc[u][v];
        }
    }
}

// out[b][co][p] = act(bias[co] + sum_ks part[ks][b][co][p])
__global__ __launch_bounds__(256) void reduce_bias_act(const float* __restrict__ part,
    const float* __restrict__ bias, float* __restrict__ out,
    int CO, int Cout, int Npx, int ksplit, int act)
{
    int idx = blockIdx.x * 256 + threadIdx.x;
    int total = 2 * Cout * Npx;
    if (idx >= total) return;
    int p  = idx % Npx;
    int co = (idx / Npx) % Cout;
    int b  = idx / (Npx * Cout);
    float s = bias[co];
    for (int ks = 0; ks < ksplit; ++ks)
        s += part[(((size_t)ks * 2 + b) * CO + co) * (size_t)Npx + p];
    if (act) s = lrelu_f(s);
    out[((size_t)b * Cout + co) * (size_t)Npx + p] = s;
}

// P[c][u][v] (Hp=2Hin+2, Wp=2Win+2): zero except odd (u,v):
// P = in[(u-1)/2][(v-1)/2] when in range. Turns deconv into stride-1 conv.
__global__ __launch_bounds__(256) void dilate_kernel(const float* __restrict__ in,
    float* __restrict__ P, int Hin, int Win, int C2, int total)
{
    int idx = blockIdx.x * 256 + threadIdx.x;
    if (idx >= total) return;
    int Wp = 2 * Win + 2, Hp = 2 * Hin + 2;
    int v = idx % Wp, u = (idx / Wp) % Hp;
    int c = idx / (Wp * Hp);
    float val = 0.f;
    if ((u & 1) && (v & 1)) {
        int r = (u - 1) >> 1, q = (v - 1) >> 1;
        if (r < Hin && q < Win) val = in[((size_t)c * Hin + r) * Win + q];
    }
    P[idx] = val;
}

// wt[o][i][ky][kx] = w[i][o][2-ky][2-kx]
__global__ __launch_bounds__(256) void deconv_w_kernel(const float* __restrict__ w,
    float* __restrict__ wt, int C)
{
    int idx = blockIdx.x * 256 + threadIdx.x;
    if (idx >= C * C * 9) return;
    int tap = idx % 9;
    int i = (idx / 9) % C;
    int o = idx / (9 * C);
    int ky = tap / 3, kx = tap % 3;
    wt[idx] = w[(((size_t)i * C + o) * 9) + (2 - ky) * 3 + (2 - kx)];
}

// ---------------------------------------------------------------------------
// Fused 1x1 convs producing th/ph/g (each 64->32) from e (B,64,N).
// ---------------------------------------------------------------------------
__global__ __launch_bounds__(256) void conv1x1x3_kernel(const float* __restrict__ e, int N,
    const float* __restrict__ tw, const float* __restrict__ tb,
    const float* __restrict__ pw, const float* __restrict__ pb,
    const float* __restrict__ gw, const float* __restrict__ gb,
    float* __restrict__ th, float* __restrict__ ph, float* __restrict__ g)
{
    __shared__ float sw[3 * 32 * 64];
    __shared__ float sb[96];
    int tid = threadIdx.x;
    for (int i = tid; i < 2048; i += 256) { sw[i] = tw[i]; sw[2048 + i] = pw[i]; sw[4096 + i] = gw[i]; }
    if (tid < 32) { sb[tid] = tb[tid]; sb[32 + tid] = pb[tid]; sb[64 + tid] = gb[tid]; }
    __syncthreads();
    int idx = blockIdx.x * 256 + tid;
    int n = idx % N, b = idx / N;
    float ein[64];
    const float* ep = e + (size_t)b * 64 * N + n;
    #pragma unroll
    for (int ci = 0; ci < 64; ++ci) ein[ci] = ep[(size_t)ci * N];
    float* outs[3] = { th, ph, g };
    #pragma unroll
    for (int j = 0; j < 3; ++j) {
        float* op = outs[j] + (size_t)b * 32 * N + n;
        for (int cc = 0; cc < 32; ++cc) {
            float acc = sb[j * 32 + cc];
            const float* wr = &sw[j * 2048 + cc * 64];
            #pragma unroll
            for (int ci = 0; ci < 64; ++ci) acc = fmaf(wr[ci], ein[ci], acc);
            op[(size_t)cc * N] = acc;
        }
    }
}

// ---------------------------------------------------------------------------
// Streaming attention: y[b,c,n] = sum_m softmax_m(th[:,n]·ph[:,m]) * g[c,m].
// ---------------------------------------------------------------------------
__global__ __launch_bounds__(256) void attn_kernel(const float* __restrict__ th,
    const float* __restrict__ ph, const float* __restrict__ g,
    float* __restrict__ y, int N)
{
    int wave = blockIdx.x * 4 + (threadIdx.x >> 6);
    int lane = threadIdx.x & 63;
    int n = wave % N, b = wave / N;
    const float* thp = th + (size_t)b * 32 * N;
    const float* php = ph + (size_t)b * 32 * N;
    const float* gp  = g  + (size_t)b * 32 * N;
    float tn[32];
    #pragma unroll
    for (int c = 0; c < 32; ++c) tn[c] = thp[(size_t)c * N + n];
    float mx = -1e30f;
    for (int m = lane; m < N; m += 64) {
        float s = 0.f;
        #pragma unroll
        for (int c = 0; c < 32; ++c) s = fmaf(tn[c], php[(size_t)c * N + m], s);
        mx = fmaxf(mx, s);
    }
    #pragma unroll
    for (int off = 32; off >= 1; off >>= 1) mx = fmaxf(mx, __shfl_xor(mx, off));
    float sum = 0.f;
    float ya[32];
    #pragma unroll
    for (int c = 0; c < 32; ++c) ya[c] = 0.f;
    for (int m = lane; m < N; m += 64) {
        float s = 0.f;
        #pragma unroll
        for (int c = 0; c < 32; ++c) s = fmaf(tn[c], php[(size_t)c * N + m], s);
        float pv = __expf(s - mx);
        sum += pv;
        #pragma unroll
        for (int c = 0; c < 32; ++c) ya[c] = fmaf(pv, gp[(size_t)c * N + m], ya[c]);
    }
    #pragma unroll
    for (int off = 32; off >= 1; off >>= 1) sum += __shfl_xor(sum, off);
    #pragma unroll
    for (int c = 0; c < 32; ++c) {
        #pragma unroll
        for (int off = 32; off >= 1; off >>= 1) ya[c] += __shfl_xor(ya[c], off);
    }
    if (lane == 0) {
        float inv = 1.f / sum;
        float* yp = y + (size_t)b * 32 * N + n;
        #pragma unroll
        for (int c = 0; c < 32; ++c) yp[(size_t)c * N] = ya[c] * inv;
    }
}

// ---------------------------------------------------------------------------
// m = 2*e + conv1x1(y; ww,wb) [+ u].
// ---------------------------------------------------------------------------
__global__ __launch_bounds__(256) void nl_merge_kernel(const float* __restrict__ e,
    const float* __restrict__ yin, const float* __restrict__ u,
    const float* __restrict__ ww, const float* __restrict__ wb,
    float* __restrict__ out, int N)
{
    __shared__ float sw[64 * 32];
    __shared__ float sb[64];
    int tid = threadIdx.x;
    for (int i = tid; i < 2048; i += 256) sw[i] = ww[i];
    if (tid < 64) sb[tid] = wb[tid];
    __syncthreads();
    int idx = blockIdx.x * 256 + tid;
    int n = idx % N, b = idx / N;
    float yv[32];
    #pragma unroll
    for (int c = 0; c < 32; ++c) yv[c] = yin[(size_t)b * 32 * N + (size_t)c * N + n];
    for (int co = 0; co < 64; ++co) {
        float acc = sb[co];
        #pragma unroll
        for (int c = 0; c < 32; ++c) acc = fmaf(sw[co * 32 + c], yv[c], acc);
        size_t o = (size_t)b * 64 * N + (size_t)co * N + n;
        acc += 2.f * e[o];
        if (u) acc += u[o];
        out[o] = acc;
    }
}

// ---------------------------------------------------------------------------
// Deformable conv 3x3 as fused implicit GEMM (unchanged from round 0).
// ---------------------------------------------------------------------------
__global__ __launch_bounds__(256) void deform_kernel(const float* __restrict__ x,
    const float* __restrict__ est, const float* __restrict__ w,
    const float* __restrict__ bias, float* __restrict__ out)
{
    const int H = 128, W = 128, HW = H * W, C = 128;
    __shared__ float sV[144 * 64];
    __shared__ float spy[576], spx[576], smk[576];
    int tile = blockIdx.x % (HW / 64);
    int b    = blockIdx.x / (HW / 64);
    int p0   = tile * 64;
    int tid  = threadIdx.x;
    const float* eb = est + (size_t)b * 27 * HW;
    for (int i = tid; i < 576; i += 256) {
        int k = i >> 6, j = i & 63;
        int p = p0 + j;
        int yy = p / W, xx = p % W;
        float oy = eb[(size_t)(9 + 2 * k) * HW + p];
        float ox = eb[(size_t)(10 + 2 * k) * HW + p];
        float mv = eb[(size_t)k * HW + p];
        smk[i] = 1.f / (1.f + __expf(-mv));
        spy[i] = (float)(yy + (k / 3) - 1) + oy;
        spx[i] = (float)(xx + (k % 3) - 1) + ox;
    }
    int tpx = tid & 15, tco = tid >> 4;
    int px0 = tpx * 4, co0 = tco * 8;
    float acc[8][4];
    #pragma unroll
    for (int u = 0; u < 8; ++u)
        #pragma unroll
        for (int v = 0; v < 4; ++v) acc[u][v] = 0.f;

    for (int cc = 0; cc < C; cc += 16) {
        __syncthreads();
        for (int vi = tid; vi < 144 * 64; vi += 256) {
            int j  = vi & 63;
            int rk = vi >> 6;
            int k  = rk % 9, cl = rk / 9;
            int c  = cc + cl;
            int si = k * 64 + j;
            float py = spy[si], px = spx[si];
            float fy0 = floorf(py), fx0 = floorf(px);
            float wy = py - fy0, wx = px - fx0;
            int y0 = (int)fy0, x0 = (int)fx0;
            const float* src = x + ((size_t)(b * C + c)) * HW;
            float v = 0.f;
            float w00 = (1.f - wy) * (1.f - wx), w01 = (1.f - wy) * wx;
            float w10 = wy * (1.f - wx),         w11 = wy * wx;
            bool yv0 = (y0 >= 0) && (y0 < H), yv1 = (y0 + 1 >= 0) && (y0 + 1 < H);
            bool xv0 = (x0 >= 0) && (x0 < W), xv1 = (x0 + 1 >= 0) && (x0 + 1 < W);
            if (yv0 && xv0) v = fmaf(w00, src[(size_t)y0 * W + x0], v);
            if (yv0 && xv1) v = fmaf(w01, src[(size_t)y0 * W + x0 + 1], v);
            if (yv1 && xv0) v = fmaf(w10, src[(size_t)(y0 + 1) * W + x0], v);
            if (yv1 && xv1) v = fmaf(w11, src[(size_t)(y0 + 1) * W + x0 + 1], v);
            sV[vi] = v * smk[si];
        }
        __syncthreads();
        const float* wb0 = w + (size_t)cc * 9;
        for (int r = 0; r < 144; ++r) {
            float vv[4];
            #pragma unroll
            for (int v2 = 0; v2 < 4; ++v2) vv[v2] = sV[r * 64 + px0 + v2];
            #pragma unroll
            for (int u = 0; u < 8; ++u) {
                float wv = wb0[(size_t)(co0 + u) * 1152 + r];
                #pragma unroll
                for (int v2 = 0; v2 < 4; ++v2) acc[u][v2] = fmaf(wv, vv[v2], acc[u][v2]);
            }
        }
    }
    #pragma unroll
    for (int u = 0; u < 8; ++u) {
        float bb = bias[co0 + u];
        #pragma unroll
        for (int v2 = 0; v2 < 4; ++v2)
            out[((size_t)(b * C + co0 + u)) * HW + p0 + px0 + v2] = acc[u][v2] + bb;
    }
}

extern "C" void kernel_launch(void* const* d_in, const int* in_sizes, int n_in,
                              void* d_out, int out_size, void* d_ws, size_t ws_size,
                              hipStream_t stream)
{
    const float* x_all     = (const float*)d_in[0];
    const float* ms_fine   = (const float*)d_in[1];
    const float* ms_coarse = (const float*)d_in[2];
    const float* enc_w0 = (const float*)d_in[3];
    const float* enc_b0 = (const float*)d_in[4];
    const float* enc_w1 = (const float*)d_in[5];
    const float* enc_b1 = (const float*)d_in[6];
    const float* nl_tw[2] = { (const float*)d_in[7],  (const float*)d_in[15] };
    const float* nl_tb[2] = { (const float*)d_in[8],  (const float*)d_in[16] };
    const float* nl_pw[2] = { (const float*)d_in[9],  (const float*)d_in[17] };
    const float* nl_pb[2] = { (const float*)d_in[10], (const float*)d_in[18] };
    const float* nl_gw[2] = { (const float*)d_in[11], (const float*)d_in[19] };
    const float* nl_gb[2] = { (const float*)d_in[12], (const float*)d_in[20] };
    const float* nl_ww[2] = { (const float*)d_in[13], (const float*)d_in[21] };
    const float* nl_wb[2] = { (const float*)d_in[14], (const float*)d_in[22] };
    const float* dec_w0 = (const float*)d_in[23];
    const float* dec_b0 = (const float*)d_in[24];
    const float* dec_w1 = (const float*)d_in[25];
    const float* dec_b1 = (const float*)d_in[26];
    const float* off_w  = (const float*)d_in[27];
    const float* off_b  = (const float*)d_in[28];
    const float* dcn_w  = (const float*)d_in[29];
    const float* dcn_b  = (const float*)d_in[30];

    float* ws  = (float*)d_ws;
    float* e0  = ws;                  // 131072
    float* th0 = e0 + 131072;         // 65536 x4
    float* ph0 = th0 + 65536;
    float* g0  = ph0 + 65536;
    float* y0  = g0 + 65536;
    float* m0  = y0 + 65536;          // 131072
    float* u0  = m0 + 131072;         // 524288
    float* e1  = u0 + 524288;         // 524288
    float* th1 = e1 + 524288;         // 262144 x4
    float* ph1 = th1 + 262144;
    float* g1  = ph1 + 262144;
    float* y1  = g1 + 262144;
    float* m1  = y1 + 262144;         // 524288
    float* mot = m1 + 524288;         // 2097152
    float* est = mot + 2097152;       // 884736
    float* P   = est + 884736;        // 2163200 (dilated input, max 2*64*130*130)
    float* wt  = P + 2163200;         // 36864
    float* partial = wt + 36864;      // 4194304
    // total ~12.5M floats (~50 MB)

    float* out = (float*)d_out;
    const size_t frame = (size_t)2 * 128 * 128 * 128;

    hipMemcpyAsync(out, x_all, frame * sizeof(float), hipMemcpyDeviceToDevice, stream);

    for (int s = 1; s < 3; ++s) {
        const float* pc = ms_coarse + (size_t)s * 2 * 256 * 64 * 64;
        const float* cc = ms_coarse;
        const float* pf = ms_fine + (size_t)s * frame;
        const float* cf = ms_fine;

        // ---- e0 = lrelu(conv3x3 s2 (pc||cc; 512->64)) : (2,64,32,32)
        conv3x3_gemm<2, 1, 4, true><<<2 * 16 * 16, 256, 0, stream>>>(
            pc, cc, 256, 64, 64, 512, 32, enc_w0, 64, 32, 32, 16, 16, partial);
        reduce_bias_act<<<512, 256, 0, stream>>>(partial, enc_b0, e0, 64, 64, 1024, 16, 1);

        // ---- non-local 0 (N=1024)
        conv1x1x3_kernel<<<8, 256, 0, stream>>>(e0, 1024,
            nl_tw[0], nl_tb[0], nl_pw[0], nl_pb[0], nl_gw[0], nl_gb[0], th0, ph0, g0);
        attn_kernel<<<512, 256, 0, stream>>>(th0, ph0, g0, y0, 1024);
        nl_merge_kernel<<<8, 256, 0, stream>>>(e0, y0, nullptr, nl_ww[0], nl_wb[0], m0, 1024);

        // ---- u0 = lrelu(deconv(m0)) : (2,64,64,64) via dilate + conv
        {
            int total = 128 * 66 * 66;
            dilate_kernel<<<(total + 255) / 256, 256, 0, stream>>>(m0, P, 32, 32, 128, total);
            deconv_w_kernel<<<144, 256, 0, stream>>>(dec_w0, wt, 64);
            conv3x3_gemm<1, 0, 4, false><<<2 * 64 * 4, 256, 0, stream>>>(
                P, P, 64, 66, 66, 64, 16, wt, 64, 64, 64, 64, 4, partial);
            reduce_bias_act<<<2048, 256, 0, stream>>>(partial, dec_b0, u0, 64, 64, 4096, 4, 1);
        }

        // ---- e1 = lrelu(conv3x3 s2 (pf||cf; 256->64)) : (2,64,64,64)
        conv3x3_gemm<2, 1, 4, true><<<2 * 64 * 4, 256, 0, stream>>>(
            pf, cf, 128, 128, 128, 256, 64, enc_w1, 64, 64, 64, 64, 4, partial);
        reduce_bias_act<<<2048, 256, 0, stream>>>(partial, enc_b1, e1, 64, 64, 4096, 4, 1);

        // ---- non-local 1 (N=4096)
        conv1x1x3_kernel<<<32, 256, 0, stream>>>(e1, 4096,
            nl_tw[1], nl_tb[1], nl_pw[1], nl_pb[1], nl_gw[1], nl_gb[1], th1, ph1, g1);
        attn_kernel<<<2048, 256, 0, stream>>>(th1, ph1, g1, y1, 4096);
        nl_merge_kernel<<<32, 256, 0, stream>>>(e1, y1, u0, nl_ww[1], nl_wb[1], m1, 4096);

        // ---- mot = lrelu(deconv(m1)) : (2,64,128,128)
        {
            int total = 128 * 130 * 130;
            dilate_kernel<<<(total + 255) / 256, 256, 0, stream>>>(m1, P, 64, 64, 128, total);
            deconv_w_kernel<<<144, 256, 0, stream>>>(dec_w1, wt, 64);
            conv3x3_gemm<1, 0, 4, false><<<2 * 256 * 2, 256, 0, stream>>>(
                P, P, 64, 130, 130, 64, 32, wt, 64, 128, 128, 256, 2, partial);
            reduce_bias_act<<<8192, 256, 0, stream>>>(partial, dec_b1, mot, 64, 64, 16384, 2, 1);
        }

        // ---- est = conv3x3 s1 (mot; 64->27) : (2,27,128,128)
        conv3x3_gemm<1, 1, 2, true><<<2 * 256 * 2, 256, 0, stream>>>(
            mot, mot, 64, 128, 128, 64, 32, off_w, 27, 128, 128, 256, 2, partial);
        reduce_bias_act<<<3456, 256, 0, stream>>>(partial, off_b, est, 32, 27, 16384, 2, 0);

        // ---- aligned[s] = deform_conv(x_all[s], offset, mask)
        deform_kernel<<<2 * 256, 256, 0, stream>>>(
            x_all + (size_t)s * frame, est, dcn_w, dcn_b, out + (size_t)s * frame);
    }
}

// Round 3
// 2586.024 us; speedup vs baseline: 2.0271x; 1.0968x over previous
//
#include <hip/hip_runtime.h>
#include <math.h>

typedef __attribute__((ext_vector_type(8))) short bf16x8;
typedef __attribute__((ext_vector_type(4))) float f32x4;
typedef unsigned short ushort_t;
typedef unsigned int uint_t;

__device__ __forceinline__ float lrelu_f(float x) { return x >= 0.f ? x : 0.01f * x; }

__device__ __forceinline__ ushort_t f2bf(float f) {
    uint_t x = __float_as_uint(f);
    uint_t r = (x + 0x7fffu + ((x >> 16) & 1u)) >> 16;
    return (ushort_t)r;
}

// ===========================================================================
// Register-tiled implicit-GEMM 3x3 conv (fp32). Unchanged from round 1.
// ===========================================================================
#define CONV_CB 8

template<int STRIDE, int PAD, int TCO, bool MASK>
__global__ __launch_bounds__(256) void conv3x3_gemm(
    const float* __restrict__ inA, const float* __restrict__ inB, int CinA,
    int Hin, int Win, int Cin, int Cspan,
    const float* __restrict__ w, int Cout,
    int Hout, int Wout, int tilesPerMap, int ksplit,
    float* __restrict__ part)
{
    constexpr int CO = TCO * 16;
    __shared__ float sw[CONV_CB * 9 * CO];
    int tile = blockIdx.x % tilesPerMap;
    int ks   = (blockIdx.x / tilesPerMap) % ksplit;
    int b    = blockIdx.x / (tilesPerMap * ksplit);
    int tid  = threadIdx.x;
    int tpx  = tid & 15, tco = tid >> 4;
    int co0  = tco * TCO;
    int Npx  = Hout * Wout;

    int   off[4][9];
    float m[4][9];
    #pragma unroll
    for (int v = 0; v < 4; ++v) {
        int p = tile * 64 + tpx + v * 16;
        int oy = p / Wout, ox = p % Wout;
        #pragma unroll
        for (int ky = 0; ky < 3; ++ky) {
            int iy = oy * STRIDE - PAD + ky;
            bool vy = (iy >= 0) && (iy < Hin);
            int iyc = min(max(iy, 0), Hin - 1);
            #pragma unroll
            for (int kx = 0; kx < 3; ++kx) {
                int ix = ox * STRIDE - PAD + kx;
                bool vx = (ix >= 0) && (ix < Win);
                int ixc = min(max(ix, 0), Win - 1);
                off[v][ky * 3 + kx] = (iyc * Win + ixc) * 4;
                if (MASK) m[v][ky * 3 + kx] = (vy && vx) ? 1.f : 0.f;
            }
        }
    }

    float acc[TCO][4];
    #pragma unroll
    for (int u = 0; u < TCO; ++u)
        #pragma unroll
        for (int v = 0; v < 4; ++v) acc[u][v] = 0.f;

    int c0 = ks * Cspan;
    int CinB = Cin - CinA;
    for (int cc = 0; cc < Cspan; cc += CONV_CB) {
        __syncthreads();
        for (int i = tid; i < CONV_CB * 9 * CO; i += 256) {
            int co = i / (CONV_CB * 9);
            int r  = i % (CONV_CB * 9);
            int ci = r / 9, tap = r % 9;
            float wv = 0.f;
            if (co < Cout) wv = w[((size_t)co * Cin + (c0 + cc + ci)) * 9 + tap];
            sw[(ci * 9 + tap) * CO + co] = wv;
        }
        __syncthreads();
        #pragma unroll 1
        for (int ci = 0; ci < CONV_CB; ++ci) {
            int c = c0 + cc + ci;
            const float* src;
            if (c < CinA) src = inA + ((size_t)b * CinA + c) * (size_t)(Hin * Win);
            else          src = inB + ((size_t)b * CinB + (c - CinA)) * (size_t)(Hin * Win);
            const float* wrow = &sw[ci * 9 * CO];
            #pragma unroll
            for (int t = 0; t < 9; ++t) {
                float vals[4];
                #pragma unroll
                for (int v = 0; v < 4; ++v) {
                    float x = *(const float*)((const char*)src + off[v][t]);
                    vals[v] = MASK ? x * m[v][t] : x;
                }
                #pragma unroll
                for (int u = 0; u < TCO; ++u) {
                    float wv = wrow[t * CO + co0 + u];
                    #pragma unroll
                    for (int v = 0; v < 4; ++v)
                        acc[u][v] = fmaf(wv, vals[v], acc[u][v]);
                }
            }
        }
    }

    #pragma unroll
    for (int u = 0; u < TCO; ++u) {
        #pragma unroll
        for (int v = 0; v < 4; ++v) {
            int p = tile * 64 + tpx + v * 16;
            part[(((size_t)ks * 2 + b) * CO + co0 + u) * (size_t)Npx + p] = acc[u][v];
        }
    }
}

__global__ __launch_bounds__(256) void reduce_bias_act(const float* __restrict__ part,
    const float* __restrict__ bias, float* __restrict__ out,
    int CO, int Cout, int Npx, int ksplit, int act)
{
    int idx = blockIdx.x * 256 + threadIdx.x;
    int total = 2 * Cout * Npx;
    if (idx >= total) return;
    int p  = idx % Npx;
    int co = (idx / Npx) % Cout;
    int b  = idx / (Npx * Cout);
    float s = bias[co];
    for (int ks = 0; ks < ksplit; ++ks)
        s += part[(((size_t)ks * 2 + b) * CO + co) * (size_t)Npx + p];
    if (act) s = lrelu_f(s);
    out[((size_t)b * Cout + co) * (size_t)Npx + p] = s;
}

__global__ __launch_bounds__(256) void dilate_kernel(const float* __restrict__ in,
    float* __restrict__ P, int Hin, int Win, int C2, int total)
{
    int idx = blockIdx.x * 256 + threadIdx.x;
    if (idx >= total) return;
    int Wp = 2 * Win + 2, Hp = 2 * Hin + 2;
    int v = idx % Wp, u = (idx / Wp) % Hp;
    int c = idx / (Wp * Hp);
    float val = 0.f;
    if ((u & 1) && (v & 1)) {
        int r = (u - 1) >> 1, q = (v - 1) >> 1;
        if (r < Hin && q < Win) val = in[((size_t)c * Hin + r) * Win + q];
    }
    P[idx] = val;
}

__global__ __launch_bounds__(256) void deconv_w_kernel(const float* __restrict__ w,
    float* __restrict__ wt, int C)
{
    int idx = blockIdx.x * 256 + threadIdx.x;
    if (idx >= C * C * 9) return;
    int tap = idx % 9;
    int i = (idx / 9) % C;
    int o = idx / (9 * C);
    int ky = tap / 3, kx = tap % 3;
    wt[idx] = w[(((size_t)i * C + o) * 9) + (2 - ky) * 3 + (2 - kx)];
}

// cast dcn weights to bf16 [co][ci*9+tap] (already contiguous in source)
__global__ __launch_bounds__(256) void castw_kernel(const float* __restrict__ w,
    ushort_t* __restrict__ wbf, int total)
{
    int idx = blockIdx.x * 256 + threadIdx.x;
    if (idx < total) wbf[idx] = f2bf(w[idx]);
}

// ---------------------------------------------------------------------------
// Fused 1x1 convs producing th/ph/g (each 64->32) from e (B,64,N).
// ---------------------------------------------------------------------------
__global__ __launch_bounds__(256) void conv1x1x3_kernel(const float* __restrict__ e, int N,
    const float* __restrict__ tw, const float* __restrict__ tb,
    const float* __restrict__ pw, const float* __restrict__ pb,
    const float* __restrict__ gw, const float* __restrict__ gb,
    float* __restrict__ th, float* __restrict__ ph, float* __restrict__ g)
{
    __shared__ float sw[3 * 32 * 64];
    __shared__ float sb[96];
    int tid = threadIdx.x;
    for (int i = tid; i < 2048; i += 256) { sw[i] = tw[i]; sw[2048 + i] = pw[i]; sw[4096 + i] = gw[i]; }
    if (tid < 32) { sb[tid] = tb[tid]; sb[32 + tid] = pb[tid]; sb[64 + tid] = gb[tid]; }
    __syncthreads();
    int idx = blockIdx.x * 256 + tid;
    int n = idx % N, b = idx / N;
    float ein[64];
    const float* ep = e + (size_t)b * 64 * N + n;
    #pragma unroll
    for (int ci = 0; ci < 64; ++ci) ein[ci] = ep[(size_t)ci * N];
    float* outs[3] = { th, ph, g };
    #pragma unroll
    for (int j = 0; j < 3; ++j) {
        float* op = outs[j] + (size_t)b * 32 * N + n;
        for (int cc = 0; cc < 32; ++cc) {
            float acc = sb[j * 32 + cc];
            const float* wr = &sw[j * 2048 + cc * 64];
            #pragma unroll
            for (int ci = 0; ci < 64; ++ci) acc = fmaf(wr[ci], ein[ci], acc);
            op[(size_t)cc * N] = acc;
        }
    }
}

// ---------------------------------------------------------------------------
// Streaming attention, two-pass, 4-way split accumulators for ILP.
// ---------------------------------------------------------------------------
__global__ __launch_bounds__(256) void attn_kernel(const float* __restrict__ th,
    const float* __restrict__ ph, const float* __restrict__ g,
    float* __restrict__ y, int N)
{
    int wave = blockIdx.x * 4 + (threadIdx.x >> 6);
    int lane = threadIdx.x & 63;
    int n = wave % N, b = wave / N;
    const float* thp = th + (size_t)b * 32 * N;
    const float* php = ph + (size_t)b * 32 * N;
    const float* gp  = g  + (size_t)b * 32 * N;
    float tn[32];
    #pragma unroll
    for (int c = 0; c < 32; ++c) tn[c] = thp[(size_t)c * N + n];
    float mx = -1e30f;
    for (int m = lane; m < N; m += 64) {
        float s0 = 0.f, s1 = 0.f, s2 = 0.f, s3 = 0.f;
        #pragma unroll
        for (int c = 0; c < 8; ++c) {
            s0 = fmaf(tn[c],      php[(size_t)c * N + m], s0);
            s1 = fmaf(tn[8 + c],  php[(size_t)(8 + c) * N + m], s1);
            s2 = fmaf(tn[16 + c], php[(size_t)(16 + c) * N + m], s2);
            s3 = fmaf(tn[24 + c], php[(size_t)(24 + c) * N + m], s3);
        }
        mx = fmaxf(mx, (s0 + s1) + (s2 + s3));
    }
    #pragma unroll
    for (int off = 32; off >= 1; off >>= 1) mx = fmaxf(mx, __shfl_xor(mx, off));
    float sum = 0.f;
    float ya[32];
    #pragma unroll
    for (int c = 0; c < 32; ++c) ya[c] = 0.f;
    for (int m = lane; m < N; m += 64) {
        float s0 = 0.f, s1 = 0.f, s2 = 0.f, s3 = 0.f;
        #pragma unroll
        for (int c = 0; c < 8; ++c) {
            s0 = fmaf(tn[c],      php[(size_t)c * N + m], s0);
            s1 = fmaf(tn[8 + c],  php[(size_t)(8 + c) * N + m], s1);
            s2 = fmaf(tn[16 + c], php[(size_t)(16 + c) * N + m], s2);
            s3 = fmaf(tn[24 + c], php[(size_t)(24 + c) * N + m], s3);
        }
        float pv = __expf((s0 + s1) + (s2 + s3) - mx);
        sum += pv;
        #pragma unroll
        for (int c = 0; c < 32; ++c) ya[c] = fmaf(pv, gp[(size_t)c * N + m], ya[c]);
    }
    #pragma unroll
    for (int off = 32; off >= 1; off >>= 1) sum += __shfl_xor(sum, off);
    #pragma unroll
    for (int c = 0; c < 32; ++c) {
        #pragma unroll
        for (int off = 32; off >= 1; off >>= 1) ya[c] += __shfl_xor(ya[c], off);
    }
    if (lane == 0) {
        float inv = 1.f / sum;
        float* yp = y + (size_t)b * 32 * N + n;
        #pragma unroll
        for (int c = 0; c < 32; ++c) yp[(size_t)c * N] = ya[c] * inv;
    }
}

__global__ __launch_bounds__(256) void nl_merge_kernel(const float* __restrict__ e,
    const float* __restrict__ yin, const float* __restrict__ u,
    const float* __restrict__ ww, const float* __restrict__ wb,
    float* __restrict__ out, int N)
{
    __shared__ float sw[64 * 32];
    __shared__ float sb[64];
    int tid = threadIdx.x;
    for (int i = tid; i < 2048; i += 256) sw[i] = ww[i];
    if (tid < 64) sb[tid] = wb[tid];
    __syncthreads();
    int idx = blockIdx.x * 256 + tid;
    int n = idx % N, b = idx / N;
    float yv[32];
    #pragma unroll
    for (int c = 0; c < 32; ++c) yv[c] = yin[(size_t)b * 32 * N + (size_t)c * N + n];
    for (int co = 0; co < 64; ++co) {
        float acc = sb[co];
        #pragma unroll
        for (int c = 0; c < 32; ++c) acc = fmaf(sw[co * 32 + c], yv[c], acc);
        size_t o = (size_t)b * 64 * N + (size_t)co * N + n;
        acc += 2.f * e[o];
        if (u) acc += u[o];
        out[o] = acc;
    }
}

// ===========================================================================
// Deformable conv 3x3 as bf16 MFMA implicit GEMM.
// Block: 256 threads = 4 waves; tile = 64 px, all 128 co. K = 1152, chunked
// by 32 input channels (288 K-rows) staged as bf16 in LDS [px][296].
// Wave w computes co [32w, 32w+32) x 64 px via 2x4 16x16x32 fragments.
// ===========================================================================
__global__ __launch_bounds__(256) void deform_mfma(const float* __restrict__ x,
    const float* __restrict__ est, const ushort_t* __restrict__ wbf,
    const float* __restrict__ bias, float* __restrict__ out)
{
    const int H = 128, W = 128, HW = 16384;
    const int BS = 296; // sB row stride (ushorts)
    __shared__ ushort_t sB[64 * BS];
    __shared__ float spy[576], spx[576], smk[576];
    int tile = blockIdx.x & 255;
    int b    = blockIdx.x >> 8;
    int p0   = tile * 64;
    int tid  = threadIdx.x;

    const float* eb = est + (size_t)b * 27 * HW;
    for (int i = tid; i < 576; i += 256) {
        int k = i >> 6, j = i & 63;
        int p = p0 + j;
        int yy = p >> 7, xx = p & 127;
        float oy = eb[(size_t)(9 + 2 * k) * HW + p];
        float ox = eb[(size_t)(10 + 2 * k) * HW + p];
        float mv = eb[(size_t)k * HW + p];
        smk[i] = 1.f / (1.f + __expf(-mv));
        spy[i] = (float)(yy + (k / 3) - 1) + oy;
        spx[i] = (float)(xx + (k % 3) - 1) + ox;
    }

    int wave = tid >> 6, lane = tid & 63;
    int co_base = wave * 32;
    int lrow = lane & 15, lkg = lane >> 4;

    f32x4 acc[2][4];
    #pragma unroll
    for (int m2 = 0; m2 < 2; ++m2)
        #pragma unroll
        for (int n2 = 0; n2 < 4; ++n2) acc[m2][n2] = (f32x4){0.f, 0.f, 0.f, 0.f};

    const float* xb = x + (size_t)b * 128 * HW;

    for (int cc = 0; cc < 128; cc += 32) {
        __syncthreads();
        for (int vi = tid; vi < 288 * 64; vi += 256) {
            int px  = vi & 63;
            int row = vi >> 6;           // 0..287 = cl*9 + tap
            int cl  = row / 9;
            int tap = row - cl * 9;
            int si  = tap * 64 + px;
            float py = spy[si], qx = spx[si];
            float fy0 = floorf(py), fx0 = floorf(qx);
            float wy = py - fy0, wx = qx - fx0;
            int y0 = (int)fy0, x0 = (int)fx0;
            const float* src = xb + (size_t)(cc + cl) * HW;
            float v = 0.f;
            float w00 = (1.f - wy) * (1.f - wx), w01 = (1.f - wy) * wx;
            float w10 = wy * (1.f - wx),         w11 = wy * wx;
            bool yv0 = (y0 >= 0) && (y0 < H), yv1 = (y0 + 1 >= 0) && (y0 + 1 < H);
            bool xv0 = (x0 >= 0) && (x0 < W), xv1 = (x0 + 1 >= 0) && (x0 + 1 < W);
            if (yv0 && xv0) v = fmaf(w00, src[(size_t)y0 * W + x0], v);
            if (yv0 && xv1) v = fmaf(w01, src[(size_t)y0 * W + x0 + 1], v);
            if (yv1 && xv0) v = fmaf(w10, src[(size_t)(y0 + 1) * W + x0], v);
            if (yv1 && xv1) v = fmaf(w11, src[(size_t)(y0 + 1) * W + x0 + 1], v);
            sB[px * BS + row] = f2bf(v * smk[si]);
        }
        __syncthreads();
        int kbase = cc * 9;
        #pragma unroll
        for (int ks = 0; ks < 9; ++ks) {
            bf16x8 afr[2], bfr[4];
            #pragma unroll
            for (int m2 = 0; m2 < 2; ++m2)
                afr[m2] = *reinterpret_cast<const bf16x8*>(
                    wbf + (size_t)(co_base + m2 * 16 + lrow) * 1152 + kbase + ks * 32 + lkg * 8);
            #pragma unroll
            for (int n2 = 0; n2 < 4; ++n2)
                bfr[n2] = *reinterpret_cast<const bf16x8*>(
                    &sB[(n2 * 16 + lrow) * BS + ks * 32 + lkg * 8]);
            #pragma unroll
            for (int m2 = 0; m2 < 2; ++m2)
                #pragma unroll
                for (int n2 = 0; n2 < 4; ++n2)
                    acc[m2][n2] = __builtin_amdgcn_mfma_f32_16x16x32_bf16(
                        afr[m2], bfr[n2], acc[m2][n2], 0, 0, 0);
        }
    }

    #pragma unroll
    for (int m2 = 0; m2 < 2; ++m2) {
        #pragma unroll
        for (int j = 0; j < 4; ++j) {
            int co = co_base + m2 * 16 + lkg * 4 + j;
            float bb = bias[co];
            #pragma unroll
            for (int n2 = 0; n2 < 4; ++n2) {
                int px = p0 + n2 * 16 + lrow;
                out[((size_t)(b * 128 + co)) * HW + px] = acc[m2][n2][j] + bb;
            }
        }
    }
}

extern "C" void kernel_launch(void* const* d_in, const int* in_sizes, int n_in,
                              void* d_out, int out_size, void* d_ws, size_t ws_size,
                              hipStream_t stream)
{
    const float* x_all     = (const float*)d_in[0];
    const float* ms_fine   = (const float*)d_in[1];
    const float* ms_coarse = (const float*)d_in[2];
    const float* enc_w0 = (const float*)d_in[3];
    const float* enc_b0 = (const float*)d_in[4];
    const float* enc_w1 = (const float*)d_in[5];
    const float* enc_b1 = (const float*)d_in[6];
    const float* nl_tw[2] = { (const float*)d_in[7],  (const float*)d_in[15] };
    const float* nl_tb[2] = { (const float*)d_in[8],  (const float*)d_in[16] };
    const float* nl_pw[2] = { (const float*)d_in[9],  (const float*)d_in[17] };
    const float* nl_pb[2] = { (const float*)d_in[10], (const float*)d_in[18] };
    const float* nl_gw[2] = { (const float*)d_in[11], (const float*)d_in[19] };
    const float* nl_gb[2] = { (const float*)d_in[12], (const float*)d_in[20] };
    const float* nl_ww[2] = { (const float*)d_in[13], (const float*)d_in[21] };
    const float* nl_wb[2] = { (const float*)d_in[14], (const float*)d_in[22] };
    const float* dec_w0 = (const float*)d_in[23];
    const float* dec_b0 = (const float*)d_in[24];
    const float* dec_w1 = (const float*)d_in[25];
    const float* dec_b1 = (const float*)d_in[26];
    const float* off_w  = (const float*)d_in[27];
    const float* off_b  = (const float*)d_in[28];
    const float* dcn_w  = (const float*)d_in[29];
    const float* dcn_b  = (const float*)d_in[30];

    float* ws  = (float*)d_ws;
    float* e0  = ws;                  // 131072
    float* th0 = e0 + 131072;
    float* ph0 = th0 + 65536;
    float* g0  = ph0 + 65536;
    float* y0  = g0 + 65536;
    float* m0  = y0 + 65536;          // 131072
    float* u0  = m0 + 131072;         // 524288
    float* e1  = u0 + 524288;         // 524288
    float* th1 = e1 + 524288;
    float* ph1 = th1 + 262144;
    float* g1  = ph1 + 262144;
    float* y1  = g1 + 262144;
    float* m1  = y1 + 262144;         // 524288
    float* mot = m1 + 524288;         // 2097152
    float* est = mot + 2097152;       // 884736
    float* P   = est + 884736;        // 2163200
    float* wt  = P + 2163200;         // 36864
    float* partial = wt + 36864;      // 4194304
    ushort_t* wbf = (ushort_t*)(partial + 4194304); // 147456 ushorts

    float* out = (float*)d_out;
    const size_t frame = (size_t)2 * 128 * 128 * 128;

    hipMemcpyAsync(out, x_all, frame * sizeof(float), hipMemcpyDeviceToDevice, stream);
    castw_kernel<<<(147456 + 255) / 256, 256, 0, stream>>>(dcn_w, wbf, 147456);

    for (int s = 1; s < 3; ++s) {
        const float* pc = ms_coarse + (size_t)s * 2 * 256 * 64 * 64;
        const float* cc = ms_coarse;
        const float* pf = ms_fine + (size_t)s * frame;
        const float* cf = ms_fine;

        // ---- e0 = lrelu(conv3x3 s2 (pc||cc; 512->64)) : (2,64,32,32)
        conv3x3_gemm<2, 1, 4, true><<<2 * 16 * 16, 256, 0, stream>>>(
            pc, cc, 256, 64, 64, 512, 32, enc_w0, 64, 32, 32, 16, 16, partial);
        reduce_bias_act<<<512, 256, 0, stream>>>(partial, enc_b0, e0, 64, 64, 1024, 16, 1);

        // ---- non-local 0 (N=1024)
        conv1x1x3_kernel<<<8, 256, 0, stream>>>(e0, 1024,
            nl_tw[0], nl_tb[0], nl_pw[0], nl_pb[0], nl_gw[0], nl_gb[0], th0, ph0, g0);
        attn_kernel<<<512, 256, 0, stream>>>(th0, ph0, g0, y0, 1024);
        nl_merge_kernel<<<8, 256, 0, stream>>>(e0, y0, nullptr, nl_ww[0], nl_wb[0], m0, 1024);

        // ---- u0 = lrelu(deconv(m0)) : (2,64,64,64)
        {
            int total = 128 * 66 * 66;
            dilate_kernel<<<(total + 255) / 256, 256, 0, stream>>>(m0, P, 32, 32, 128, total);
            deconv_w_kernel<<<144, 256, 0, stream>>>(dec_w0, wt, 64);
            conv3x3_gemm<1, 0, 4, false><<<2 * 64 * 4, 256, 0, stream>>>(
                P, P, 64, 66, 66, 64, 16, wt, 64, 64, 64, 64, 4, partial);
            reduce_bias_act<<<2048, 256, 0, stream>>>(partial, dec_b0, u0, 64, 64, 4096, 4, 1);
        }

        // ---- e1 = lrelu(conv3x3 s2 (pf||cf; 256->64)) : (2,64,64,64)
        conv3x3_gemm<2, 1, 4, true><<<2 * 64 * 4, 256, 0, stream>>>(
            pf, cf, 128, 128, 128, 256, 64, enc_w1, 64, 64, 64, 64, 4, partial);
        reduce_bias_act<<<2048, 256, 0, stream>>>(partial, enc_b1, e1, 64, 64, 4096, 4, 1);

        // ---- non-local 1 (N=4096)
        conv1x1x3_kernel<<<32, 256, 0, stream>>>(e1, 4096,
            nl_tw[1], nl_tb[1], nl_pw[1], nl_pb[1], nl_gw[1], nl_gb[1], th1, ph1, g1);
        attn_kernel<<<2048, 256, 0, stream>>>(th1, ph1, g1, y1, 4096);
        nl_merge_kernel<<<32, 256, 0, stream>>>(e1, y1, u0, nl_ww[1], nl_wb[1], m1, 4096);

        // ---- mot = lrelu(deconv(m1)) : (2,64,128,128)
        {
            int total = 128 * 130 * 130;
            dilate_kernel<<<(total + 255) / 256, 256, 0, stream>>>(m1, P, 64, 64, 128, total);
            deconv_w_kernel<<<144, 256, 0, stream>>>(dec_w1, wt, 64);
            conv3x3_gemm<1, 0, 4, false><<<2 * 256 * 2, 256, 0, stream>>>(
                P, P, 64, 130, 130, 64, 32, wt, 64, 128, 128, 256, 2, partial);
            reduce_bias_act<<<8192, 256, 0, stream>>>(partial, dec_b1, mot, 64, 64, 16384, 2, 1);
        }

        // ---- est = conv3x3 s1 (mot; 64->27) : (2,27,128,128)
        conv3x3_gemm<1, 1, 2, true><<<2 * 256 * 2, 256, 0, stream>>>(
            mot, mot, 64, 128, 128, 64, 32, off_w, 27, 128, 128, 256, 2, partial);
        reduce_bias_act<<<3456, 256, 0, stream>>>(partial, off_b, est, 32, 27, 16384, 2, 0);

        // ---- aligned[s] = deform_conv(x_all[s], offset, mask)  [bf16 MFMA]
        deform_mfma<<<512, 256, 0, stream>>>(
            x_all + (size_t)s * frame, est, wbf, dcn_b, out + (size_t)s * frame);
    }
}

// Round 4
// 1888.457 us; speedup vs baseline: 2.7758x; 1.3694x over previous
//
#include <hip/hip_runtime.h>
#include <math.h>

typedef __attribute__((ext_vector_type(8))) short bf16x8;
typedef __attribute__((ext_vector_type(4))) float f32x4;
typedef unsigned short ushort_t;
typedef unsigned int uint_t;

__device__ __forceinline__ float lrelu_f(float x) { return x >= 0.f ? x : 0.01f * x; }

__device__ __forceinline__ ushort_t f2bf(float f) {
    uint_t x = __float_as_uint(f);
    uint_t r = (x + 0x7fffu + ((x >> 16) & 1u)) >> 16;
    return (ushort_t)r;
}

__device__ __forceinline__ uint_t pack_bf16(float lo, float hi) {
    uint_t out;
    asm("v_cvt_pk_bf16_f32 %0, %1, %2" : "=v"(out) : "v"(lo), "v"(hi));
    return out;
}

// ===========================================================================
// Register-tiled implicit-GEMM 3x3 conv (fp32). Unchanged.
// ===========================================================================
#define CONV_CB 8

template<int STRIDE, int PAD, int TCO, bool MASK>
__global__ __launch_bounds__(256) void conv3x3_gemm(
    const float* __restrict__ inA, const float* __restrict__ inB, int CinA,
    int Hin, int Win, int Cin, int Cspan,
    const float* __restrict__ w, int Cout,
    int Hout, int Wout, int tilesPerMap, int ksplit,
    float* __restrict__ part)
{
    constexpr int CO = TCO * 16;
    __shared__ float sw[CONV_CB * 9 * CO];
    int tile = blockIdx.x % tilesPerMap;
    int ks   = (blockIdx.x / tilesPerMap) % ksplit;
    int b    = blockIdx.x / (tilesPerMap * ksplit);
    int tid  = threadIdx.x;
    int tpx  = tid & 15, tco = tid >> 4;
    int co0  = tco * TCO;
    int Npx  = Hout * Wout;

    int   off[4][9];
    float m[4][9];
    #pragma unroll
    for (int v = 0; v < 4; ++v) {
        int p = tile * 64 + tpx + v * 16;
        int oy = p / Wout, ox = p % Wout;
        #pragma unroll
        for (int ky = 0; ky < 3; ++ky) {
            int iy = oy * STRIDE - PAD + ky;
            bool vy = (iy >= 0) && (iy < Hin);
            int iyc = min(max(iy, 0), Hin - 1);
            #pragma unroll
            for (int kx = 0; kx < 3; ++kx) {
                int ix = ox * STRIDE - PAD + kx;
                bool vx = (ix >= 0) && (ix < Win);
                int ixc = min(max(ix, 0), Win - 1);
                off[v][ky * 3 + kx] = (iyc * Win + ixc) * 4;
                if (MASK) m[v][ky * 3 + kx] = (vy && vx) ? 1.f : 0.f;
            }
        }
    }

    float acc[TCO][4];
    #pragma unroll
    for (int u = 0; u < TCO; ++u)
        #pragma unroll
        for (int v = 0; v < 4; ++v) acc[u][v] = 0.f;

    int c0 = ks * Cspan;
    int CinB = Cin - CinA;
    for (int cc = 0; cc < Cspan; cc += CONV_CB) {
        __syncthreads();
        for (int i = tid; i < CONV_CB * 9 * CO; i += 256) {
            int co = i / (CONV_CB * 9);
            int r  = i % (CONV_CB * 9);
            int ci = r / 9, tap = r % 9;
            float wv = 0.f;
            if (co < Cout) wv = w[((size_t)co * Cin + (c0 + cc + ci)) * 9 + tap];
            sw[(ci * 9 + tap) * CO + co] = wv;
        }
        __syncthreads();
        #pragma unroll 1
        for (int ci = 0; ci < CONV_CB; ++ci) {
            int c = c0 + cc + ci;
            const float* src;
            if (c < CinA) src = inA + ((size_t)b * CinA + c) * (size_t)(Hin * Win);
            else          src = inB + ((size_t)b * CinB + (c - CinA)) * (size_t)(Hin * Win);
            const float* wrow = &sw[ci * 9 * CO];
            #pragma unroll
            for (int t = 0; t < 9; ++t) {
                float vals[4];
                #pragma unroll
                for (int v = 0; v < 4; ++v) {
                    float x = *(const float*)((const char*)src + off[v][t]);
                    vals[v] = MASK ? x * m[v][t] : x;
                }
                #pragma unroll
                for (int u = 0; u < TCO; ++u) {
                    float wv = wrow[t * CO + co0 + u];
                    #pragma unroll
                    for (int v = 0; v < 4; ++v)
                        acc[u][v] = fmaf(wv, vals[v], acc[u][v]);
                }
            }
        }
    }

    #pragma unroll
    for (int u = 0; u < TCO; ++u) {
        #pragma unroll
        for (int v = 0; v < 4; ++v) {
            int p = tile * 64 + tpx + v * 16;
            part[(((size_t)ks * 2 + b) * CO + co0 + u) * (size_t)Npx + p] = acc[u][v];
        }
    }
}

__global__ __launch_bounds__(256) void reduce_bias_act(const float* __restrict__ part,
    const float* __restrict__ bias, float* __restrict__ out,
    int CO, int Cout, int Npx, int ksplit, int act)
{
    int idx = blockIdx.x * 256 + threadIdx.x;
    int total = 2 * Cout * Npx;
    if (idx >= total) return;
    int p  = idx % Npx;
    int co = (idx / Npx) % Cout;
    int b  = idx / (Npx * Cout);
    float s = bias[co];
    for (int ks = 0; ks < ksplit; ++ks)
        s += part[(((size_t)ks * 2 + b) * CO + co) * (size_t)Npx + p];
    if (act) s = lrelu_f(s);
    out[((size_t)b * Cout + co) * (size_t)Npx + p] = s;
}

__global__ __launch_bounds__(256) void dilate_kernel(const float* __restrict__ in,
    float* __restrict__ P, int Hin, int Win, int C2, int total)
{
    int idx = blockIdx.x * 256 + threadIdx.x;
    if (idx >= total) return;
    int Wp = 2 * Win + 2, Hp = 2 * Hin + 2;
    int v = idx % Wp, u = (idx / Wp) % Hp;
    int c = idx / (Wp * Hp);
    float val = 0.f;
    if ((u & 1) && (v & 1)) {
        int r = (u - 1) >> 1, q = (v - 1) >> 1;
        if (r < Hin && q < Win) val = in[((size_t)c * Hin + r) * Win + q];
    }
    P[idx] = val;
}

__global__ __launch_bounds__(256) void deconv_w_kernel(const float* __restrict__ w,
    float* __restrict__ wt, int C)
{
    int idx = blockIdx.x * 256 + threadIdx.x;
    if (idx >= C * C * 9) return;
    int tap = idx % 9;
    int i = (idx / 9) % C;
    int o = idx / (9 * C);
    int ky = tap / 3, kx = tap % 3;
    wt[idx] = w[(((size_t)i * C + o) * 9) + (2 - ky) * 3 + (2 - kx)];
}

__global__ __launch_bounds__(256) void castw_kernel(const float* __restrict__ w,
    ushort_t* __restrict__ wbf, int total)
{
    int idx = blockIdx.x * 256 + threadIdx.x;
    if (idx < total) wbf[idx] = f2bf(w[idx]);
}

// ---------------------------------------------------------------------------
// Fused 1x1 convs producing th/ph/g (each 64->32) from e (B,64,N).
// ---------------------------------------------------------------------------
__global__ __launch_bounds__(256) void conv1x1x3_kernel(const float* __restrict__ e, int N,
    const float* __restrict__ tw, const float* __restrict__ tb,
    const float* __restrict__ pw, const float* __restrict__ pb,
    const float* __restrict__ gw, const float* __restrict__ gb,
    float* __restrict__ th, float* __restrict__ ph, float* __restrict__ g)
{
    __shared__ float sw[3 * 32 * 64];
    __shared__ float sb[96];
    int tid = threadIdx.x;
    for (int i = tid; i < 2048; i += 256) { sw[i] = tw[i]; sw[2048 + i] = pw[i]; sw[4096 + i] = gw[i]; }
    if (tid < 32) { sb[tid] = tb[tid]; sb[32 + tid] = pb[tid]; sb[64 + tid] = gb[tid]; }
    __syncthreads();
    int idx = blockIdx.x * 256 + tid;
    int n = idx % N, b = idx / N;
    float ein[64];
    const float* ep = e + (size_t)b * 64 * N + n;
    #pragma unroll
    for (int ci = 0; ci < 64; ++ci) ein[ci] = ep[(size_t)ci * N];
    float* outs[3] = { th, ph, g };
    #pragma unroll
    for (int j = 0; j < 3; ++j) {
        float* op = outs[j] + (size_t)b * 32 * N + n;
        for (int cc = 0; cc < 32; ++cc) {
            float acc = sb[j * 32 + cc];
            const float* wr = &sw[j * 2048 + cc * 64];
            #pragma unroll
            for (int ci = 0; ci < 64; ++ci) acc = fmaf(wr[ci], ein[ci], acc);
            op[(size_t)cc * N] = acc;
        }
    }
}

// ===========================================================================
// Flash-style MFMA attention (bf16 inputs, fp32 accumulate).
// Grid: B * N/32 blocks, 128 threads (2 waves, 16 q-rows each).
// Swapped QK^T: T[m][q] = mfma(A=K[m][c], B=Q[c][q]) so D col = q.
// Per 64-m tile: stage K transposed sK[m][c], V natural sV[c][m] (bf16),
// online softmax (4-lane shfl reduce), P via per-wave LDS -> PV MFMA.
// ===========================================================================
__global__ __launch_bounds__(128) void attn_mfma(const float* __restrict__ th,
    const float* __restrict__ ph, const float* __restrict__ g,
    float* __restrict__ y, int N)
{
    __shared__ ushort_t sK[64 * 40];      // [m][c], stride 40 (80B, 16B-aligned)
    __shared__ ushort_t sV[32 * 72];      // [c][m], stride 72 (144B)
    __shared__ ushort_t sP[2][16 * 40];   // per-wave P [q][m]

    int tid  = threadIdx.x;
    int wave = tid >> 6, lane = tid & 63;
    int lq = lane & 15, lkg = lane >> 4;
    int nq = N / 32;
    int b  = blockIdx.x / nq;
    int q0 = (blockIdx.x % nq) * 32;

    const float* thp = th + (size_t)b * 32 * N;
    const float* php = ph + (size_t)b * 32 * N;
    const float* gp  = g  + (size_t)b * 32 * N;

    // Q fragment (loaded once): B[k=c][col=q] -> lane holds th[8*lkg+j][qg]
    bf16x8 qf;
    {
        int qg = q0 + 16 * wave + lq;
        #pragma unroll
        for (int j = 0; j < 8; ++j)
            ((ushort_t*)&qf)[j] = f2bf(thp[(size_t)(8 * lkg + j) * N + qg]);
    }

    float m_run = -1e30f, l_run = 0.f;
    f32x4 acc[2];
    acc[0] = (f32x4){0.f, 0.f, 0.f, 0.f};
    acc[1] = (f32x4){0.f, 0.f, 0.f, 0.f};

    int mK = tid & 63;
    int cb = (tid >> 6) * 16;
    int cV = tid >> 2;
    int msg = (tid & 3) * 16;

    for (int m0 = 0; m0 < N; m0 += 64) {
        __syncthreads();
        // ---- stage K (transposed) and V (natural), coalesced global reads
        {
            float kv[16];
            #pragma unroll
            for (int i = 0; i < 16; ++i) kv[i] = php[(size_t)(cb + i) * N + m0 + mK];
            #pragma unroll
            for (int i = 0; i < 8; ++i)
                *(uint_t*)&sK[mK * 40 + cb + 2 * i] = pack_bf16(kv[2 * i], kv[2 * i + 1]);
            float vv[16];
            #pragma unroll
            for (int i = 0; i < 16; ++i) vv[i] = gp[(size_t)cV * N + m0 + msg + i];
            #pragma unroll
            for (int i = 0; i < 8; ++i)
                *(uint_t*)&sV[cV * 72 + msg + 2 * i] = pack_bf16(vv[2 * i], vv[2 * i + 1]);
        }
        __syncthreads();

        // ---- QK^T: 4 m-subtile fragments. T[m][q], lane: q=lq, m=f*16+4*lkg+r
        f32x4 tf[4];
        #pragma unroll
        for (int f = 0; f < 4; ++f) {
            bf16x8 kf = *(const bf16x8*)&sK[(f * 16 + lq) * 40 + 8 * lkg];
            tf[f] = __builtin_amdgcn_mfma_f32_16x16x32_bf16(kf, qf,
                        (f32x4){0.f, 0.f, 0.f, 0.f}, 0, 0, 0);
        }

        // ---- online softmax (row stats across the 4 lanes sharing lq)
        float mx = -1e30f;
        #pragma unroll
        for (int f = 0; f < 4; ++f)
            #pragma unroll
            for (int r = 0; r < 4; ++r) mx = fmaxf(mx, tf[f][r]);
        mx = fmaxf(mx, __shfl_xor(mx, 16));
        mx = fmaxf(mx, __shfl_xor(mx, 32));
        float m_new = fmaxf(m_run, mx);
        float scale = __expf(m_run - m_new);
        float rs = 0.f;
        #pragma unroll
        for (int f = 0; f < 4; ++f)
            #pragma unroll
            for (int r = 0; r < 4; ++r) {
                float p = __expf(tf[f][r] - m_new);
                tf[f][r] = p;
                rs += p;
            }
        rs += __shfl_xor(rs, 16);
        rs += __shfl_xor(rs, 32);
        l_run = l_run * scale + rs;
        m_run = m_new;

        // rescale accumulator: lane's Y rows are q'=4*lkg+r; scale held by lane q'
        float sc[4];
        #pragma unroll
        for (int r = 0; r < 4; ++r) sc[r] = __shfl(scale, 4 * lkg + r);
        #pragma unroll
        for (int h = 0; h < 2; ++h)
            #pragma unroll
            for (int r = 0; r < 4; ++r) acc[h][r] *= sc[r];

        // ---- P -> bf16 -> per-wave LDS [q][m]
        #pragma unroll
        for (int f = 0; f < 4; ++f) {
            *(uint_t*)&sP[wave][lq * 40 + f * 16 + 4 * lkg]     = pack_bf16(tf[f][0], tf[f][1]);
            *(uint_t*)&sP[wave][lq * 40 + f * 16 + 4 * lkg + 2] = pack_bf16(tf[f][2], tf[f][3]);
        }

        // ---- PV: acc[h] += P[16q x 32m] * V[32m x 16c], 2 m-chunks
        #pragma unroll
        for (int mc = 0; mc < 2; ++mc) {
            bf16x8 pf = *(const bf16x8*)&sP[wave][lq * 40 + mc * 32 + 8 * lkg];
            #pragma unroll
            for (int h = 0; h < 2; ++h) {
                bf16x8 vf = *(const bf16x8*)&sV[(h * 16 + lq) * 72 + mc * 32 + 8 * lkg];
                acc[h] = __builtin_amdgcn_mfma_f32_16x16x32_bf16(pf, vf, acc[h], 0, 0, 0);
            }
        }
    }

    // ---- finalize: divide by l_run (lane's rows q'=4*lkg+r)
    float lr[4];
    #pragma unroll
    for (int r = 0; r < 4; ++r) lr[r] = __shfl(l_run, 4 * lkg + r);
    #pragma unroll
    for (int h = 0; h < 2; ++h) {
        int c = h * 16 + lq;
        #pragma unroll
        for (int r = 0; r < 4; ++r) {
            int n = q0 + 16 * wave + 4 * lkg + r;
            y[(size_t)b * 32 * N + (size_t)c * N + n] = acc[h][r] / lr[r];
        }
    }
}

__global__ __launch_bounds__(256) void nl_merge_kernel(const float* __restrict__ e,
    const float* __restrict__ yin, const float* __restrict__ u,
    const float* __restrict__ ww, const float* __restrict__ wb,
    float* __restrict__ out, int N)
{
    __shared__ float sw[64 * 32];
    __shared__ float sb[64];
    int tid = threadIdx.x;
    for (int i = tid; i < 2048; i += 256) sw[i] = ww[i];
    if (tid < 64) sb[tid] = wb[tid];
    __syncthreads();
    int idx = blockIdx.x * 256 + tid;
    int n = idx % N, b = idx / N;
    float yv[32];
    #pragma unroll
    for (int c = 0; c < 32; ++c) yv[c] = yin[(size_t)b * 32 * N + (size_t)c * N + n];
    for (int co = 0; co < 64; ++co) {
        float acc = sb[co];
        #pragma unroll
        for (int c = 0; c < 32; ++c) acc = fmaf(sw[co * 32 + c], yv[c], acc);
        size_t o = (size_t)b * 64 * N + (size_t)co * N + n;
        acc += 2.f * e[o];
        if (u) acc += u[o];
        out[o] = acc;
    }
}

// ===========================================================================
// Deformable conv 3x3 as bf16 MFMA implicit GEMM. Unchanged.
// ===========================================================================
__global__ __launch_bounds__(256) void deform_mfma(const float* __restrict__ x,
    const float* __restrict__ est, const ushort_t* __restrict__ wbf,
    const float* __restrict__ bias, float* __restrict__ out)
{
    const int H = 128, W = 128, HW = 16384;
    const int BS = 296;
    __shared__ ushort_t sB[64 * BS];
    __shared__ float spy[576], spx[576], smk[576];
    int tile = blockIdx.x & 255;
    int b    = blockIdx.x >> 8;
    int p0   = tile * 64;
    int tid  = threadIdx.x;

    const float* eb = est + (size_t)b * 27 * HW;
    for (int i = tid; i < 576; i += 256) {
        int k = i >> 6, j = i & 63;
        int p = p0 + j;
        int yy = p >> 7, xx = p & 127;
        float oy = eb[(size_t)(9 + 2 * k) * HW + p];
        float ox = eb[(size_t)(10 + 2 * k) * HW + p];
        float mv = eb[(size_t)k * HW + p];
        smk[i] = 1.f / (1.f + __expf(-mv));
        spy[i] = (float)(yy + (k / 3) - 1) + oy;
        spx[i] = (float)(xx + (k % 3) - 1) + ox;
    }

    int wave = tid >> 6, lane = tid & 63;
    int co_base = wave * 32;
    int lrow = lane & 15, lkg = lane >> 4;

    f32x4 acc[2][4];
    #pragma unroll
    for (int m2 = 0; m2 < 2; ++m2)
        #pragma unroll
        for (int n2 = 0; n2 < 4; ++n2) acc[m2][n2] = (f32x4){0.f, 0.f, 0.f, 0.f};

    const float* xb = x + (size_t)b * 128 * HW;

    for (int cc = 0; cc < 128; cc += 32) {
        __syncthreads();
        for (int vi = tid; vi < 288 * 64; vi += 256) {
            int px  = vi & 63;
            int row = vi >> 6;
            int cl  = row / 9;
            int tap = row - cl * 9;
            int si  = tap * 64 + px;
            float py = spy[si], qx = spx[si];
            float fy0 = floorf(py), fx0 = floorf(qx);
            float wy = py - fy0, wx = qx - fx0;
            int y0 = (int)fy0, x0 = (int)fx0;
            const float* src = xb + (size_t)(cc + cl) * HW;
            float v = 0.f;
            float w00 = (1.f - wy) * (1.f - wx), w01 = (1.f - wy) * wx;
            float w10 = wy * (1.f - wx),         w11 = wy * wx;
            bool yv0 = (y0 >= 0) && (y0 < H), yv1 = (y0 + 1 >= 0) && (y0 + 1 < H);
            bool xv0 = (x0 >= 0) && (x0 < W), xv1 = (x0 + 1 >= 0) && (x0 + 1 < W);
            if (yv0 && xv0) v = fmaf(w00, src[(size_t)y0 * W + x0], v);
            if (yv0 && xv1) v = fmaf(w01, src[(size_t)y0 * W + x0 + 1], v);
            if (yv1 && xv0) v = fmaf(w10, src[(size_t)(y0 + 1) * W + x0], v);
            if (yv1 && xv1) v = fmaf(w11, src[(size_t)(y0 + 1) * W + x0 + 1], v);
            sB[px * BS + row] = f2bf(v * smk[si]);
        }
        __syncthreads();
        int kbase = cc * 9;
        #pragma unroll
        for (int ks = 0; ks < 9; ++ks) {
            bf16x8 afr[2], bfr[4];
            #pragma unroll
            for (int m2 = 0; m2 < 2; ++m2)
                afr[m2] = *reinterpret_cast<const bf16x8*>(
                    wbf + (size_t)(co_base + m2 * 16 + lrow) * 1152 + kbase + ks * 32 + lkg * 8);
            #pragma unroll
            for (int n2 = 0; n2 < 4; ++n2)
                bfr[n2] = *reinterpret_cast<const bf16x8*>(
                    &sB[(n2 * 16 + lrow) * BS + ks * 32 + lkg * 8]);
            #pragma unroll
            for (int m2 = 0; m2 < 2; ++m2)
                #pragma unroll
                for (int n2 = 0; n2 < 4; ++n2)
                    acc[m2][n2] = __builtin_amdgcn_mfma_f32_16x16x32_bf16(
                        afr[m2], bfr[n2], acc[m2][n2], 0, 0, 0);
        }
    }

    #pragma unroll
    for (int m2 = 0; m2 < 2; ++m2) {
        #pragma unroll
        for (int j = 0; j < 4; ++j) {
            int co = co_base + m2 * 16 + lkg * 4 + j;
            float bb = bias[co];
            #pragma unroll
            for (int n2 = 0; n2 < 4; ++n2) {
                int px = p0 + n2 * 16 + lrow;
                out[((size_t)(b * 128 + co)) * HW + px] = acc[m2][n2][j] + bb;
            }
        }
    }
}

extern "C" void kernel_launch(void* const* d_in, const int* in_sizes, int n_in,
                              void* d_out, int out_size, void* d_ws, size_t ws_size,
                              hipStream_t stream)
{
    const float* x_all     = (const float*)d_in[0];
    const float* ms_fine   = (const float*)d_in[1];
    const float* ms_coarse = (const float*)d_in[2];
    const float* enc_w0 = (const float*)d_in[3];
    const float* enc_b0 = (const float*)d_in[4];
    const float* enc_w1 = (const float*)d_in[5];
    const float* enc_b1 = (const float*)d_in[6];
    const float* nl_tw[2] = { (const float*)d_in[7],  (const float*)d_in[15] };
    const float* nl_tb[2] = { (const float*)d_in[8],  (const float*)d_in[16] };
    const float* nl_pw[2] = { (const float*)d_in[9],  (const float*)d_in[17] };
    const float* nl_pb[2] = { (const float*)d_in[10], (const float*)d_in[18] };
    const float* nl_gw[2] = { (const float*)d_in[11], (const float*)d_in[19] };
    const float* nl_gb[2] = { (const float*)d_in[12], (const float*)d_in[20] };
    const float* nl_ww[2] = { (const float*)d_in[13], (const float*)d_in[21] };
    const float* nl_wb[2] = { (const float*)d_in[14], (const float*)d_in[22] };
    const float* dec_w0 = (const float*)d_in[23];
    const float* dec_b0 = (const float*)d_in[24];
    const float* dec_w1 = (const float*)d_in[25];
    const float* dec_b1 = (const float*)d_in[26];
    const float* off_w  = (const float*)d_in[27];
    const float* off_b  = (const float*)d_in[28];
    const float* dcn_w  = (const float*)d_in[29];
    const float* dcn_b  = (const float*)d_in[30];

    float* ws  = (float*)d_ws;
    float* e0  = ws;
    float* th0 = e0 + 131072;
    float* ph0 = th0 + 65536;
    float* g0  = ph0 + 65536;
    float* y0  = g0 + 65536;
    float* m0  = y0 + 65536;
    float* u0  = m0 + 131072;
    float* e1  = u0 + 524288;
    float* th1 = e1 + 524288;
    float* ph1 = th1 + 262144;
    float* g1  = ph1 + 262144;
    float* y1  = g1 + 262144;
    float* m1  = y1 + 262144;
    float* mot = m1 + 524288;
    float* est = mot + 2097152;
    float* P   = est + 884736;
    float* wt  = P + 2163200;
    float* partial = wt + 36864;
    ushort_t* wbf = (ushort_t*)(partial + 4194304);

    float* out = (float*)d_out;
    const size_t frame = (size_t)2 * 128 * 128 * 128;

    hipMemcpyAsync(out, x_all, frame * sizeof(float), hipMemcpyDeviceToDevice, stream);
    castw_kernel<<<(147456 + 255) / 256, 256, 0, stream>>>(dcn_w, wbf, 147456);

    for (int s = 1; s < 3; ++s) {
        const float* pc = ms_coarse + (size_t)s * 2 * 256 * 64 * 64;
        const float* cc = ms_coarse;
        const float* pf = ms_fine + (size_t)s * frame;
        const float* cf = ms_fine;

        // ---- e0 = lrelu(conv3x3 s2 (pc||cc; 512->64)) : (2,64,32,32)
        conv3x3_gemm<2, 1, 4, true><<<2 * 16 * 16, 256, 0, stream>>>(
            pc, cc, 256, 64, 64, 512, 32, enc_w0, 64, 32, 32, 16, 16, partial);
        reduce_bias_act<<<512, 256, 0, stream>>>(partial, enc_b0, e0, 64, 64, 1024, 16, 1);

        // ---- non-local 0 (N=1024)
        conv1x1x3_kernel<<<8, 256, 0, stream>>>(e0, 1024,
            nl_tw[0], nl_tb[0], nl_pw[0], nl_pb[0], nl_gw[0], nl_gb[0], th0, ph0, g0);
        attn_mfma<<<2 * 32, 128, 0, stream>>>(th0, ph0, g0, y0, 1024);
        nl_merge_kernel<<<8, 256, 0, stream>>>(e0, y0, nullptr, nl_ww[0], nl_wb[0], m0, 1024);

        // ---- u0 = lrelu(deconv(m0)) : (2,64,64,64)
        {
            int total = 128 * 66 * 66;
            dilate_kernel<<<(total + 255) / 256, 256, 0, stream>>>(m0, P, 32, 32, 128, total);
            deconv_w_kernel<<<144, 256, 0, stream>>>(dec_w0, wt, 64);
            conv3x3_gemm<1, 0, 4, false><<<2 * 64 * 4, 256, 0, stream>>>(
                P, P, 64, 66, 66, 64, 16, wt, 64, 64, 64, 64, 4, partial);
            reduce_bias_act<<<2048, 256, 0, stream>>>(partial, dec_b0, u0, 64, 64, 4096, 4, 1);
        }

        // ---- e1 = lrelu(conv3x3 s2 (pf||cf; 256->64)) : (2,64,64,64)
        conv3x3_gemm<2, 1, 4, true><<<2 * 64 * 4, 256, 0, stream>>>(
            pf, cf, 128, 128, 128, 256, 64, enc_w1, 64, 64, 64, 64, 4, partial);
        reduce_bias_act<<<2048, 256, 0, stream>>>(partial, enc_b1, e1, 64, 64, 4096, 4, 1);

        // ---- non-local 1 (N=4096)
        conv1x1x3_kernel<<<32, 256, 0, stream>>>(e1, 4096,
            nl_tw[1], nl_tb[1], nl_pw[1], nl_pb[1], nl_gw[1], nl_gb[1], th1, ph1, g1);
        attn_mfma<<<2 * 128, 128, 0, stream>>>(th1, ph1, g1, y1, 4096);
        nl_merge_kernel<<<32, 256, 0, stream>>>(e1, y1, u0, nl_ww[1], nl_wb[1], m1, 4096);

        // ---- mot = lrelu(deconv(m1)) : (2,64,128,128)
        {
            int total = 128 * 130 * 130;
            dilate_kernel<<<(total + 255) / 256, 256, 0, stream>>>(m1, P, 64, 64, 128, total);
            deconv_w_kernel<<<144, 256, 0, stream>>>(dec_w1, wt, 64);
            conv3x3_gemm<1, 0, 4, false><<<2 * 256 * 2, 256, 0, stream>>>(
                P, P, 64, 130, 130, 64, 32, wt, 64, 128, 128, 256, 2, partial);
            reduce_bias_act<<<8192, 256, 0, stream>>>(partial, dec_b1, mot, 64, 64, 16384, 2, 1);
        }

        // ---- est = conv3x3 s1 (mot; 64->27) : (2,27,128,128)
        conv3x3_gemm<1, 1, 2, true><<<2 * 256 * 2, 256, 0, stream>>>(
            mot, mot, 64, 128, 128, 64, 32, off_w, 27, 128, 128, 256, 2, partial);
        reduce_bias_act<<<3456, 256, 0, stream>>>(partial, off_b, est, 32, 27, 16384, 2, 0);

        // ---- aligned[s] = deform_conv(x_all[s], offset, mask)  [bf16 MFMA]
        deform_mfma<<<512, 256, 0, stream>>>(
            x_all + (size_t)s * frame, est, wbf, dcn_b, out + (size_t)s * frame);
    }
}

// Round 5
// 1405.124 us; speedup vs baseline: 3.7307x; 1.3440x over previous
//
#include <hip/hip_runtime.h>
#include <math.h>

typedef __attribute__((ext_vector_type(8))) short bf16x8;
typedef __attribute__((ext_vector_type(4))) float f32x4;
typedef unsigned short ushort_t;
typedef unsigned int uint_t;

__device__ __forceinline__ float lrelu_f(float x) { return x >= 0.f ? x : 0.01f * x; }

__device__ __forceinline__ ushort_t f2bf(float f) {
    uint_t x = __float_as_uint(f);
    uint_t r = (x + 0x7fffu + ((x >> 16) & 1u)) >> 16;
    return (ushort_t)r;
}

__device__ __forceinline__ uint_t pack_bf16(float lo, float hi) {
    uint_t out;
    asm("v_cvt_pk_bf16_f32 %0, %1, %2" : "=v"(out) : "v"(lo), "v"(hi));
    return out;
}

// ===========================================================================
// Register-tiled implicit-GEMM 3x3 conv (fp32). Unchanged.
// ===========================================================================
#define CONV_CB 8

template<int STRIDE, int PAD, int TCO, bool MASK>
__global__ __launch_bounds__(256) void conv3x3_gemm(
    const float* __restrict__ inA, const float* __restrict__ inB, int CinA,
    int Hin, int Win, int Cin, int Cspan,
    const float* __restrict__ w, int Cout,
    int Hout, int Wout, int tilesPerMap, int ksplit,
    float* __restrict__ part)
{
    constexpr int CO = TCO * 16;
    __shared__ float sw[CONV_CB * 9 * CO];
    int tile = blockIdx.x % tilesPerMap;
    int ks   = (blockIdx.x / tilesPerMap) % ksplit;
    int b    = blockIdx.x / (tilesPerMap * ksplit);
    int tid  = threadIdx.x;
    int tpx  = tid & 15, tco = tid >> 4;
    int co0  = tco * TCO;
    int Npx  = Hout * Wout;

    int   off[4][9];
    float m[4][9];
    #pragma unroll
    for (int v = 0; v < 4; ++v) {
        int p = tile * 64 + tpx + v * 16;
        int oy = p / Wout, ox = p % Wout;
        #pragma unroll
        for (int ky = 0; ky < 3; ++ky) {
            int iy = oy * STRIDE - PAD + ky;
            bool vy = (iy >= 0) && (iy < Hin);
            int iyc = min(max(iy, 0), Hin - 1);
            #pragma unroll
            for (int kx = 0; kx < 3; ++kx) {
                int ix = ox * STRIDE - PAD + kx;
                bool vx = (ix >= 0) && (ix < Win);
                int ixc = min(max(ix, 0), Win - 1);
                off[v][ky * 3 + kx] = (iyc * Win + ixc) * 4;
                if (MASK) m[v][ky * 3 + kx] = (vy && vx) ? 1.f : 0.f;
            }
        }
    }

    float acc[TCO][4];
    #pragma unroll
    for (int u = 0; u < TCO; ++u)
        #pragma unroll
        for (int v = 0; v < 4; ++v) acc[u][v] = 0.f;

    int c0 = ks * Cspan;
    int CinB = Cin - CinA;
    for (int cc = 0; cc < Cspan; cc += CONV_CB) {
        __syncthreads();
        for (int i = tid; i < CONV_CB * 9 * CO; i += 256) {
            int co = i / (CONV_CB * 9);
            int r  = i % (CONV_CB * 9);
            int ci = r / 9, tap = r % 9;
            float wv = 0.f;
            if (co < Cout) wv = w[((size_t)co * Cin + (c0 + cc + ci)) * 9 + tap];
            sw[(ci * 9 + tap) * CO + co] = wv;
        }
        __syncthreads();
        #pragma unroll 1
        for (int ci = 0; ci < CONV_CB; ++ci) {
            int c = c0 + cc + ci;
            const float* src;
            if (c < CinA) src = inA + ((size_t)b * CinA + c) * (size_t)(Hin * Win);
            else          src = inB + ((size_t)b * CinB + (c - CinA)) * (size_t)(Hin * Win);
            const float* wrow = &sw[ci * 9 * CO];
            #pragma unroll
            for (int t = 0; t < 9; ++t) {
                float vals[4];
                #pragma unroll
                for (int v = 0; v < 4; ++v) {
                    float x = *(const float*)((const char*)src + off[v][t]);
                    vals[v] = MASK ? x * m[v][t] : x;
                }
                #pragma unroll
                for (int u = 0; u < TCO; ++u) {
                    float wv = wrow[t * CO + co0 + u];
                    #pragma unroll
                    for (int v = 0; v < 4; ++v)
                        acc[u][v] = fmaf(wv, vals[v], acc[u][v]);
                }
            }
        }
    }

    #pragma unroll
    for (int u = 0; u < TCO; ++u) {
        #pragma unroll
        for (int v = 0; v < 4; ++v) {
            int p = tile * 64 + tpx + v * 16;
            part[(((size_t)ks * 2 + b) * CO + co0 + u) * (size_t)Npx + p] = acc[u][v];
        }
    }
}

__global__ __launch_bounds__(256) void reduce_bias_act(const float* __restrict__ part,
    const float* __restrict__ bias, float* __restrict__ out,
    int CO, int Cout, int Npx, int ksplit, int act)
{
    int idx = blockIdx.x * 256 + threadIdx.x;
    int total = 2 * Cout * Npx;
    if (idx >= total) return;
    int p  = idx % Npx;
    int co = (idx / Npx) % Cout;
    int b  = idx / (Npx * Cout);
    float s = bias[co];
    for (int ks = 0; ks < ksplit; ++ks)
        s += part[(((size_t)ks * 2 + b) * CO + co) * (size_t)Npx + p];
    if (act) s = lrelu_f(s);
    out[((size_t)b * Cout + co) * (size_t)Npx + p] = s;
}

__global__ __launch_bounds__(256) void dilate_kernel(const float* __restrict__ in,
    float* __restrict__ P, int Hin, int Win, int C2, int total)
{
    int idx = blockIdx.x * 256 + threadIdx.x;
    if (idx >= total) return;
    int Wp = 2 * Win + 2, Hp = 2 * Hin + 2;
    int v = idx % Wp, u = (idx / Wp) % Hp;
    int c = idx / (Wp * Hp);
    float val = 0.f;
    if ((u & 1) && (v & 1)) {
        int r = (u - 1) >> 1, q = (v - 1) >> 1;
        if (r < Hin && q < Win) val = in[((size_t)c * Hin + r) * Win + q];
    }
    P[idx] = val;
}

__global__ __launch_bounds__(256) void deconv_w_kernel(const float* __restrict__ w,
    float* __restrict__ wt, int C)
{
    int idx = blockIdx.x * 256 + threadIdx.x;
    if (idx >= C * C * 9) return;
    int tap = idx % 9;
    int i = (idx / 9) % C;
    int o = idx / (9 * C);
    int ky = tap / 3, kx = tap % 3;
    wt[idx] = w[(((size_t)i * C + o) * 9) + (2 - ky) * 3 + (2 - kx)];
}

// dcn weights -> bf16, permuted K: wbf[co][chunk*288 + tap*32 + cl] = w[co][chunk*32+cl][tap]
__global__ __launch_bounds__(256) void castw_perm_kernel(const float* __restrict__ w,
    ushort_t* __restrict__ wbf)
{
    int idx = blockIdx.x * 256 + threadIdx.x;
    if (idx >= 147456) return;
    int co = idx / 1152;
    int r  = idx % 1152;
    int chunk = r / 288;
    int r2 = r % 288;
    int tap = r2 >> 5;
    int cl  = r2 & 31;
    int ci = chunk * 32 + cl;
    wbf[idx] = f2bf(w[(size_t)co * 1152 + ci * 9 + tap]);
}

// NCHW frame [2][128][16384] -> NHWC [2][16384][128], LDS-tiled 32x32
__global__ __launch_bounds__(256) void transpose_nhwc_kernel(const float* __restrict__ x,
    float* __restrict__ xT)
{
    __shared__ float t[32][33];
    int cT = blockIdx.x & 3;
    int pT = (blockIdx.x >> 2) & 511;
    int b  = blockIdx.x >> 11;
    int tx = threadIdx.x & 31, ty = threadIdx.x >> 5;
    const float* src = x + ((size_t)b * 128 + cT * 32) * 16384 + (size_t)pT * 32;
    #pragma unroll
    for (int i = 0; i < 4; ++i)
        t[ty + 8 * i][tx] = src[(size_t)(ty + 8 * i) * 16384 + tx];
    __syncthreads();
    float* dst = xT + ((size_t)b * 16384 + (size_t)pT * 32) * 128 + cT * 32;
    #pragma unroll
    for (int i = 0; i < 4; ++i)
        dst[(size_t)(ty + 8 * i) * 128 + tx] = t[tx][ty + 8 * i];
}

// ---------------------------------------------------------------------------
// Fused 1x1 convs producing th/ph/g (each 64->32) from e (B,64,N).
// ---------------------------------------------------------------------------
__global__ __launch_bounds__(256) void conv1x1x3_kernel(const float* __restrict__ e, int N,
    const float* __restrict__ tw, const float* __restrict__ tb,
    const float* __restrict__ pw, const float* __restrict__ pb,
    const float* __restrict__ gw, const float* __restrict__ gb,
    float* __restrict__ th, float* __restrict__ ph, float* __restrict__ g)
{
    __shared__ float sw[3 * 32 * 64];
    __shared__ float sb[96];
    int tid = threadIdx.x;
    for (int i = tid; i < 2048; i += 256) { sw[i] = tw[i]; sw[2048 + i] = pw[i]; sw[4096 + i] = gw[i]; }
    if (tid < 32) { sb[tid] = tb[tid]; sb[32 + tid] = pb[tid]; sb[64 + tid] = gb[tid]; }
    __syncthreads();
    int idx = blockIdx.x * 256 + tid;
    int n = idx % N, b = idx / N;
    float ein[64];
    const float* ep = e + (size_t)b * 64 * N + n;
    #pragma unroll
    for (int ci = 0; ci < 64; ++ci) ein[ci] = ep[(size_t)ci * N];
    float* outs[3] = { th, ph, g };
    #pragma unroll
    for (int j = 0; j < 3; ++j) {
        float* op = outs[j] + (size_t)b * 32 * N + n;
        for (int cc = 0; cc < 32; ++cc) {
            float acc = sb[j * 32 + cc];
            const float* wr = &sw[j * 2048 + cc * 64];
            #pragma unroll
            for (int ci = 0; ci < 64; ++ci) acc = fmaf(wr[ci], ein[ci], acc);
            op[(size_t)cc * N] = acc;
        }
    }
}

// ===========================================================================
// Flash-style MFMA attention (bf16, fp32 accumulate). Unchanged.
// ===========================================================================
__global__ __launch_bounds__(128) void attn_mfma(const float* __restrict__ th,
    const float* __restrict__ ph, const float* __restrict__ g,
    float* __restrict__ y, int N)
{
    __shared__ ushort_t sK[64 * 40];
    __shared__ ushort_t sV[32 * 72];
    __shared__ ushort_t sP[2][16 * 40];

    int tid  = threadIdx.x;
    int wave = tid >> 6, lane = tid & 63;
    int lq = lane & 15, lkg = lane >> 4;
    int nq = N / 32;
    int b  = blockIdx.x / nq;
    int q0 = (blockIdx.x % nq) * 32;

    const float* thp = th + (size_t)b * 32 * N;
    const float* php = ph + (size_t)b * 32 * N;
    const float* gp  = g  + (size_t)b * 32 * N;

    bf16x8 qf;
    {
        int qg = q0 + 16 * wave + lq;
        #pragma unroll
        for (int j = 0; j < 8; ++j)
            ((ushort_t*)&qf)[j] = f2bf(thp[(size_t)(8 * lkg + j) * N + qg]);
    }

    float m_run = -1e30f, l_run = 0.f;
    f32x4 acc[2];
    acc[0] = (f32x4){0.f, 0.f, 0.f, 0.f};
    acc[1] = (f32x4){0.f, 0.f, 0.f, 0.f};

    int mK = tid & 63;
    int cb = (tid >> 6) * 16;
    int cV = tid >> 2;
    int msg = (tid & 3) * 16;

    for (int m0 = 0; m0 < N; m0 += 64) {
        __syncthreads();
        {
            float kv[16];
            #pragma unroll
            for (int i = 0; i < 16; ++i) kv[i] = php[(size_t)(cb + i) * N + m0 + mK];
            #pragma unroll
            for (int i = 0; i < 8; ++i)
                *(uint_t*)&sK[mK * 40 + cb + 2 * i] = pack_bf16(kv[2 * i], kv[2 * i + 1]);
            float vv[16];
            #pragma unroll
            for (int i = 0; i < 16; ++i) vv[i] = gp[(size_t)cV * N + m0 + msg + i];
            #pragma unroll
            for (int i = 0; i < 8; ++i)
                *(uint_t*)&sV[cV * 72 + msg + 2 * i] = pack_bf16(vv[2 * i], vv[2 * i + 1]);
        }
        __syncthreads();

        f32x4 tf[4];
        #pragma unroll
        for (int f = 0; f < 4; ++f) {
            bf16x8 kf = *(const bf16x8*)&sK[(f * 16 + lq) * 40 + 8 * lkg];
            tf[f] = __builtin_amdgcn_mfma_f32_16x16x32_bf16(kf, qf,
                        (f32x4){0.f, 0.f, 0.f, 0.f}, 0, 0, 0);
        }

        float mx = -1e30f;
        #pragma unroll
        for (int f = 0; f < 4; ++f)
            #pragma unroll
            for (int r = 0; r < 4; ++r) mx = fmaxf(mx, tf[f][r]);
        mx = fmaxf(mx, __shfl_xor(mx, 16));
        mx = fmaxf(mx, __shfl_xor(mx, 32));
        float m_new = fmaxf(m_run, mx);
        float scale = __expf(m_run - m_new);
        float rs = 0.f;
        #pragma unroll
        for (int f = 0; f < 4; ++f)
            #pragma unroll
            for (int r = 0; r < 4; ++r) {
                float p = __expf(tf[f][r] - m_new);
                tf[f][r] = p;
                rs += p;
            }
        rs += __shfl_xor(rs, 16);
        rs += __shfl_xor(rs, 32);
        l_run = l_run * scale + rs;
        m_run = m_new;

        float sc[4];
        #pragma unroll
        for (int r = 0; r < 4; ++r) sc[r] = __shfl(scale, 4 * lkg + r);
        #pragma unroll
        for (int h = 0; h < 2; ++h)
            #pragma unroll
            for (int r = 0; r < 4; ++r) acc[h][r] *= sc[r];

        #pragma unroll
        for (int f = 0; f < 4; ++f) {
            *(uint_t*)&sP[wave][lq * 40 + f * 16 + 4 * lkg]     = pack_bf16(tf[f][0], tf[f][1]);
            *(uint_t*)&sP[wave][lq * 40 + f * 16 + 4 * lkg + 2] = pack_bf16(tf[f][2], tf[f][3]);
        }

        #pragma unroll
        for (int mc = 0; mc < 2; ++mc) {
            bf16x8 pf = *(const bf16x8*)&sP[wave][lq * 40 + mc * 32 + 8 * lkg];
            #pragma unroll
            for (int h = 0; h < 2; ++h) {
                bf16x8 vf = *(const bf16x8*)&sV[(h * 16 + lq) * 72 + mc * 32 + 8 * lkg];
                acc[h] = __builtin_amdgcn_mfma_f32_16x16x32_bf16(pf, vf, acc[h], 0, 0, 0);
            }
        }
    }

    float lr[4];
    #pragma unroll
    for (int r = 0; r < 4; ++r) lr[r] = __shfl(l_run, 4 * lkg + r);
    #pragma unroll
    for (int h = 0; h < 2; ++h) {
        int c = h * 16 + lq;
        #pragma unroll
        for (int r = 0; r < 4; ++r) {
            int n = q0 + 16 * wave + 4 * lkg + r;
            y[(size_t)b * 32 * N + (size_t)c * N + n] = acc[h][r] / lr[r];
        }
    }
}

__global__ __launch_bounds__(256) void nl_merge_kernel(const float* __restrict__ e,
    const float* __restrict__ yin, const float* __restrict__ u,
    const float* __restrict__ ww, const float* __restrict__ wb,
    float* __restrict__ out, int N)
{
    __shared__ float sw[64 * 32];
    __shared__ float sb[64];
    int tid = threadIdx.x;
    for (int i = tid; i < 2048; i += 256) sw[i] = ww[i];
    if (tid < 64) sb[tid] = wb[tid];
    __syncthreads();
    int idx = blockIdx.x * 256 + tid;
    int n = idx % N, b = idx / N;
    float yv[32];
    #pragma unroll
    for (int c = 0; c < 32; ++c) yv[c] = yin[(size_t)b * 32 * N + (size_t)c * N + n];
    for (int co = 0; co < 64; ++co) {
        float acc = sb[co];
        #pragma unroll
        for (int c = 0; c < 32; ++c) acc = fmaf(sw[co * 32 + c], yv[c], acc);
        size_t o = (size_t)b * 64 * N + (size_t)co * N + n;
        acc += 2.f * e[o];
        if (u) acc += u[o];
        out[o] = acc;
    }
}

// ===========================================================================
// Deformable conv v2: NHWC input, float4 corner loads (4 ch/thread-iter),
// tap-major K staging (b64 conflict-free LDS writes), bf16 MFMA GEMM.
// ===========================================================================
__global__ __launch_bounds__(256) void deform_mfma2(const float* __restrict__ xT,
    const float* __restrict__ est, const ushort_t* __restrict__ wbf,
    const float* __restrict__ bias, float* __restrict__ out)
{
    const int H = 128, W = 128, HW = 16384;
    const int BS = 296;
    __shared__ ushort_t sB[64 * BS];
    __shared__ float spy[576], spx[576], smk[576];
    int tile = blockIdx.x & 255;
    int b    = blockIdx.x >> 8;
    int p0   = tile * 64;
    int tid  = threadIdx.x;

    const float* eb = est + (size_t)b * 27 * HW;
    for (int i = tid; i < 576; i += 256) {
        int k = i >> 6, j = i & 63;
        int p = p0 + j;
        int yy = p >> 7, xx = p & 127;
        float oy = eb[(size_t)(9 + 2 * k) * HW + p];
        float ox = eb[(size_t)(10 + 2 * k) * HW + p];
        float mv = eb[(size_t)k * HW + p];
        smk[i] = 1.f / (1.f + __expf(-mv));
        spy[i] = (float)(yy + (k / 3) - 1) + oy;
        spx[i] = (float)(xx + (k % 3) - 1) + ox;
    }

    int wave = tid >> 6, lane = tid & 63;
    int co_base = wave * 32;
    int lrow = lane & 15, lkg = lane >> 4;

    f32x4 acc[2][4];
    #pragma unroll
    for (int m2 = 0; m2 < 2; ++m2)
        #pragma unroll
        for (int n2 = 0; n2 < 4; ++n2) acc[m2][n2] = (f32x4){0.f, 0.f, 0.f, 0.f};

    const float* xb = xT + (size_t)b * HW * 128;

    for (int cc = 0; cc < 128; cc += 32) {
        __syncthreads();
        #pragma unroll 2
        for (int it = 0; it < 18; ++it) {
            int task = it * 256 + tid;
            int cg = task & 7;
            int si = task >> 3;
            float py = spy[si], qx = spx[si], mk = smk[si];
            float fy0 = floorf(py), fx0 = floorf(qx);
            float wy = py - fy0, wx = qx - fx0;
            int y0 = (int)fy0, x0 = (int)fx0;
            int y1 = y0 + 1, x1 = x0 + 1;
            bool yv0 = (y0 >= 0) && (y0 < H), yv1 = (y1 >= 0) && (y1 < H);
            bool xv0 = (x0 >= 0) && (x0 < W), xv1 = (x1 >= 0) && (x1 < W);
            int y0c = min(max(y0, 0), H - 1), y1c = min(max(y1, 0), H - 1);
            int x0c = min(max(x0, 0), W - 1), x1c = min(max(x1, 0), W - 1);
            float w00 = (yv0 && xv0) ? (1.f - wy) * (1.f - wx) * mk : 0.f;
            float w01 = (yv0 && xv1) ? (1.f - wy) * wx * mk : 0.f;
            float w10 = (yv1 && xv0) ? wy * (1.f - wx) * mk : 0.f;
            float w11 = (yv1 && xv1) ? wy * wx * mk : 0.f;
            int chv = (cc >> 2) + cg;   // f32x4 index within pixel
            const f32x4* r0 = (const f32x4*)(xb + (size_t)y0c * W * 128);
            const f32x4* r1 = (const f32x4*)(xb + (size_t)y1c * W * 128);
            f32x4 c00 = r0[x0c * 32 + chv];
            f32x4 c01 = r0[x1c * 32 + chv];
            f32x4 c10 = r1[x0c * 32 + chv];
            f32x4 c11 = r1[x1c * 32 + chv];
            f32x4 v;
            #pragma unroll
            for (int j = 0; j < 4; ++j)
                v[j] = w00 * c00[j] + w01 * c01[j] + w10 * c10[j] + w11 * c11[j];
            int pxl = si & 63, tap = si >> 6;
            uint2 pk;
            pk.x = pack_bf16(v[0], v[1]);
            pk.y = pack_bf16(v[2], v[3]);
            *(uint2*)&sB[pxl * BS + tap * 32 + cg * 4] = pk;
        }
        __syncthreads();
        int kbase = cc * 9;   // = (cc/32)*288
        #pragma unroll
        for (int ks = 0; ks < 9; ++ks) {
            bf16x8 afr[2], bfr[4];
            #pragma unroll
            for (int m2 = 0; m2 < 2; ++m2)
                afr[m2] = *reinterpret_cast<const bf16x8*>(
                    wbf + (size_t)(co_base + m2 * 16 + lrow) * 1152 + kbase + ks * 32 + lkg * 8);
            #pragma unroll
            for (int n2 = 0; n2 < 4; ++n2)
                bfr[n2] = *reinterpret_cast<const bf16x8*>(
                    &sB[(n2 * 16 + lrow) * BS + ks * 32 + lkg * 8]);
            #pragma unroll
            for (int m2 = 0; m2 < 2; ++m2)
                #pragma unroll
                for (int n2 = 0; n2 < 4; ++n2)
                    acc[m2][n2] = __builtin_amdgcn_mfma_f32_16x16x32_bf16(
                        afr[m2], bfr[n2], acc[m2][n2], 0, 0, 0);
        }
    }

    #pragma unroll
    for (int m2 = 0; m2 < 2; ++m2) {
        #pragma unroll
        for (int j = 0; j < 4; ++j) {
            int co = co_base + m2 * 16 + lkg * 4 + j;
            float bb = bias[co];
            #pragma unroll
            for (int n2 = 0; n2 < 4; ++n2) {
                int px = p0 + n2 * 16 + lrow;
                out[((size_t)(b * 128 + co)) * HW + px] = acc[m2][n2][j] + bb;
            }
        }
    }
}

extern "C" void kernel_launch(void* const* d_in, const int* in_sizes, int n_in,
                              void* d_out, int out_size, void* d_ws, size_t ws_size,
                              hipStream_t stream)
{
    const float* x_all     = (const float*)d_in[0];
    const float* ms_fine   = (const float*)d_in[1];
    const float* ms_coarse = (const float*)d_in[2];
    const float* enc_w0 = (const float*)d_in[3];
    const float* enc_b0 = (const float*)d_in[4];
    const float* enc_w1 = (const float*)d_in[5];
    const float* enc_b1 = (const float*)d_in[6];
    const float* nl_tw[2] = { (const float*)d_in[7],  (const float*)d_in[15] };
    const float* nl_tb[2] = { (const float*)d_in[8],  (const float*)d_in[16] };
    const float* nl_pw[2] = { (const float*)d_in[9],  (const float*)d_in[17] };
    const float* nl_pb[2] = { (const float*)d_in[10], (const float*)d_in[18] };
    const float* nl_gw[2] = { (const float*)d_in[11], (const float*)d_in[19] };
    const float* nl_gb[2] = { (const float*)d_in[12], (const float*)d_in[20] };
    const float* nl_ww[2] = { (const float*)d_in[13], (const float*)d_in[21] };
    const float* nl_wb[2] = { (const float*)d_in[14], (const float*)d_in[22] };
    const float* dec_w0 = (const float*)d_in[23];
    const float* dec_b0 = (const float*)d_in[24];
    const float* dec_w1 = (const float*)d_in[25];
    const float* dec_b1 = (const float*)d_in[26];
    const float* off_w  = (const float*)d_in[27];
    const float* off_b  = (const float*)d_in[28];
    const float* dcn_w  = (const float*)d_in[29];
    const float* dcn_b  = (const float*)d_in[30];

    float* ws  = (float*)d_ws;
    float* e0  = ws;
    float* th0 = e0 + 131072;
    float* ph0 = th0 + 65536;
    float* g0  = ph0 + 65536;
    float* y0  = g0 + 65536;
    float* m0  = y0 + 65536;
    float* u0  = m0 + 131072;
    float* e1  = u0 + 524288;
    float* th1 = e1 + 524288;
    float* ph1 = th1 + 262144;
    float* g1  = ph1 + 262144;
    float* y1  = g1 + 262144;
    float* m1  = y1 + 262144;
    float* mot = m1 + 524288;
    float* est = mot + 2097152;
    float* P   = est + 884736;
    float* wt  = P + 2163200;
    float* partial = wt + 36864;                     // 4,194,304 floats (doubles as xT)
    ushort_t* wbf = (ushort_t*)(partial + 4194304);

    float* out = (float*)d_out;
    const size_t frame = (size_t)2 * 128 * 128 * 128;

    hipMemcpyAsync(out, x_all, frame * sizeof(float), hipMemcpyDeviceToDevice, stream);
    castw_perm_kernel<<<(147456 + 255) / 256, 256, 0, stream>>>(dcn_w, wbf);

    for (int s = 1; s < 3; ++s) {
        const float* pc = ms_coarse + (size_t)s * 2 * 256 * 64 * 64;
        const float* cc = ms_coarse;
        const float* pf = ms_fine + (size_t)s * frame;
        const float* cf = ms_fine;

        // ---- e0 = lrelu(conv3x3 s2 (pc||cc; 512->64)) : (2,64,32,32)
        conv3x3_gemm<2, 1, 4, true><<<2 * 16 * 16, 256, 0, stream>>>(
            pc, cc, 256, 64, 64, 512, 32, enc_w0, 64, 32, 32, 16, 16, partial);
        reduce_bias_act<<<512, 256, 0, stream>>>(partial, enc_b0, e0, 64, 64, 1024, 16, 1);

        // ---- non-local 0 (N=1024)
        conv1x1x3_kernel<<<8, 256, 0, stream>>>(e0, 1024,
            nl_tw[0], nl_tb[0], nl_pw[0], nl_pb[0], nl_gw[0], nl_gb[0], th0, ph0, g0);
        attn_mfma<<<2 * 32, 128, 0, stream>>>(th0, ph0, g0, y0, 1024);
        nl_merge_kernel<<<8, 256, 0, stream>>>(e0, y0, nullptr, nl_ww[0], nl_wb[0], m0, 1024);

        // ---- u0 = lrelu(deconv(m0)) : (2,64,64,64)
        {
            int total = 128 * 66 * 66;
            dilate_kernel<<<(total + 255) / 256, 256, 0, stream>>>(m0, P, 32, 32, 128, total);
            deconv_w_kernel<<<144, 256, 0, stream>>>(dec_w0, wt, 64);
            conv3x3_gemm<1, 0, 4, false><<<2 * 64 * 4, 256, 0, stream>>>(
                P, P, 64, 66, 66, 64, 16, wt, 64, 64, 64, 64, 4, partial);
            reduce_bias_act<<<2048, 256, 0, stream>>>(partial, dec_b0, u0, 64, 64, 4096, 4, 1);
        }

        // ---- e1 = lrelu(conv3x3 s2 (pf||cf; 256->64)) : (2,64,64,64)
        conv3x3_gemm<2, 1, 4, true><<<2 * 64 * 4, 256, 0, stream>>>(
            pf, cf, 128, 128, 128, 256, 64, enc_w1, 64, 64, 64, 64, 4, partial);
        reduce_bias_act<<<2048, 256, 0, stream>>>(partial, enc_b1, e1, 64, 64, 4096, 4, 1);

        // ---- non-local 1 (N=4096)
        conv1x1x3_kernel<<<32, 256, 0, stream>>>(e1, 4096,
            nl_tw[1], nl_tb[1], nl_pw[1], nl_pb[1], nl_gw[1], nl_gb[1], th1, ph1, g1);
        attn_mfma<<<2 * 128, 128, 0, stream>>>(th1, ph1, g1, y1, 4096);
        nl_merge_kernel<<<32, 256, 0, stream>>>(e1, y1, u0, nl_ww[1], nl_wb[1], m1, 4096);

        // ---- mot = lrelu(deconv(m1)) : (2,64,128,128)
        {
            int total = 128 * 130 * 130;
            dilate_kernel<<<(total + 255) / 256, 256, 0, stream>>>(m1, P, 64, 64, 128, total);
            deconv_w_kernel<<<144, 256, 0, stream>>>(dec_w1, wt, 64);
            conv3x3_gemm<1, 0, 4, false><<<2 * 256 * 2, 256, 0, stream>>>(
                P, P, 64, 130, 130, 64, 32, wt, 64, 128, 128, 256, 2, partial);
            reduce_bias_act<<<8192, 256, 0, stream>>>(partial, dec_b1, mot, 64, 64, 16384, 2, 1);
        }

        // ---- est = conv3x3 s1 (mot; 64->27) : (2,27,128,128)
        conv3x3_gemm<1, 1, 2, true><<<2 * 256 * 2, 256, 0, stream>>>(
            mot, mot, 64, 128, 128, 64, 32, off_w, 27, 128, 128, 256, 2, partial);
        reduce_bias_act<<<3456, 256, 0, stream>>>(partial, off_b, est, 32, 27, 16384, 2, 0);

        // ---- xT = NHWC(x_all[s]) into partial (free after est), then deform
        transpose_nhwc_kernel<<<4096, 256, 0, stream>>>(x_all + (size_t)s * frame, partial);
        deform_mfma2<<<512, 256, 0, stream>>>(partial, est, wbf, dcn_b, out + (size_t)s * frame);
    }
}

// Round 6
// 759.821 us; speedup vs baseline: 6.8990x; 1.8493x over previous
//
#include <hip/hip_runtime.h>
#include <math.h>

typedef __attribute__((ext_vector_type(8))) short bf16x8;
typedef __attribute__((ext_vector_type(4))) float f32x4;
typedef unsigned short ushort_t;
typedef unsigned int uint_t;

__device__ __forceinline__ float lrelu_f(float x) { return x >= 0.f ? x : 0.01f * x; }

__device__ __forceinline__ ushort_t f2bf(float f) {
    uint_t x = __float_as_uint(f);
    uint_t r = (x + 0x7fffu + ((x >> 16) & 1u)) >> 16;
    return (ushort_t)r;
}

__device__ __forceinline__ uint_t pack_bf16(float lo, float hi) {
    uint_t out;
    asm("v_cvt_pk_bf16_f32 %0, %1, %2" : "=v"(out) : "v"(lo), "v"(hi));
    return out;
}

// ===========================================================================
// Weight prep: w2[co64][K'=tap*Cin+ci] bf16, co padded to 64 with zeros.
// deconv: src w[Cin][Cout][3][3], flipped taps (8-tap) + transposed.
// ===========================================================================
__global__ __launch_bounds__(256) void castw2_kernel(const float* __restrict__ w,
    ushort_t* __restrict__ w2, int Cout, int Cin, int K, int deconv)
{
    int idx = blockIdx.x * 256 + threadIdx.x;
    if (idx >= 64 * K) return;
    int co = idx / K, kp = idx % K;
    int tap = kp / Cin, ci = kp % Cin;
    float val = 0.f;
    if (co < Cout)
        val = deconv ? w[(size_t)(ci * Cout + co) * 9 + (8 - tap)]
                     : w[(size_t)(co * Cin + ci) * 9 + tap];
    w2[idx] = f2bf(val);
}

// ===========================================================================
// bf16 MFMA implicit-GEMM 3x3 conv. Block: 256 thr = 4 waves, 64co x 64px
// tile. K tap-major in 32-ci chunks; im2col chunk staged bf16 in LDS.
// Optional channel-concat input (inA||inB). Writes fp32 partials [ks][b][64][Npx].
// ===========================================================================
template<int STRIDE, int PAD>
__global__ __launch_bounds__(256) void conv3x3_mfma(
    const float* __restrict__ inA, const float* __restrict__ inB, int CinA,
    int Hin, int Win, int Cin,
    const ushort_t* __restrict__ w2, int K,
    int Wout, int Npx, int tilesPerMap, int ksplit, int chunksPerKs,
    float* __restrict__ part)
{
    __shared__ ushort_t sB[64 * 40];   // [px][32+8 pad] bf16
    int tile = blockIdx.x % tilesPerMap;
    int ks   = (blockIdx.x / tilesPerMap) % ksplit;
    int b    = blockIdx.x / (tilesPerMap * ksplit);
    int tid  = threadIdx.x;
    int wave = tid >> 6, lane = tid & 63;
    int lrow = lane & 15, lkg = lane >> 4;
    int px  = tid & 63;
    int cio = wave * 8;                 // 8 channels per thread
    int p   = tile * 64 + px;
    int oy  = p / Wout, ox = p - oy * Wout;
    int HWin = Hin * Win;
    int CinB = Cin - CinA;

    f32x4 acc[4];
    #pragma unroll
    for (int n2 = 0; n2 < 4; ++n2) acc[n2] = (f32x4){0.f, 0.f, 0.f, 0.f};

    for (int cch = 0; cch < chunksPerKs; ++cch) {
        int kk  = (ks * chunksPerKs + cch) * 32;
        int tap = kk / Cin;
        int cib = kk - tap * Cin;
        int ky = tap / 3, kx = tap - ky * 3;
        int iy = oy * STRIDE - PAD + ky;
        int ix = ox * STRIDE - PAD + kx;
        float msk = 1.f;
        int offp;
        if (PAD) {
            bool vld = (iy >= 0) && (iy < Hin) && (ix >= 0) && (ix < Win);
            msk = vld ? 1.f : 0.f;
            int iyc = min(max(iy, 0), Hin - 1), ixc = min(max(ix, 0), Win - 1);
            offp = iyc * Win + ixc;
        } else {
            offp = iy * Win + ix;
        }
        int c = cib + cio;
        const float* src = (c < CinA)
            ? inA + (size_t)(b * CinA + c) * HWin
            : inB + (size_t)(b * CinB + (c - CinA)) * HWin;
        float v[8];
        #pragma unroll
        for (int j = 0; j < 8; ++j) v[j] = src[(size_t)j * HWin + offp];
        if (PAD) {
            #pragma unroll
            for (int j = 0; j < 8; ++j) v[j] *= msk;
        }
        uint4 pk;
        pk.x = pack_bf16(v[0], v[1]);
        pk.y = pack_bf16(v[2], v[3]);
        pk.z = pack_bf16(v[4], v[5]);
        pk.w = pack_bf16(v[6], v[7]);
        __syncthreads();                 // prev MFMA done reading sB
        *(uint4*)&sB[px * 40 + cio] = pk;
        __syncthreads();                 // staging visible

        const ushort_t* wr = w2 + (size_t)(wave * 16 + lrow) * K + kk + lkg * 8;
        bf16x8 afr = *(const bf16x8*)wr;
        #pragma unroll
        for (int n2 = 0; n2 < 4; ++n2) {
            bf16x8 bfr = *(const bf16x8*)&sB[(n2 * 16 + lrow) * 40 + lkg * 8];
            acc[n2] = __builtin_amdgcn_mfma_f32_16x16x32_bf16(afr, bfr, acc[n2], 0, 0, 0);
        }
    }

    #pragma unroll
    for (int n2 = 0; n2 < 4; ++n2) {
        #pragma unroll
        for (int j = 0; j < 4; ++j) {
            int co = wave * 16 + lkg * 4 + j;
            int pp = tile * 64 + n2 * 16 + lrow;
            part[((size_t)(ks * 2 + b) * 64 + co) * (size_t)Npx + pp] = acc[n2][j];
        }
    }
}

// out[b][co][p] = act(bias[co] + sum_ks part[ks][b][co][p]) ; CO = 64 stride
__global__ __launch_bounds__(256) void reduce_bias_act(const float* __restrict__ part,
    const float* __restrict__ bias, float* __restrict__ out,
    int CO, int Cout, int Npx, int ksplit, int act)
{
    int idx = blockIdx.x * 256 + threadIdx.x;
    int total = 2 * Cout * Npx;
    if (idx >= total) return;
    int p  = idx % Npx;
    int co = (idx / Npx) % Cout;
    int b  = idx / (Npx * Cout);
    float s = bias[co];
    for (int ks = 0; ks < ksplit; ++ks)
        s += part[(((size_t)ks * 2 + b) * CO + co) * (size_t)Npx + p];
    if (act) s = lrelu_f(s);
    out[((size_t)b * Cout + co) * (size_t)Npx + p] = s;
}

__global__ __launch_bounds__(256) void dilate_kernel(const float* __restrict__ in,
    float* __restrict__ P, int Hin, int Win, int C2, int total)
{
    int idx = blockIdx.x * 256 + threadIdx.x;
    if (idx >= total) return;
    int Wp = 2 * Win + 2, Hp = 2 * Hin + 2;
    int v = idx % Wp, u = (idx / Wp) % Hp;
    int c = idx / (Wp * Hp);
    float val = 0.f;
    if ((u & 1) && (v & 1)) {
        int r = (u - 1) >> 1, q = (v - 1) >> 1;
        if (r < Hin && q < Win) val = in[((size_t)c * Hin + r) * Win + q];
    }
    P[idx] = val;
}

// dcn weights -> bf16, permuted K: wbf[co][chunk*288 + tap*32 + cl]
__global__ __launch_bounds__(256) void castw_perm_kernel(const float* __restrict__ w,
    ushort_t* __restrict__ wbf)
{
    int idx = blockIdx.x * 256 + threadIdx.x;
    if (idx >= 147456) return;
    int co = idx / 1152;
    int r  = idx % 1152;
    int chunk = r / 288;
    int r2 = r % 288;
    int tap = r2 >> 5;
    int cl  = r2 & 31;
    int ci = chunk * 32 + cl;
    wbf[idx] = f2bf(w[(size_t)co * 1152 + ci * 9 + tap]);
}

// NCHW frame [2][128][16384] -> NHWC [2][16384][128]
__global__ __launch_bounds__(256) void transpose_nhwc_kernel(const float* __restrict__ x,
    float* __restrict__ xT)
{
    __shared__ float t[32][33];
    int cT = blockIdx.x & 3;
    int pT = (blockIdx.x >> 2) & 511;
    int b  = blockIdx.x >> 11;
    int tx = threadIdx.x & 31, ty = threadIdx.x >> 5;
    const float* src = x + ((size_t)b * 128 + cT * 32) * 16384 + (size_t)pT * 32;
    #pragma unroll
    for (int i = 0; i < 4; ++i)
        t[ty + 8 * i][tx] = src[(size_t)(ty + 8 * i) * 16384 + tx];
    __syncthreads();
    float* dst = xT + ((size_t)b * 16384 + (size_t)pT * 32) * 128 + cT * 32;
    #pragma unroll
    for (int i = 0; i < 4; ++i)
        dst[(size_t)(ty + 8 * i) * 128 + tx] = t[tx][ty + 8 * i];
}

// ---------------------------------------------------------------------------
// Fused 1x1 convs producing th/ph/g (each 64->32) from e (B,64,N).
// ---------------------------------------------------------------------------
__global__ __launch_bounds__(256) void conv1x1x3_kernel(const float* __restrict__ e, int N,
    const float* __restrict__ tw, const float* __restrict__ tb,
    const float* __restrict__ pw, const float* __restrict__ pb,
    const float* __restrict__ gw, const float* __restrict__ gb,
    float* __restrict__ th, float* __restrict__ ph, float* __restrict__ g)
{
    __shared__ float sw[3 * 32 * 64];
    __shared__ float sb[96];
    int tid = threadIdx.x;
    for (int i = tid; i < 2048; i += 256) { sw[i] = tw[i]; sw[2048 + i] = pw[i]; sw[4096 + i] = gw[i]; }
    if (tid < 32) { sb[tid] = tb[tid]; sb[32 + tid] = pb[tid]; sb[64 + tid] = gb[tid]; }
    __syncthreads();
    int idx = blockIdx.x * 256 + tid;
    int n = idx % N, b = idx / N;
    float ein[64];
    const float* ep = e + (size_t)b * 64 * N + n;
    #pragma unroll
    for (int ci = 0; ci < 64; ++ci) ein[ci] = ep[(size_t)ci * N];
    float* outs[3] = { th, ph, g };
    #pragma unroll
    for (int j = 0; j < 3; ++j) {
        float* op = outs[j] + (size_t)b * 32 * N + n;
        for (int cc = 0; cc < 32; ++cc) {
            float acc = sb[j * 32 + cc];
            const float* wr = &sw[j * 2048 + cc * 64];
            #pragma unroll
            for (int ci = 0; ci < 64; ++ci) acc = fmaf(wr[ci], ein[ci], acc);
            op[(size_t)cc * N] = acc;
        }
    }
}

// ===========================================================================
// Flash-style MFMA attention (bf16, fp32 accumulate). Unchanged.
// ===========================================================================
__global__ __launch_bounds__(128) void attn_mfma(const float* __restrict__ th,
    const float* __restrict__ ph, const float* __restrict__ g,
    float* __restrict__ y, int N)
{
    __shared__ ushort_t sK[64 * 40];
    __shared__ ushort_t sV[32 * 72];
    __shared__ ushort_t sP[2][16 * 40];

    int tid  = threadIdx.x;
    int wave = tid >> 6, lane = tid & 63;
    int lq = lane & 15, lkg = lane >> 4;
    int nq = N / 32;
    int b  = blockIdx.x / nq;
    int q0 = (blockIdx.x % nq) * 32;

    const float* thp = th + (size_t)b * 32 * N;
    const float* php = ph + (size_t)b * 32 * N;
    const float* gp  = g  + (size_t)b * 32 * N;

    bf16x8 qf;
    {
        int qg = q0 + 16 * wave + lq;
        #pragma unroll
        for (int j = 0; j < 8; ++j)
            ((ushort_t*)&qf)[j] = f2bf(thp[(size_t)(8 * lkg + j) * N + qg]);
    }

    float m_run = -1e30f, l_run = 0.f;
    f32x4 acc[2];
    acc[0] = (f32x4){0.f, 0.f, 0.f, 0.f};
    acc[1] = (f32x4){0.f, 0.f, 0.f, 0.f};

    int mK = tid & 63;
    int cb = (tid >> 6) * 16;
    int cV = tid >> 2;
    int msg = (tid & 3) * 16;

    for (int m0 = 0; m0 < N; m0 += 64) {
        __syncthreads();
        {
            float kv[16];
            #pragma unroll
            for (int i = 0; i < 16; ++i) kv[i] = php[(size_t)(cb + i) * N + m0 + mK];
            #pragma unroll
            for (int i = 0; i < 8; ++i)
                *(uint_t*)&sK[mK * 40 + cb + 2 * i] = pack_bf16(kv[2 * i], kv[2 * i + 1]);
            float vv[16];
            #pragma unroll
            for (int i = 0; i < 16; ++i) vv[i] = gp[(size_t)cV * N + m0 + msg + i];
            #pragma unroll
            for (int i = 0; i < 8; ++i)
                *(uint_t*)&sV[cV * 72 + msg + 2 * i] = pack_bf16(vv[2 * i], vv[2 * i + 1]);
        }
        __syncthreads();

        f32x4 tf[4];
        #pragma unroll
        for (int f = 0; f < 4; ++f) {
            bf16x8 kf = *(const bf16x8*)&sK[(f * 16 + lq) * 40 + 8 * lkg];
            tf[f] = __builtin_amdgcn_mfma_f32_16x16x32_bf16(kf, qf,
                        (f32x4){0.f, 0.f, 0.f, 0.f}, 0, 0, 0);
        }

        float mx = -1e30f;
        #pragma unroll
        for (int f = 0; f < 4; ++f)
            #pragma unroll
            for (int r = 0; r < 4; ++r) mx = fmaxf(mx, tf[f][r]);
        mx = fmaxf(mx, __shfl_xor(mx, 16));
        mx = fmaxf(mx, __shfl_xor(mx, 32));
        float m_new = fmaxf(m_run, mx);
        float scale = __expf(m_run - m_new);
        float rs = 0.f;
        #pragma unroll
        for (int f = 0; f < 4; ++f)
            #pragma unroll
            for (int r = 0; r < 4; ++r) {
                float pv = __expf(tf[f][r] - m_new);
                tf[f][r] = pv;
                rs += pv;
            }
        rs += __shfl_xor(rs, 16);
        rs += __shfl_xor(rs, 32);
        l_run = l_run * scale + rs;
        m_run = m_new;

        float sc[4];
        #pragma unroll
        for (int r = 0; r < 4; ++r) sc[r] = __shfl(scale, 4 * lkg + r);
        #pragma unroll
        for (int h = 0; h < 2; ++h)
            #pragma unroll
            for (int r = 0; r < 4; ++r) acc[h][r] *= sc[r];

        #pragma unroll
        for (int f = 0; f < 4; ++f) {
            *(uint_t*)&sP[wave][lq * 40 + f * 16 + 4 * lkg]     = pack_bf16(tf[f][0], tf[f][1]);
            *(uint_t*)&sP[wave][lq * 40 + f * 16 + 4 * lkg + 2] = pack_bf16(tf[f][2], tf[f][3]);
        }

        #pragma unroll
        for (int mc = 0; mc < 2; ++mc) {
            bf16x8 pf = *(const bf16x8*)&sP[wave][lq * 40 + mc * 32 + 8 * lkg];
            #pragma unroll
            for (int h = 0; h < 2; ++h) {
                bf16x8 vf = *(const bf16x8*)&sV[(h * 16 + lq) * 72 + mc * 32 + 8 * lkg];
                acc[h] = __builtin_amdgcn_mfma_f32_16x16x32_bf16(pf, vf, acc[h], 0, 0, 0);
            }
        }
    }

    float lr[4];
    #pragma unroll
    for (int r = 0; r < 4; ++r) lr[r] = __shfl(l_run, 4 * lkg + r);
    #pragma unroll
    for (int h = 0; h < 2; ++h) {
        int c = h * 16 + lq;
        #pragma unroll
        for (int r = 0; r < 4; ++r) {
            int n = q0 + 16 * wave + 4 * lkg + r;
            y[(size_t)b * 32 * N + (size_t)c * N + n] = acc[h][r] / lr[r];
        }
    }
}

__global__ __launch_bounds__(256) void nl_merge_kernel(const float* __restrict__ e,
    const float* __restrict__ yin, const float* __restrict__ u,
    const float* __restrict__ ww, const float* __restrict__ wb,
    float* __restrict__ out, int N)
{
    __shared__ float sw[64 * 32];
    __shared__ float sb[64];
    int tid = threadIdx.x;
    for (int i = tid; i < 2048; i += 256) sw[i] = ww[i];
    if (tid < 64) sb[tid] = wb[tid];
    __syncthreads();
    int idx = blockIdx.x * 256 + tid;
    int n = idx % N, b = idx / N;
    float yv[32];
    #pragma unroll
    for (int c = 0; c < 32; ++c) yv[c] = yin[(size_t)b * 32 * N + (size_t)c * N + n];
    for (int co = 0; co < 64; ++co) {
        float acc = sb[co];
        #pragma unroll
        for (int c = 0; c < 32; ++c) acc = fmaf(sw[co * 32 + c], yv[c], acc);
        size_t o = (size_t)b * 64 * N + (size_t)co * N + n;
        acc += 2.f * e[o];
        if (u) acc += u[o];
        out[o] = acc;
    }
}

// ===========================================================================
// Deformable conv (NHWC input, float4 corner loads, bf16 MFMA). Unchanged.
// ===========================================================================
__global__ __launch_bounds__(256) void deform_mfma2(const float* __restrict__ xT,
    const float* __restrict__ est, const ushort_t* __restrict__ wbf,
    const float* __restrict__ bias, float* __restrict__ out)
{
    const int H = 128, W = 128, HW = 16384;
    const int BS = 296;
    __shared__ ushort_t sB[64 * BS];
    __shared__ float spy[576], spx[576], smk[576];
    int tile = blockIdx.x & 255;
    int b    = blockIdx.x >> 8;
    int p0   = tile * 64;
    int tid  = threadIdx.x;

    const float* eb = est + (size_t)b * 27 * HW;
    for (int i = tid; i < 576; i += 256) {
        int k = i >> 6, j = i & 63;
        int p = p0 + j;
        int yy = p >> 7, xx = p & 127;
        float oy = eb[(size_t)(9 + 2 * k) * HW + p];
        float ox = eb[(size_t)(10 + 2 * k) * HW + p];
        float mv = eb[(size_t)k * HW + p];
        smk[i] = 1.f / (1.f + __expf(-mv));
        spy[i] = (float)(yy + (k / 3) - 1) + oy;
        spx[i] = (float)(xx + (k % 3) - 1) + ox;
    }

    int wave = tid >> 6, lane = tid & 63;
    int co_base = wave * 32;
    int lrow = lane & 15, lkg = lane >> 4;

    f32x4 acc[2][4];
    #pragma unroll
    for (int m2 = 0; m2 < 2; ++m2)
        #pragma unroll
        for (int n2 = 0; n2 < 4; ++n2) acc[m2][n2] = (f32x4){0.f, 0.f, 0.f, 0.f};

    const float* xb = xT + (size_t)b * HW * 128;

    for (int cc = 0; cc < 128; cc += 32) {
        __syncthreads();
        #pragma unroll 2
        for (int it = 0; it < 18; ++it) {
            int task = it * 256 + tid;
            int cg = task & 7;
            int si = task >> 3;
            float py = spy[si], qx = spx[si], mk = smk[si];
            float fy0 = floorf(py), fx0 = floorf(qx);
            float wy = py - fy0, wx = qx - fx0;
            int y0 = (int)fy0, x0 = (int)fx0;
            int y1 = y0 + 1, x1 = x0 + 1;
            bool yv0 = (y0 >= 0) && (y0 < H), yv1 = (y1 >= 0) && (y1 < H);
            bool xv0 = (x0 >= 0) && (x0 < W), xv1 = (x1 >= 0) && (x1 < W);
            int y0c = min(max(y0, 0), H - 1), y1c = min(max(y1, 0), H - 1);
            int x0c = min(max(x0, 0), W - 1), x1c = min(max(x1, 0), W - 1);
            float w00 = (yv0 && xv0) ? (1.f - wy) * (1.f - wx) * mk : 0.f;
            float w01 = (yv0 && xv1) ? (1.f - wy) * wx * mk : 0.f;
            float w10 = (yv1 && xv0) ? wy * (1.f - wx) * mk : 0.f;
            float w11 = (yv1 && xv1) ? wy * wx * mk : 0.f;
            int chv = (cc >> 2) + cg;
            const f32x4* r0 = (const f32x4*)(xb + (size_t)y0c * W * 128);
            const f32x4* r1 = (const f32x4*)(xb + (size_t)y1c * W * 128);
            f32x4 c00 = r0[x0c * 32 + chv];
            f32x4 c01 = r0[x1c * 32 + chv];
            f32x4 c10 = r1[x0c * 32 + chv];
            f32x4 c11 = r1[x1c * 32 + chv];
            f32x4 v;
            #pragma unroll
            for (int j = 0; j < 4; ++j)
                v[j] = w00 * c00[j] + w01 * c01[j] + w10 * c10[j] + w11 * c11[j];
            int pxl = si & 63, tap = si >> 6;
            uint2 pk;
            pk.x = pack_bf16(v[0], v[1]);
            pk.y = pack_bf16(v[2], v[3]);
            *(uint2*)&sB[pxl * BS + tap * 32 + cg * 4] = pk;
        }
        __syncthreads();
        int kbase = cc * 9;
        #pragma unroll
        for (int ks = 0; ks < 9; ++ks) {
            bf16x8 afr[2], bfr[4];
            #pragma unroll
            for (int m2 = 0; m2 < 2; ++m2)
                afr[m2] = *reinterpret_cast<const bf16x8*>(
                    wbf + (size_t)(co_base + m2 * 16 + lrow) * 1152 + kbase + ks * 32 + lkg * 8);
            #pragma unroll
            for (int n2 = 0; n2 < 4; ++n2)
                bfr[n2] = *reinterpret_cast<const bf16x8*>(
                    &sB[(n2 * 16 + lrow) * BS + ks * 32 + lkg * 8]);
            #pragma unroll
            for (int m2 = 0; m2 < 2; ++m2)
                #pragma unroll
                for (int n2 = 0; n2 < 4; ++n2)
                    acc[m2][n2] = __builtin_amdgcn_mfma_f32_16x16x32_bf16(
                        afr[m2], bfr[n2], acc[m2][n2], 0, 0, 0);
        }
    }

    #pragma unroll
    for (int m2 = 0; m2 < 2; ++m2) {
        #pragma unroll
        for (int j = 0; j < 4; ++j) {
            int co = co_base + m2 * 16 + lkg * 4 + j;
            float bb = bias[co];
            #pragma unroll
            for (int n2 = 0; n2 < 4; ++n2) {
                int px = p0 + n2 * 16 + lrow;
                out[((size_t)(b * 128 + co)) * HW + px] = acc[m2][n2][j] + bb;
            }
        }
    }
}

extern "C" void kernel_launch(void* const* d_in, const int* in_sizes, int n_in,
                              void* d_out, int out_size, void* d_ws, size_t ws_size,
                              hipStream_t stream)
{
    const float* x_all     = (const float*)d_in[0];
    const float* ms_fine   = (const float*)d_in[1];
    const float* ms_coarse = (const float*)d_in[2];
    const float* enc_w0 = (const float*)d_in[3];
    const float* enc_b0 = (const float*)d_in[4];
    const float* enc_w1 = (const float*)d_in[5];
    const float* enc_b1 = (const float*)d_in[6];
    const float* nl_tw[2] = { (const float*)d_in[7],  (const float*)d_in[15] };
    const float* nl_tb[2] = { (const float*)d_in[8],  (const float*)d_in[16] };
    const float* nl_pw[2] = { (const float*)d_in[9],  (const float*)d_in[17] };
    const float* nl_pb[2] = { (const float*)d_in[10], (const float*)d_in[18] };
    const float* nl_gw[2] = { (const float*)d_in[11], (const float*)d_in[19] };
    const float* nl_gb[2] = { (const float*)d_in[12], (const float*)d_in[20] };
    const float* nl_ww[2] = { (const float*)d_in[13], (const float*)d_in[21] };
    const float* nl_wb[2] = { (const float*)d_in[14], (const float*)d_in[22] };
    const float* dec_w0 = (const float*)d_in[23];
    const float* dec_b0 = (const float*)d_in[24];
    const float* dec_w1 = (const float*)d_in[25];
    const float* dec_b1 = (const float*)d_in[26];
    const float* off_w  = (const float*)d_in[27];
    const float* off_b  = (const float*)d_in[28];
    const float* dcn_w  = (const float*)d_in[29];
    const float* dcn_b  = (const float*)d_in[30];

    float* ws  = (float*)d_ws;
    float* e0  = ws;                  // 131072
    float* th0 = e0 + 131072;
    float* ph0 = th0 + 65536;
    float* g0  = ph0 + 65536;
    float* y0  = g0 + 65536;
    float* m0  = y0 + 65536;          // 131072
    float* u0  = m0 + 131072;         // 524288
    float* e1  = u0 + 524288;         // 524288
    float* th1 = e1 + 524288;
    float* ph1 = th1 + 262144;
    float* g1  = ph1 + 262144;
    float* y1  = g1 + 262144;
    float* m1  = y1 + 262144;         // 524288
    float* mot = m1 + 524288;         // 2097152
    float* est = mot + 2097152;       // 884736
    float* P   = est + 884736;        // 2163200 (xT reuses P+partial: 4260352 >= 4194304)
    float* partial = P + 2163200;     // 2097152
    ushort_t* wbf     = (ushort_t*)(partial + 2097152); // dcn: 147456
    ushort_t* w2_enc0 = wbf + 147456;      // 64*4608 = 294912
    ushort_t* w2_enc1 = w2_enc0 + 294912;  // 64*2304 = 147456
    ushort_t* w2_dec0 = w2_enc1 + 147456;  // 64*576 = 36864
    ushort_t* w2_dec1 = w2_dec0 + 36864;
    ushort_t* w2_est  = w2_dec1 + 36864;
    float* xT = P;

    float* out = (float*)d_out;
    const size_t frame = (size_t)2 * 128 * 128 * 128;

    hipMemcpyAsync(out, x_all, frame * sizeof(float), hipMemcpyDeviceToDevice, stream);

    // ---- one-time weight prep (deterministic, graph-safe)
    castw_perm_kernel<<<(147456 + 255) / 256, 256, 0, stream>>>(dcn_w, wbf);
    castw2_kernel<<<(64 * 4608 + 255) / 256, 256, 0, stream>>>(enc_w0, w2_enc0, 64, 512, 4608, 0);
    castw2_kernel<<<(64 * 2304 + 255) / 256, 256, 0, stream>>>(enc_w1, w2_enc1, 64, 256, 2304, 0);
    castw2_kernel<<<(64 * 576 + 255) / 256, 256, 0, stream>>>(dec_w0, w2_dec0, 64, 64, 576, 1);
    castw2_kernel<<<(64 * 576 + 255) / 256, 256, 0, stream>>>(dec_w1, w2_dec1, 64, 64, 576, 1);
    castw2_kernel<<<(64 * 576 + 255) / 256, 256, 0, stream>>>(off_w, w2_est, 27, 64, 576, 0);

    for (int s = 1; s < 3; ++s) {
        const float* pc = ms_coarse + (size_t)s * 2 * 256 * 64 * 64;
        const float* cc = ms_coarse;
        const float* pf = ms_fine + (size_t)s * frame;
        const float* cf = ms_fine;

        // ---- e0 = lrelu(conv3x3 s2 (pc||cc; 512->64)) : (2,64,32,32)
        conv3x3_mfma<2, 1><<<2 * 16 * 16, 256, 0, stream>>>(
            pc, cc, 256, 64, 64, 512, w2_enc0, 4608, 32, 1024, 16, 16, 9, partial);
        reduce_bias_act<<<512, 256, 0, stream>>>(partial, enc_b0, e0, 64, 64, 1024, 16, 1);

        // ---- non-local 0 (N=1024)
        conv1x1x3_kernel<<<8, 256, 0, stream>>>(e0, 1024,
            nl_tw[0], nl_tb[0], nl_pw[0], nl_pb[0], nl_gw[0], nl_gb[0], th0, ph0, g0);
        attn_mfma<<<2 * 32, 128, 0, stream>>>(th0, ph0, g0, y0, 1024);
        nl_merge_kernel<<<8, 256, 0, stream>>>(e0, y0, nullptr, nl_ww[0], nl_wb[0], m0, 1024);

        // ---- u0 = lrelu(deconv(m0)) : (2,64,64,64)
        {
            int total = 128 * 66 * 66;
            dilate_kernel<<<(total + 255) / 256, 256, 0, stream>>>(m0, P, 32, 32, 128, total);
            conv3x3_mfma<1, 0><<<2 * 64 * 3, 256, 0, stream>>>(
                P, P, 64, 66, 66, 64, w2_dec0, 576, 64, 4096, 64, 3, 6, partial);
            reduce_bias_act<<<2048, 256, 0, stream>>>(partial, dec_b0, u0, 64, 64, 4096, 3, 1);
        }

        // ---- e1 = lrelu(conv3x3 s2 (pf||cf; 256->64)) : (2,64,64,64)
        conv3x3_mfma<2, 1><<<2 * 64 * 4, 256, 0, stream>>>(
            pf, cf, 128, 128, 128, 256, w2_enc1, 2304, 64, 4096, 64, 4, 18, partial);
        reduce_bias_act<<<2048, 256, 0, stream>>>(partial, enc_b1, e1, 64, 64, 4096, 4, 1);

        // ---- non-local 1 (N=4096)
        conv1x1x3_kernel<<<32, 256, 0, stream>>>(e1, 4096,
            nl_tw[1], nl_tb[1], nl_pw[1], nl_pb[1], nl_gw[1], nl_gb[1], th1, ph1, g1);
        attn_mfma<<<2 * 128, 128, 0, stream>>>(th1, ph1, g1, y1, 4096);
        nl_merge_kernel<<<32, 256, 0, stream>>>(e1, y1, u0, nl_ww[1], nl_wb[1], m1, 4096);

        // ---- mot = lrelu(deconv(m1)) : (2,64,128,128)
        {
            int total = 128 * 130 * 130;
            dilate_kernel<<<(total + 255) / 256, 256, 0, stream>>>(m1, P, 64, 64, 128, total);
            conv3x3_mfma<1, 0><<<2 * 256 * 1, 256, 0, stream>>>(
                P, P, 64, 130, 130, 64, w2_dec1, 576, 128, 16384, 256, 1, 18, partial);
            reduce_bias_act<<<8192, 256, 0, stream>>>(partial, dec_b1, mot, 64, 64, 16384, 1, 1);
        }

        // ---- est = conv3x3 s1 (mot; 64->27) : (2,27,128,128)
        conv3x3_mfma<1, 1><<<2 * 256 * 1, 256, 0, stream>>>(
            mot, mot, 64, 128, 128, 64, w2_est, 576, 128, 16384, 256, 1, 18, partial);
        reduce_bias_act<<<3456, 256, 0, stream>>>(partial, off_b, est, 64, 27, 16384, 1, 0);

        // ---- xT = NHWC(x_all[s]) into P (dead after mot/est), then deform
        transpose_nhwc_kernel<<<4096, 256, 0, stream>>>(x_all + (size_t)s * frame, xT);
        deform_mfma2<<<512, 256, 0, stream>>>(xT, est, wbf, dcn_b, out + (size_t)s * frame);
    }
}

// Round 7
// 700.177 us; speedup vs baseline: 7.4867x; 1.0852x over previous
//
#include <hip/hip_runtime.h>
#include <math.h>

typedef __attribute__((ext_vector_type(8))) short bf16x8;
typedef __attribute__((ext_vector_type(4))) float f32x4;
typedef unsigned short ushort_t;
typedef unsigned int uint_t;

__device__ __forceinline__ float lrelu_f(float x) { return x >= 0.f ? x : 0.01f * x; }

__device__ __forceinline__ ushort_t f2bf(float f) {
    uint_t x = __float_as_uint(f);
    uint_t r = (x + 0x7fffu + ((x >> 16) & 1u)) >> 16;
    return (ushort_t)r;
}

__device__ __forceinline__ uint_t pack_bf16(float lo, float hi) {
    uint_t out;
    asm("v_cvt_pk_bf16_f32 %0, %1, %2" : "=v"(out) : "v"(lo), "v"(hi));
    return out;
}

// ===========================================================================
// Weight prep: w2[co64][K'=tap*Cin+ci] bf16, co padded to 64 with zeros.
// ===========================================================================
__global__ __launch_bounds__(256) void castw2_kernel(const float* __restrict__ w,
    ushort_t* __restrict__ w2, int Cout, int Cin, int K, int deconv)
{
    int idx = blockIdx.x * 256 + threadIdx.x;
    if (idx >= 64 * K) return;
    int co = idx / K, kp = idx % K;
    int tap = kp / Cin, ci = kp % Cin;
    float val = 0.f;
    if (co < Cout)
        val = deconv ? w[(size_t)(ci * Cout + co) * 9 + (8 - tap)]
                     : w[(size_t)(co * Cin + ci) * 9 + tap];
    w2[idx] = f2bf(val);
}

// ===========================================================================
// bf16 MFMA implicit-GEMM 3x3 conv. Unchanged from round 5.
// ===========================================================================
template<int STRIDE, int PAD>
__global__ __launch_bounds__(256) void conv3x3_mfma(
    const float* __restrict__ inA, const float* __restrict__ inB, int CinA,
    int Hin, int Win, int Cin,
    const ushort_t* __restrict__ w2, int K,
    int Wout, int Npx, int tilesPerMap, int ksplit, int chunksPerKs,
    float* __restrict__ part)
{
    __shared__ ushort_t sB[64 * 40];
    int tile = blockIdx.x % tilesPerMap;
    int ks   = (blockIdx.x / tilesPerMap) % ksplit;
    int b    = blockIdx.x / (tilesPerMap * ksplit);
    int tid  = threadIdx.x;
    int wave = tid >> 6, lane = tid & 63;
    int lrow = lane & 15, lkg = lane >> 4;
    int px  = tid & 63;
    int cio = wave * 8;
    int p   = tile * 64 + px;
    int oy  = p / Wout, ox = p - oy * Wout;
    int HWin = Hin * Win;
    int CinB = Cin - CinA;

    f32x4 acc[4];
    #pragma unroll
    for (int n2 = 0; n2 < 4; ++n2) acc[n2] = (f32x4){0.f, 0.f, 0.f, 0.f};

    for (int cch = 0; cch < chunksPerKs; ++cch) {
        int kk  = (ks * chunksPerKs + cch) * 32;
        int tap = kk / Cin;
        int cib = kk - tap * Cin;
        int ky = tap / 3, kx = tap - ky * 3;
        int iy = oy * STRIDE - PAD + ky;
        int ix = ox * STRIDE - PAD + kx;
        float msk = 1.f;
        int offp;
        if (PAD) {
            bool vld = (iy >= 0) && (iy < Hin) && (ix >= 0) && (ix < Win);
            msk = vld ? 1.f : 0.f;
            int iyc = min(max(iy, 0), Hin - 1), ixc = min(max(ix, 0), Win - 1);
            offp = iyc * Win + ixc;
        } else {
            offp = iy * Win + ix;
        }
        int c = cib + cio;
        const float* src = (c < CinA)
            ? inA + (size_t)(b * CinA + c) * HWin
            : inB + (size_t)(b * CinB + (c - CinA)) * HWin;
        float v[8];
        #pragma unroll
        for (int j = 0; j < 8; ++j) v[j] = src[(size_t)j * HWin + offp];
        if (PAD) {
            #pragma unroll
            for (int j = 0; j < 8; ++j) v[j] *= msk;
        }
        uint4 pk;
        pk.x = pack_bf16(v[0], v[1]);
        pk.y = pack_bf16(v[2], v[3]);
        pk.z = pack_bf16(v[4], v[5]);
        pk.w = pack_bf16(v[6], v[7]);
        __syncthreads();
        *(uint4*)&sB[px * 40 + cio] = pk;
        __syncthreads();

        const ushort_t* wr = w2 + (size_t)(wave * 16 + lrow) * K + kk + lkg * 8;
        bf16x8 afr = *(const bf16x8*)wr;
        #pragma unroll
        for (int n2 = 0; n2 < 4; ++n2) {
            bf16x8 bfr = *(const bf16x8*)&sB[(n2 * 16 + lrow) * 40 + lkg * 8];
            acc[n2] = __builtin_amdgcn_mfma_f32_16x16x32_bf16(afr, bfr, acc[n2], 0, 0, 0);
        }
    }

    #pragma unroll
    for (int n2 = 0; n2 < 4; ++n2) {
        #pragma unroll
        for (int j = 0; j < 4; ++j) {
            int co = wave * 16 + lkg * 4 + j;
            int pp = tile * 64 + n2 * 16 + lrow;
            part[((size_t)(ks * 2 + b) * 64 + co) * (size_t)Npx + pp] = acc[n2][j];
        }
    }
}

__global__ __launch_bounds__(256) void reduce_bias_act(const float* __restrict__ part,
    const float* __restrict__ bias, float* __restrict__ out,
    int CO, int Cout, int Npx, int ksplit, int act)
{
    int idx = blockIdx.x * 256 + threadIdx.x;
    int total = 2 * Cout * Npx;
    if (idx >= total) return;
    int p  = idx % Npx;
    int co = (idx / Npx) % Cout;
    int b  = idx / (Npx * Cout);
    float s = bias[co];
    for (int ks = 0; ks < ksplit; ++ks)
        s += part[(((size_t)ks * 2 + b) * CO + co) * (size_t)Npx + p];
    if (act) s = lrelu_f(s);
    out[((size_t)b * Cout + co) * (size_t)Npx + p] = s;
}

__global__ __launch_bounds__(256) void dilate_kernel(const float* __restrict__ in,
    float* __restrict__ P, int Hin, int Win, int C2, int total)
{
    int idx = blockIdx.x * 256 + threadIdx.x;
    if (idx >= total) return;
    int Wp = 2 * Win + 2, Hp = 2 * Hin + 2;
    int v = idx % Wp, u = (idx / Wp) % Hp;
    int c = idx / (Wp * Hp);
    float val = 0.f;
    if ((u & 1) && (v & 1)) {
        int r = (u - 1) >> 1, q = (v - 1) >> 1;
        if (r < Hin && q < Win) val = in[((size_t)c * Hin + r) * Win + q];
    }
    P[idx] = val;
}

__global__ __launch_bounds__(256) void castw_perm_kernel(const float* __restrict__ w,
    ushort_t* __restrict__ wbf)
{
    int idx = blockIdx.x * 256 + threadIdx.x;
    if (idx >= 147456) return;
    int co = idx / 1152;
    int r  = idx % 1152;
    int chunk = r / 288;
    int r2 = r % 288;
    int tap = r2 >> 5;
    int cl  = r2 & 31;
    int ci = chunk * 32 + cl;
    wbf[idx] = f2bf(w[(size_t)co * 1152 + ci * 9 + tap]);
}

// NCHW frame [2][128][16384] -> NHWC [2][16384][128]
__global__ __launch_bounds__(256) void transpose_nhwc_kernel(const float* __restrict__ x,
    float* __restrict__ xT)
{
    __shared__ float t[32][33];
    int cT = blockIdx.x & 3;
    int pT = (blockIdx.x >> 2) & 511;
    int b  = blockIdx.x >> 11;
    int tx = threadIdx.x & 31, ty = threadIdx.x >> 5;
    const float* src = x + ((size_t)b * 128 + cT * 32) * 16384 + (size_t)pT * 32;
    #pragma unroll
    for (int i = 0; i < 4; ++i)
        t[ty + 8 * i][tx] = src[(size_t)(ty + 8 * i) * 16384 + tx];
    __syncthreads();
    float* dst = xT + ((size_t)b * 16384 + (size_t)pT * 32) * 128 + cT * 32;
    #pragma unroll
    for (int i = 0; i < 4; ++i)
        dst[(size_t)(ty + 8 * i) * 128 + tx] = t[tx][ty + 8 * i];
}

// ---------------------------------------------------------------------------
// Fused 1x1 convs -> bf16 attention operands:
//   thT/phT [b][n][32] bf16 (row-major, 64B rows), gT [b][32][N] bf16.
// ---------------------------------------------------------------------------
__global__ __launch_bounds__(256) void conv1x1x3_bf16(const float* __restrict__ e, int N,
    const float* __restrict__ tw, const float* __restrict__ tb,
    const float* __restrict__ pw, const float* __restrict__ pb,
    const float* __restrict__ gw, const float* __restrict__ gb,
    ushort_t* __restrict__ thT, ushort_t* __restrict__ phT, ushort_t* __restrict__ gT)
{
    __shared__ float sw[3 * 32 * 64];
    __shared__ float sb[96];
    int tid = threadIdx.x;
    for (int i = tid; i < 2048; i += 256) { sw[i] = tw[i]; sw[2048 + i] = pw[i]; sw[4096 + i] = gw[i]; }
    if (tid < 32) { sb[tid] = tb[tid]; sb[32 + tid] = pb[tid]; sb[64 + tid] = gb[tid]; }
    __syncthreads();
    int idx = blockIdx.x * 256 + tid;
    int n = idx % N, b = idx / N;
    float ein[64];
    const float* ep = e + (size_t)b * 64 * N + n;
    #pragma unroll
    for (int ci = 0; ci < 64; ++ci) ein[ci] = ep[(size_t)ci * N];

    float val[32];
    ushort_t* rowOuts[2] = { thT, phT };
    #pragma unroll
    for (int j = 0; j < 2; ++j) {
        #pragma unroll
        for (int cc = 0; cc < 32; ++cc) {
            float acc = sb[j * 32 + cc];
            const float* wr = &sw[j * 2048 + cc * 64];
            #pragma unroll
            for (int ci = 0; ci < 64; ++ci) acc = fmaf(wr[ci], ein[ci], acc);
            val[cc] = acc;
        }
        ushort_t* row = rowOuts[j] + ((size_t)b * N + n) * 32;
        #pragma unroll
        for (int w4 = 0; w4 < 4; ++w4) {
            uint4 pk;
            pk.x = pack_bf16(val[8 * w4 + 0], val[8 * w4 + 1]);
            pk.y = pack_bf16(val[8 * w4 + 2], val[8 * w4 + 3]);
            pk.z = pack_bf16(val[8 * w4 + 4], val[8 * w4 + 5]);
            pk.w = pack_bf16(val[8 * w4 + 6], val[8 * w4 + 7]);
            *(uint4*)(row + 8 * w4) = pk;
        }
    }
    #pragma unroll
    for (int cc = 0; cc < 32; ++cc) {
        float acc = sb[64 + cc];
        const float* wr = &sw[4096 + cc * 64];
        #pragma unroll
        for (int ci = 0; ci < 64; ++ci) acc = fmaf(wr[ci], ein[ci], acc);
        gT[((size_t)b * 32 + cc) * N + n] = f2bf(acc);
    }
}

// ===========================================================================
// Flash split-K MFMA attention, fragments direct from global (L2-resident).
// Block: 256 thr = 4 waves, each wave owns 16 q-rows; grid = B*(N/64)*KVS.
// No __syncthreads (sP is wave-private). Writes unnormalized partials + (m,l).
// ===========================================================================
__global__ __launch_bounds__(256) void attn_flash(const ushort_t* __restrict__ thT,
    const ushort_t* __restrict__ phT, const ushort_t* __restrict__ gT,
    float* __restrict__ partO, float* __restrict__ partML, int N, int KVS)
{
    __shared__ ushort_t sP[4][16 * 40];
    int tid  = threadIdx.x;
    int wave = tid >> 6, lane = tid & 63;
    int lq = lane & 15, lkg = lane >> 4;
    int nqb = N / 64;
    int ks = blockIdx.x % KVS;
    int qb = (blockIdx.x / KVS) % nqb;
    int b  = blockIdx.x / (KVS * nqb);
    int q0w = qb * 64 + wave * 16;
    int chunk = N / KVS;
    int m_start = ks * chunk;

    bf16x8 qf = *(const bf16x8*)(thT + ((size_t)b * N + q0w + lq) * 32 + 8 * lkg);

    float m_run = -1e30f, l_run = 0.f;
    f32x4 acc[2];
    acc[0] = (f32x4){0.f, 0.f, 0.f, 0.f};
    acc[1] = (f32x4){0.f, 0.f, 0.f, 0.f};

    for (int m0 = m_start; m0 < m_start + chunk; m0 += 64) {
        // QK^T: T[m][q]; lane: q=lq, m=f*16+4*lkg+r
        f32x4 tf[4];
        #pragma unroll
        for (int f = 0; f < 4; ++f) {
            bf16x8 kf = *(const bf16x8*)(phT + ((size_t)b * N + m0 + f * 16 + lq) * 32 + 8 * lkg);
            tf[f] = __builtin_amdgcn_mfma_f32_16x16x32_bf16(kf, qf,
                        (f32x4){0.f, 0.f, 0.f, 0.f}, 0, 0, 0);
        }

        float mx = -1e30f;
        #pragma unroll
        for (int f = 0; f < 4; ++f)
            #pragma unroll
            for (int r = 0; r < 4; ++r) mx = fmaxf(mx, tf[f][r]);
        mx = fmaxf(mx, __shfl_xor(mx, 16));
        mx = fmaxf(mx, __shfl_xor(mx, 32));
        float m_new = fmaxf(m_run, mx);
        float scale = __expf(m_run - m_new);
        float rs = 0.f;
        #pragma unroll
        for (int f = 0; f < 4; ++f)
            #pragma unroll
            for (int r = 0; r < 4; ++r) {
                float pv = __expf(tf[f][r] - m_new);
                tf[f][r] = pv;
                rs += pv;
            }
        rs += __shfl_xor(rs, 16);
        rs += __shfl_xor(rs, 32);
        l_run = l_run * scale + rs;
        m_run = m_new;

        float sc[4];
        #pragma unroll
        for (int r = 0; r < 4; ++r) sc[r] = __shfl(scale, 4 * lkg + r);
        #pragma unroll
        for (int h = 0; h < 2; ++h)
            #pragma unroll
            for (int r = 0; r < 4; ++r) acc[h][r] *= sc[r];

        #pragma unroll
        for (int f = 0; f < 4; ++f) {
            *(uint_t*)&sP[wave][lq * 40 + f * 16 + 4 * lkg]     = pack_bf16(tf[f][0], tf[f][1]);
            *(uint_t*)&sP[wave][lq * 40 + f * 16 + 4 * lkg + 2] = pack_bf16(tf[f][2], tf[f][3]);
        }

        #pragma unroll
        for (int mc = 0; mc < 2; ++mc) {
            bf16x8 pf = *(const bf16x8*)&sP[wave][lq * 40 + mc * 32 + 8 * lkg];
            #pragma unroll
            for (int h = 0; h < 2; ++h) {
                bf16x8 vf = *(const bf16x8*)(gT + ((size_t)b * 32 + h * 16 + lq) * N
                                             + m0 + mc * 32 + 8 * lkg);
                acc[h] = __builtin_amdgcn_mfma_f32_16x16x32_bf16(pf, vf, acc[h], 0, 0, 0);
            }
        }
    }

    // partO[ks][b][q][c], partML[ks][b][q][2]
    #pragma unroll
    for (int h = 0; h < 2; ++h) {
        #pragma unroll
        for (int r = 0; r < 4; ++r) {
            int q = q0w + 4 * lkg + r;
            partO[(((size_t)ks * 2 + b) * N + q) * 32 + h * 16 + lq] = acc[h][r];
        }
    }
    if (lane < 16) {
        size_t mlo = (((size_t)ks * 2 + b) * N + q0w + lq) * 2;
        partML[mlo]     = m_run;
        partML[mlo + 1] = l_run;
    }
}

// Combine KVS flash partials -> y[b][c][n] fp32.
__global__ __launch_bounds__(256) void attn_merge(const float* __restrict__ partO,
    const float* __restrict__ partML, float* __restrict__ y, int N, int KVS)
{
    int idx = blockIdx.x * 256 + threadIdx.x;
    if (idx >= 2 * N) return;
    int n = idx % N, b = idx / N;
    float mstar = -1e30f;
    for (int ks = 0; ks < KVS; ++ks)
        mstar = fmaxf(mstar, partML[(((size_t)ks * 2 + b) * N + n) * 2]);
    float denom = 0.f;
    float o[32];
    #pragma unroll
    for (int c = 0; c < 32; ++c) o[c] = 0.f;
    for (int ks = 0; ks < KVS; ++ks) {
        size_t mlo = (((size_t)ks * 2 + b) * N + n) * 2;
        float w = __expf(partML[mlo] - mstar);
        denom += w * partML[mlo + 1];
        const f32x4* op = (const f32x4*)(partO + (((size_t)ks * 2 + b) * N + n) * 32);
        #pragma unroll
        for (int j = 0; j < 8; ++j) {
            f32x4 v = op[j];
            #pragma unroll
            for (int t = 0; t < 4; ++t) o[4 * j + t] = fmaf(w, v[t], o[4 * j + t]);
        }
    }
    float inv = 1.f / denom;
    #pragma unroll
    for (int c = 0; c < 32; ++c)
        y[((size_t)b * 32 + c) * N + n] = o[c] * inv;
}

__global__ __launch_bounds__(256) void nl_merge_kernel(const float* __restrict__ e,
    const float* __restrict__ yin, const float* __restrict__ u,
    const float* __restrict__ ww, const float* __restrict__ wb,
    float* __restrict__ out, int N)
{
    __shared__ float sw[64 * 32];
    __shared__ float sb[64];
    int tid = threadIdx.x;
    for (int i = tid; i < 2048; i += 256) sw[i] = ww[i];
    if (tid < 64) sb[tid] = wb[tid];
    __syncthreads();
    int idx = blockIdx.x * 256 + tid;
    int n = idx % N, b = idx / N;
    float yv[32];
    #pragma unroll
    for (int c = 0; c < 32; ++c) yv[c] = yin[(size_t)b * 32 * N + (size_t)c * N + n];
    for (int co = 0; co < 64; ++co) {
        float acc = sb[co];
        #pragma unroll
        for (int c = 0; c < 32; ++c) acc = fmaf(sw[co * 32 + c], yv[c], acc);
        size_t o = (size_t)b * 64 * N + (size_t)co * N + n;
        acc += 2.f * e[o];
        if (u) acc += u[o];
        out[o] = acc;
    }
}

// ===========================================================================
// Deformable conv (NHWC input, float4 corner loads, bf16 MFMA). Unchanged.
// ===========================================================================
__global__ __launch_bounds__(256) void deform_mfma2(const float* __restrict__ xT,
    const float* __restrict__ est, const ushort_t* __restrict__ wbf,
    const float* __restrict__ bias, float* __restrict__ out)
{
    const int H = 128, W = 128, HW = 16384;
    const int BS = 296;
    __shared__ ushort_t sB[64 * BS];
    __shared__ float spy[576], spx[576], smk[576];
    int tile = blockIdx.x & 255;
    int b    = blockIdx.x >> 8;
    int p0   = tile * 64;
    int tid  = threadIdx.x;

    const float* eb = est + (size_t)b * 27 * HW;
    for (int i = tid; i < 576; i += 256) {
        int k = i >> 6, j = i & 63;
        int p = p0 + j;
        int yy = p >> 7, xx = p & 127;
        float oy = eb[(size_t)(9 + 2 * k) * HW + p];
        float ox = eb[(size_t)(10 + 2 * k) * HW + p];
        float mv = eb[(size_t)k * HW + p];
        smk[i] = 1.f / (1.f + __expf(-mv));
        spy[i] = (float)(yy + (k / 3) - 1) + oy;
        spx[i] = (float)(xx + (k % 3) - 1) + ox;
    }

    int wave = tid >> 6, lane = tid & 63;
    int co_base = wave * 32;
    int lrow = lane & 15, lkg = lane >> 4;

    f32x4 acc[2][4];
    #pragma unroll
    for (int m2 = 0; m2 < 2; ++m2)
        #pragma unroll
        for (int n2 = 0; n2 < 4; ++n2) acc[m2][n2] = (f32x4){0.f, 0.f, 0.f, 0.f};

    const float* xb = xT + (size_t)b * HW * 128;

    for (int cc = 0; cc < 128; cc += 32) {
        __syncthreads();
        #pragma unroll 2
        for (int it = 0; it < 18; ++it) {
            int task = it * 256 + tid;
            int cg = task & 7;
            int si = task >> 3;
            float py = spy[si], qx = spx[si], mk = smk[si];
            float fy0 = floorf(py), fx0 = floorf(qx);
            float wy = py - fy0, wx = qx - fx0;
            int y0 = (int)fy0, x0 = (int)fx0;
            int y1 = y0 + 1, x1 = x0 + 1;
            bool yv0 = (y0 >= 0) && (y0 < H), yv1 = (y1 >= 0) && (y1 < H);
            bool xv0 = (x0 >= 0) && (x0 < W), xv1 = (x1 >= 0) && (x1 < W);
            int y0c = min(max(y0, 0), H - 1), y1c = min(max(y1, 0), H - 1);
            int x0c = min(max(x0, 0), W - 1), x1c = min(max(x1, 0), W - 1);
            float w00 = (yv0 && xv0) ? (1.f - wy) * (1.f - wx) * mk : 0.f;
            float w01 = (yv0 && xv1) ? (1.f - wy) * wx * mk : 0.f;
            float w10 = (yv1 && xv0) ? wy * (1.f - wx) * mk : 0.f;
            float w11 = (yv1 && xv1) ? wy * wx * mk : 0.f;
            int chv = (cc >> 2) + cg;
            const f32x4* r0 = (const f32x4*)(xb + (size_t)y0c * W * 128);
            const f32x4* r1 = (const f32x4*)(xb + (size_t)y1c * W * 128);
            f32x4 c00 = r0[x0c * 32 + chv];
            f32x4 c01 = r0[x1c * 32 + chv];
            f32x4 c10 = r1[x0c * 32 + chv];
            f32x4 c11 = r1[x1c * 32 + chv];
            f32x4 v;
            #pragma unroll
            for (int j = 0; j < 4; ++j)
                v[j] = w00 * c00[j] + w01 * c01[j] + w10 * c10[j] + w11 * c11[j];
            int pxl = si & 63, tap = si >> 6;
            uint2 pk;
            pk.x = pack_bf16(v[0], v[1]);
            pk.y = pack_bf16(v[2], v[3]);
            *(uint2*)&sB[pxl * BS + tap * 32 + cg * 4] = pk;
        }
        __syncthreads();
        int kbase = cc * 9;
        #pragma unroll
        for (int ks = 0; ks < 9; ++ks) {
            bf16x8 afr[2], bfr[4];
            #pragma unroll
            for (int m2 = 0; m2 < 2; ++m2)
                afr[m2] = *reinterpret_cast<const bf16x8*>(
                    wbf + (size_t)(co_base + m2 * 16 + lrow) * 1152 + kbase + ks * 32 + lkg * 8);
            #pragma unroll
            for (int n2 = 0; n2 < 4; ++n2)
                bfr[n2] = *reinterpret_cast<const bf16x8*>(
                    &sB[(n2 * 16 + lrow) * BS + ks * 32 + lkg * 8]);
            #pragma unroll
            for (int m2 = 0; m2 < 2; ++m2)
                #pragma unroll
                for (int n2 = 0; n2 < 4; ++n2)
                    acc[m2][n2] = __builtin_amdgcn_mfma_f32_16x16x32_bf16(
                        afr[m2], bfr[n2], acc[m2][n2], 0, 0, 0);
        }
    }

    #pragma unroll
    for (int m2 = 0; m2 < 2; ++m2) {
        #pragma unroll
        for (int j = 0; j < 4; ++j) {
            int co = co_base + m2 * 16 + lkg * 4 + j;
            float bb = bias[co];
            #pragma unroll
            for (int n2 = 0; n2 < 4; ++n2) {
                int px = p0 + n2 * 16 + lrow;
                out[((size_t)(b * 128 + co)) * HW + px] = acc[m2][n2][j] + bb;
            }
        }
    }
}

extern "C" void kernel_launch(void* const* d_in, const int* in_sizes, int n_in,
                              void* d_out, int out_size, void* d_ws, size_t ws_size,
                              hipStream_t stream)
{
    const float* x_all     = (const float*)d_in[0];
    const float* ms_fine   = (const float*)d_in[1];
    const float* ms_coarse = (const float*)d_in[2];
    const float* enc_w0 = (const float*)d_in[3];
    const float* enc_b0 = (const float*)d_in[4];
    const float* enc_w1 = (const float*)d_in[5];
    const float* enc_b1 = (const float*)d_in[6];
    const float* nl_tw[2] = { (const float*)d_in[7],  (const float*)d_in[15] };
    const float* nl_tb[2] = { (const float*)d_in[8],  (const float*)d_in[16] };
    const float* nl_pw[2] = { (const float*)d_in[9],  (const float*)d_in[17] };
    const float* nl_pb[2] = { (const float*)d_in[10], (const float*)d_in[18] };
    const float* nl_gw[2] = { (const float*)d_in[11], (const float*)d_in[19] };
    const float* nl_gb[2] = { (const float*)d_in[12], (const float*)d_in[20] };
    const float* nl_ww[2] = { (const float*)d_in[13], (const float*)d_in[21] };
    const float* nl_wb[2] = { (const float*)d_in[14], (const float*)d_in[22] };
    const float* dec_w0 = (const float*)d_in[23];
    const float* dec_b0 = (const float*)d_in[24];
    const float* dec_w1 = (const float*)d_in[25];
    const float* dec_b1 = (const float*)d_in[26];
    const float* off_w  = (const float*)d_in[27];
    const float* off_b  = (const float*)d_in[28];
    const float* dcn_w  = (const float*)d_in[29];
    const float* dcn_b  = (const float*)d_in[30];

    float* ws  = (float*)d_ws;
    float* e0  = ws;                  // 131072
    float* th0 = e0 + 131072;         // (bf16 slots now)
    float* ph0 = th0 + 65536;
    float* g0  = ph0 + 65536;
    float* y0  = g0 + 65536;
    float* m0  = y0 + 65536;
    float* u0  = m0 + 131072;
    float* e1  = u0 + 524288;
    float* th1 = e1 + 524288;
    float* ph1 = th1 + 262144;
    float* g1  = ph1 + 262144;
    float* y1  = g1 + 262144;
    float* m1  = y1 + 262144;
    float* mot = m1 + 524288;
    float* est = mot + 2097152;
    float* P   = est + 884736;        // xT reuses P+partial
    float* partial = P + 2163200;     // 2097152 floats (also attn partO)
    ushort_t* wbf     = (ushort_t*)(partial + 2097152);
    ushort_t* w2_enc0 = wbf + 147456;
    ushort_t* w2_enc1 = w2_enc0 + 294912;
    ushort_t* w2_dec0 = w2_enc1 + 147456;
    ushort_t* w2_dec1 = w2_dec0 + 36864;
    ushort_t* w2_est  = w2_dec1 + 36864;
    float* partML = (float*)(w2_est + 36864);   // 131072 floats
    float* xT = P;

    ushort_t* thT0 = (ushort_t*)th0;
    ushort_t* phT0 = (ushort_t*)ph0;
    ushort_t* gT0  = (ushort_t*)g0;
    ushort_t* thT1 = (ushort_t*)th1;
    ushort_t* phT1 = (ushort_t*)ph1;
    ushort_t* gT1  = (ushort_t*)g1;

    float* out = (float*)d_out;
    const size_t frame = (size_t)2 * 128 * 128 * 128;

    hipMemcpyAsync(out, x_all, frame * sizeof(float), hipMemcpyDeviceToDevice, stream);

    castw_perm_kernel<<<(147456 + 255) / 256, 256, 0, stream>>>(dcn_w, wbf);
    castw2_kernel<<<(64 * 4608 + 255) / 256, 256, 0, stream>>>(enc_w0, w2_enc0, 64, 512, 4608, 0);
    castw2_kernel<<<(64 * 2304 + 255) / 256, 256, 0, stream>>>(enc_w1, w2_enc1, 64, 256, 2304, 0);
    castw2_kernel<<<(64 * 576 + 255) / 256, 256, 0, stream>>>(dec_w0, w2_dec0, 64, 64, 576, 1);
    castw2_kernel<<<(64 * 576 + 255) / 256, 256, 0, stream>>>(dec_w1, w2_dec1, 64, 64, 576, 1);
    castw2_kernel<<<(64 * 576 + 255) / 256, 256, 0, stream>>>(off_w, w2_est, 27, 64, 576, 0);

    for (int s = 1; s < 3; ++s) {
        const float* pc = ms_coarse + (size_t)s * 2 * 256 * 64 * 64;
        const float* cc = ms_coarse;
        const float* pf = ms_fine + (size_t)s * frame;
        const float* cf = ms_fine;

        // ---- e0 = lrelu(conv3x3 s2 (pc||cc; 512->64)) : (2,64,32,32)
        conv3x3_mfma<2, 1><<<2 * 16 * 16, 256, 0, stream>>>(
            pc, cc, 256, 64, 64, 512, w2_enc0, 4608, 32, 1024, 16, 16, 9, partial);
        reduce_bias_act<<<512, 256, 0, stream>>>(partial, enc_b0, e0, 64, 64, 1024, 16, 1);

        // ---- non-local 0 (N=1024, KVS=4)
        conv1x1x3_bf16<<<8, 256, 0, stream>>>(e0, 1024,
            nl_tw[0], nl_tb[0], nl_pw[0], nl_pb[0], nl_gw[0], nl_gb[0], thT0, phT0, gT0);
        attn_flash<<<2 * 16 * 4, 256, 0, stream>>>(thT0, phT0, gT0, partial, partML, 1024, 4);
        attn_merge<<<(2 * 1024 + 255) / 256, 256, 0, stream>>>(partial, partML, y0, 1024, 4);
        nl_merge_kernel<<<8, 256, 0, stream>>>(e0, y0, nullptr, nl_ww[0], nl_wb[0], m0, 1024);

        // ---- u0 = lrelu(deconv(m0)) : (2,64,64,64)
        {
            int total = 128 * 66 * 66;
            dilate_kernel<<<(total + 255) / 256, 256, 0, stream>>>(m0, P, 32, 32, 128, total);
            conv3x3_mfma<1, 0><<<2 * 64 * 3, 256, 0, stream>>>(
                P, P, 64, 66, 66, 64, w2_dec0, 576, 64, 4096, 64, 3, 6, partial);
            reduce_bias_act<<<2048, 256, 0, stream>>>(partial, dec_b0, u0, 64, 64, 4096, 3, 1);
        }

        // ---- e1 = lrelu(conv3x3 s2 (pf||cf; 256->64)) : (2,64,64,64)
        conv3x3_mfma<2, 1><<<2 * 64 * 4, 256, 0, stream>>>(
            pf, cf, 128, 128, 128, 256, w2_enc1, 2304, 64, 4096, 64, 4, 18, partial);
        reduce_bias_act<<<2048, 256, 0, stream>>>(partial, enc_b1, e1, 64, 64, 4096, 4, 1);

        // ---- non-local 1 (N=4096, KVS=8)
        conv1x1x3_bf16<<<32, 256, 0, stream>>>(e1, 4096,
            nl_tw[1], nl_tb[1], nl_pw[1], nl_pb[1], nl_gw[1], nl_gb[1], thT1, phT1, gT1);
        attn_flash<<<2 * 64 * 8, 256, 0, stream>>>(thT1, phT1, gT1, partial, partML, 4096, 8);
        attn_merge<<<(2 * 4096 + 255) / 256, 256, 0, stream>>>(partial, partML, y1, 4096, 8);
        nl_merge_kernel<<<32, 256, 0, stream>>>(e1, y1, u0, nl_ww[1], nl_wb[1], m1, 4096);

        // ---- mot = lrelu(deconv(m1)) : (2,64,128,128)
        {
            int total = 128 * 130 * 130;
            dilate_kernel<<<(total + 255) / 256, 256, 0, stream>>>(m1, P, 64, 64, 128, total);
            conv3x3_mfma<1, 0><<<2 * 256 * 1, 256, 0, stream>>>(
                P, P, 64, 130, 130, 64, w2_dec1, 576, 128, 16384, 256, 1, 18, partial);
            reduce_bias_act<<<8192, 256, 0, stream>>>(partial, dec_b1, mot, 64, 64, 16384, 1, 1);
        }

        // ---- est = conv3x3 s1 (mot; 64->27) : (2,27,128,128)
        conv3x3_mfma<1, 1><<<2 * 256 * 1, 256, 0, stream>>>(
            mot, mot, 64, 128, 128, 64, w2_est, 576, 128, 16384, 256, 1, 18, partial);
        reduce_bias_act<<<3456, 256, 0, stream>>>(partial, off_b, est, 64, 27, 16384, 1, 0);

        // ---- xT = NHWC(x_all[s]), then deform
        transpose_nhwc_kernel<<<4096, 256, 0, stream>>>(x_all + (size_t)s * frame, xT);
        deform_mfma2<<<512, 256, 0, stream>>>(xT, est, wbf, dcn_b, out + (size_t)s * frame);
    }
}

// Round 8
// 549.409 us; speedup vs baseline: 9.5412x; 1.2744x over previous
//
#include <hip/hip_runtime.h>
#include <math.h>

typedef __attribute__((ext_vector_type(8))) short bf16x8;
typedef __attribute__((ext_vector_type(4))) float f32x4;
typedef unsigned short ushort_t;
typedef unsigned int uint_t;

__device__ __forceinline__ float lrelu_f(float x) { return x >= 0.f ? x : 0.01f * x; }

__device__ __forceinline__ ushort_t f2bf(float f) {
    uint_t x = __float_as_uint(f);
    uint_t r = (x + 0x7fffu + ((x >> 16) & 1u)) >> 16;
    return (ushort_t)r;
}

__device__ __forceinline__ uint_t pack_bf16(float lo, float hi) {
    uint_t out;
    asm("v_cvt_pk_bf16_f32 %0, %1, %2" : "=v"(out) : "v"(lo), "v"(hi));
    return out;
}

// ===========================================================================
// Weight prep: w2[co64][K'=tap*Cin+ci] bf16, co padded to 64 with zeros.
// ===========================================================================
__global__ __launch_bounds__(256) void castw2_kernel(const float* __restrict__ w,
    ushort_t* __restrict__ w2, int Cout, int Cin, int K, int deconv)
{
    int idx = blockIdx.x * 256 + threadIdx.x;
    if (idx >= 64 * K) return;
    int co = idx / K, kp = idx % K;
    int tap = kp / Cin, ci = kp % Cin;
    float val = 0.f;
    if (co < Cout)
        val = deconv ? w[(size_t)(ci * Cout + co) * 9 + (8 - tap)]
                     : w[(size_t)(co * Cin + ci) * 9 + tap];
    w2[idx] = f2bf(val);
}

// ===========================================================================
// bf16 MFMA implicit-GEMM 3x3 conv. If bias!=nullptr (requires ksplit==1):
// fused epilogue writes act(acc+bias) directly to outDirect[b][CoutStore][Npx].
// ===========================================================================
template<int STRIDE, int PAD>
__global__ __launch_bounds__(256) void conv3x3_mfma(
    const float* __restrict__ inA, const float* __restrict__ inB, int CinA,
    int Hin, int Win, int Cin,
    const ushort_t* __restrict__ w2, int K,
    int Wout, int Npx, int tilesPerMap, int ksplit, int chunksPerKs,
    float* __restrict__ part,
    const float* __restrict__ bias, int act, int CoutStore, float* __restrict__ outDirect)
{
    __shared__ ushort_t sB[64 * 40];
    int tile = blockIdx.x % tilesPerMap;
    int ks   = (blockIdx.x / tilesPerMap) % ksplit;
    int b    = blockIdx.x / (tilesPerMap * ksplit);
    int tid  = threadIdx.x;
    int wave = tid >> 6, lane = tid & 63;
    int lrow = lane & 15, lkg = lane >> 4;
    int px  = tid & 63;
    int cio = wave * 8;
    int p   = tile * 64 + px;
    int oy  = p / Wout, ox = p - oy * Wout;
    int HWin = Hin * Win;
    int CinB = Cin - CinA;

    f32x4 acc[4];
    #pragma unroll
    for (int n2 = 0; n2 < 4; ++n2) acc[n2] = (f32x4){0.f, 0.f, 0.f, 0.f};

    for (int cch = 0; cch < chunksPerKs; ++cch) {
        int kk  = (ks * chunksPerKs + cch) * 32;
        int tap = kk / Cin;
        int cib = kk - tap * Cin;
        int ky = tap / 3, kx = tap - ky * 3;
        int iy = oy * STRIDE - PAD + ky;
        int ix = ox * STRIDE - PAD + kx;
        float msk = 1.f;
        int offp;
        if (PAD) {
            bool vld = (iy >= 0) && (iy < Hin) && (ix >= 0) && (ix < Win);
            msk = vld ? 1.f : 0.f;
            int iyc = min(max(iy, 0), Hin - 1), ixc = min(max(ix, 0), Win - 1);
            offp = iyc * Win + ixc;
        } else {
            offp = iy * Win + ix;
        }
        int c = cib + cio;
        const float* src = (c < CinA)
            ? inA + (size_t)(b * CinA + c) * HWin
            : inB + (size_t)(b * CinB + (c - CinA)) * HWin;
        float v[8];
        #pragma unroll
        for (int j = 0; j < 8; ++j) v[j] = src[(size_t)j * HWin + offp];
        if (PAD) {
            #pragma unroll
            for (int j = 0; j < 8; ++j) v[j] *= msk;
        }
        uint4 pk;
        pk.x = pack_bf16(v[0], v[1]);
        pk.y = pack_bf16(v[2], v[3]);
        pk.z = pack_bf16(v[4], v[5]);
        pk.w = pack_bf16(v[6], v[7]);
        __syncthreads();
        *(uint4*)&sB[px * 40 + cio] = pk;
        __syncthreads();

        const ushort_t* wr = w2 + (size_t)(wave * 16 + lrow) * K + kk + lkg * 8;
        bf16x8 afr = *(const bf16x8*)wr;
        #pragma unroll
        for (int n2 = 0; n2 < 4; ++n2) {
            bf16x8 bfr = *(const bf16x8*)&sB[(n2 * 16 + lrow) * 40 + lkg * 8];
            acc[n2] = __builtin_amdgcn_mfma_f32_16x16x32_bf16(afr, bfr, acc[n2], 0, 0, 0);
        }
    }

    if (bias) {
        #pragma unroll
        for (int n2 = 0; n2 < 4; ++n2) {
            #pragma unroll
            for (int j = 0; j < 4; ++j) {
                int co = wave * 16 + lkg * 4 + j;
                if (co < CoutStore) {
                    int pp = tile * 64 + n2 * 16 + lrow;
                    float r = acc[n2][j] + bias[co];
                    if (act) r = lrelu_f(r);
                    outDirect[((size_t)(b * CoutStore + co)) * (size_t)Npx + pp] = r;
                }
            }
        }
    } else {
        #pragma unroll
        for (int n2 = 0; n2 < 4; ++n2) {
            #pragma unroll
            for (int j = 0; j < 4; ++j) {
                int co = wave * 16 + lkg * 4 + j;
                int pp = tile * 64 + n2 * 16 + lrow;
                part[((size_t)(ks * 2 + b) * 64 + co) * (size_t)Npx + pp] = acc[n2][j];
            }
        }
    }
}

__global__ __launch_bounds__(256) void reduce_bias_act(const float* __restrict__ part,
    const float* __restrict__ bias, float* __restrict__ out,
    int CO, int Cout, int Npx, int ksplit, int act)
{
    int idx = blockIdx.x * 256 + threadIdx.x;
    int total = 2 * Cout * Npx;
    if (idx >= total) return;
    int p  = idx % Npx;
    int co = (idx / Npx) % Cout;
    int b  = idx / (Npx * Cout);
    float s = bias[co];
    for (int ks = 0; ks < ksplit; ++ks)
        s += part[(((size_t)ks * 2 + b) * CO + co) * (size_t)Npx + p];
    if (act) s = lrelu_f(s);
    out[((size_t)b * Cout + co) * (size_t)Npx + p] = s;
}

__global__ __launch_bounds__(256) void dilate_kernel(const float* __restrict__ in,
    float* __restrict__ P, int Hin, int Win, int C2, int total)
{
    int idx = blockIdx.x * 256 + threadIdx.x;
    if (idx >= total) return;
    int Wp = 2 * Win + 2, Hp = 2 * Hin + 2;
    int v = idx % Wp, u = (idx / Wp) % Hp;
    int c = idx / (Wp * Hp);
    float val = 0.f;
    if ((u & 1) && (v & 1)) {
        int r = (u - 1) >> 1, q = (v - 1) >> 1;
        if (r < Hin && q < Win) val = in[((size_t)c * Hin + r) * Win + q];
    }
    P[idx] = val;
}

__global__ __launch_bounds__(256) void castw_perm_kernel(const float* __restrict__ w,
    ushort_t* __restrict__ wbf)
{
    int idx = blockIdx.x * 256 + threadIdx.x;
    if (idx >= 147456) return;
    int co = idx / 1152;
    int r  = idx % 1152;
    int chunk = r / 288;
    int r2 = r % 288;
    int tap = r2 >> 5;
    int cl  = r2 & 31;
    int ci = chunk * 32 + cl;
    wbf[idx] = f2bf(w[(size_t)co * 1152 + ci * 9 + tap]);
}

// NCHW frame [2][128][16384] -> NHWC [2][16384][128]
__global__ __launch_bounds__(256) void transpose_nhwc_kernel(const float* __restrict__ x,
    float* __restrict__ xT)
{
    __shared__ float t[32][33];
    int cT = blockIdx.x & 3;
    int pT = (blockIdx.x >> 2) & 511;
    int b  = blockIdx.x >> 11;
    int tx = threadIdx.x & 31, ty = threadIdx.x >> 5;
    const float* src = x + ((size_t)b * 128 + cT * 32) * 16384 + (size_t)pT * 32;
    #pragma unroll
    for (int i = 0; i < 4; ++i)
        t[ty + 8 * i][tx] = src[(size_t)(ty + 8 * i) * 16384 + tx];
    __syncthreads();
    float* dst = xT + ((size_t)b * 16384 + (size_t)pT * 32) * 128 + cT * 32;
    #pragma unroll
    for (int i = 0; i < 4; ++i)
        dst[(size_t)(ty + 8 * i) * 128 + tx] = t[tx][ty + 8 * i];
}

// ---------------------------------------------------------------------------
// Fused 1x1 convs -> bf16 attention operands. One thread per (n, slice j):
// j=0 -> thT rows, j=1 -> phT rows, j=2 -> gT columns. j uniform per block.
// ---------------------------------------------------------------------------
__global__ __launch_bounds__(256) void conv1x1x3_bf16(const float* __restrict__ e, int N,
    const float* __restrict__ tw, const float* __restrict__ tb,
    const float* __restrict__ pw, const float* __restrict__ pb,
    const float* __restrict__ gw, const float* __restrict__ gb,
    ushort_t* __restrict__ thT, ushort_t* __restrict__ phT, ushort_t* __restrict__ gT)
{
    __shared__ float sw[32 * 64];
    __shared__ float sb[32];
    int tid = threadIdx.x;
    int idx = blockIdx.x * 256 + tid;
    int j = idx / (2 * N);
    const float* wsel = (j == 0) ? tw : (j == 1) ? pw : gw;
    const float* bsel = (j == 0) ? tb : (j == 1) ? pb : gb;
    for (int i = tid; i < 2048; i += 256) sw[i] = wsel[i];
    if (tid < 32) sb[tid] = bsel[tid];
    __syncthreads();
    int rem = idx - j * 2 * N;
    int n = rem % N, b = rem / N;
    float ein[64];
    const float* ep = e + (size_t)b * 64 * N + n;
    #pragma unroll
    for (int ci = 0; ci < 64; ++ci) ein[ci] = ep[(size_t)ci * N];

    float val[32];
    #pragma unroll
    for (int cc = 0; cc < 32; ++cc) {
        float acc = sb[cc];
        const float* wr = &sw[cc * 64];
        #pragma unroll
        for (int ci = 0; ci < 64; ++ci) acc = fmaf(wr[ci], ein[ci], acc);
        val[cc] = acc;
    }
    if (j < 2) {
        ushort_t* row = (j == 0 ? thT : phT) + ((size_t)b * N + n) * 32;
        #pragma unroll
        for (int w4 = 0; w4 < 4; ++w4) {
            uint4 pk;
            pk.x = pack_bf16(val[8 * w4 + 0], val[8 * w4 + 1]);
            pk.y = pack_bf16(val[8 * w4 + 2], val[8 * w4 + 3]);
            pk.z = pack_bf16(val[8 * w4 + 4], val[8 * w4 + 5]);
            pk.w = pack_bf16(val[8 * w4 + 6], val[8 * w4 + 7]);
            *(uint4*)(row + 8 * w4) = pk;
        }
    } else {
        #pragma unroll
        for (int cc = 0; cc < 32; ++cc)
            gT[((size_t)b * 32 + cc) * N + n] = f2bf(val[cc]);
    }
}

// ===========================================================================
// Flash split-K MFMA attention (unchanged from round 6).
// ===========================================================================
__global__ __launch_bounds__(256) void attn_flash(const ushort_t* __restrict__ thT,
    const ushort_t* __restrict__ phT, const ushort_t* __restrict__ gT,
    float* __restrict__ partO, float* __restrict__ partML, int N, int KVS)
{
    __shared__ ushort_t sP[4][16 * 40];
    int tid  = threadIdx.x;
    int wave = tid >> 6, lane = tid & 63;
    int lq = lane & 15, lkg = lane >> 4;
    int nqb = N / 64;
    int ks = blockIdx.x % KVS;
    int qb = (blockIdx.x / KVS) % nqb;
    int b  = blockIdx.x / (KVS * nqb);
    int q0w = qb * 64 + wave * 16;
    int chunk = N / KVS;
    int m_start = ks * chunk;

    bf16x8 qf = *(const bf16x8*)(thT + ((size_t)b * N + q0w + lq) * 32 + 8 * lkg);

    float m_run = -1e30f, l_run = 0.f;
    f32x4 acc[2];
    acc[0] = (f32x4){0.f, 0.f, 0.f, 0.f};
    acc[1] = (f32x4){0.f, 0.f, 0.f, 0.f};

    for (int m0 = m_start; m0 < m_start + chunk; m0 += 64) {
        f32x4 tf[4];
        #pragma unroll
        for (int f = 0; f < 4; ++f) {
            bf16x8 kf = *(const bf16x8*)(phT + ((size_t)b * N + m0 + f * 16 + lq) * 32 + 8 * lkg);
            tf[f] = __builtin_amdgcn_mfma_f32_16x16x32_bf16(kf, qf,
                        (f32x4){0.f, 0.f, 0.f, 0.f}, 0, 0, 0);
        }

        float mx = -1e30f;
        #pragma unroll
        for (int f = 0; f < 4; ++f)
            #pragma unroll
            for (int r = 0; r < 4; ++r) mx = fmaxf(mx, tf[f][r]);
        mx = fmaxf(mx, __shfl_xor(mx, 16));
        mx = fmaxf(mx, __shfl_xor(mx, 32));
        float m_new = fmaxf(m_run, mx);
        float scale = __expf(m_run - m_new);
        float rs = 0.f;
        #pragma unroll
        for (int f = 0; f < 4; ++f)
            #pragma unroll
            for (int r = 0; r < 4; ++r) {
                float pv = __expf(tf[f][r] - m_new);
                tf[f][r] = pv;
                rs += pv;
            }
        rs += __shfl_xor(rs, 16);
        rs += __shfl_xor(rs, 32);
        l_run = l_run * scale + rs;
        m_run = m_new;

        float sc[4];
        #pragma unroll
        for (int r = 0; r < 4; ++r) sc[r] = __shfl(scale, 4 * lkg + r);
        #pragma unroll
        for (int h = 0; h < 2; ++h)
            #pragma unroll
            for (int r = 0; r < 4; ++r) acc[h][r] *= sc[r];

        #pragma unroll
        for (int f = 0; f < 4; ++f) {
            *(uint_t*)&sP[wave][lq * 40 + f * 16 + 4 * lkg]     = pack_bf16(tf[f][0], tf[f][1]);
            *(uint_t*)&sP[wave][lq * 40 + f * 16 + 4 * lkg + 2] = pack_bf16(tf[f][2], tf[f][3]);
        }

        #pragma unroll
        for (int mc = 0; mc < 2; ++mc) {
            bf16x8 pf = *(const bf16x8*)&sP[wave][lq * 40 + mc * 32 + 8 * lkg];
            #pragma unroll
            for (int h = 0; h < 2; ++h) {
                bf16x8 vf = *(const bf16x8*)(gT + ((size_t)b * 32 + h * 16 + lq) * N
                                             + m0 + mc * 32 + 8 * lkg);
                acc[h] = __builtin_amdgcn_mfma_f32_16x16x32_bf16(pf, vf, acc[h], 0, 0, 0);
            }
        }
    }

    #pragma unroll
    for (int h = 0; h < 2; ++h) {
        #pragma unroll
        for (int r = 0; r < 4; ++r) {
            int q = q0w + 4 * lkg + r;
            partO[(((size_t)ks * 2 + b) * N + q) * 32 + h * 16 + lq] = acc[h][r];
        }
    }
    if (lane < 16) {
        size_t mlo = (((size_t)ks * 2 + b) * N + q0w + lq) * 2;
        partML[mlo]     = m_run;
        partML[mlo + 1] = l_run;
    }
}

// ===========================================================================
// Fused flash-combine + non-local merge: out = 2*e + W*(softmax-combined y) [+u].
// One thread per (n, 16-co group). grid = 2*4*N/256.
// ===========================================================================
__global__ __launch_bounds__(256) void nl_merge_fused(const float* __restrict__ e,
    const float* __restrict__ partO, const float* __restrict__ partML,
    const float* __restrict__ u,
    const float* __restrict__ ww, const float* __restrict__ wb,
    float* __restrict__ out, int N, int KVS)
{
    __shared__ float sw[64 * 32];
    __shared__ float sb[64];
    int tid = threadIdx.x;
    for (int i = tid; i < 2048; i += 256) sw[i] = ww[i];
    if (tid < 64) sb[tid] = wb[tid];
    __syncthreads();
    int idx = blockIdx.x * 256 + tid;
    int n = idx % N;
    int cog = (idx / N) & 3;
    int b = idx / (4 * N);

    float mstar = -1e30f;
    for (int ks = 0; ks < KVS; ++ks)
        mstar = fmaxf(mstar, partML[(((size_t)ks * 2 + b) * N + n) * 2]);
    float denom = 0.f;
    float yv[32];
    #pragma unroll
    for (int c = 0; c < 32; ++c) yv[c] = 0.f;
    for (int ks = 0; ks < KVS; ++ks) {
        size_t mlo = (((size_t)ks * 2 + b) * N + n) * 2;
        float w = __expf(partML[mlo] - mstar);
        denom += w * partML[mlo + 1];
        const f32x4* op = (const f32x4*)(partO + (((size_t)ks * 2 + b) * N + n) * 32);
        #pragma unroll
        for (int jj = 0; jj < 8; ++jj) {
            f32x4 v = op[jj];
            #pragma unroll
            for (int t = 0; t < 4; ++t) yv[4 * jj + t] = fmaf(w, v[t], yv[4 * jj + t]);
        }
    }
    float inv = 1.f / denom;
    #pragma unroll
    for (int i = 0; i < 16; ++i) {
        int co = cog * 16 + i;
        float dot = 0.f;
        const float* wr = &sw[co * 32];
        #pragma unroll
        for (int c = 0; c < 32; ++c) dot = fmaf(wr[c], yv[c], dot);
        size_t o = (size_t)b * 64 * N + (size_t)co * N + n;
        float r = sb[co] + inv * dot + 2.f * e[o];
        if (u) r += u[o];
        out[o] = r;
    }
}

// ===========================================================================
// Deformable conv v3: sampling params precomputed in prologue (fp32 weights +
// packed ushort offsets), slim staging loop, bf16 MFMA GEMM.
// ===========================================================================
__global__ __launch_bounds__(256) void deform_mfma3(const float* __restrict__ xT,
    const float* __restrict__ est, const ushort_t* __restrict__ wbf,
    const float* __restrict__ bias, float* __restrict__ out)
{
    const int H = 128, W = 128, HW = 16384;
    const int BS = 296;
    __shared__ ushort_t sB[64 * BS];
    __shared__ float4 sW[576];
    __shared__ uint2  sO[576];
    int tile = blockIdx.x & 255;
    int b    = blockIdx.x >> 8;
    int p0   = tile * 64;
    int tid  = threadIdx.x;

    const float* eb = est + (size_t)b * 27 * HW;
    for (int i = tid; i < 576; i += 256) {
        int k = i >> 6, j = i & 63;
        int p = p0 + j;
        int yy = p >> 7, xx = p & 127;
        float oy = eb[(size_t)(9 + 2 * k) * HW + p];
        float ox = eb[(size_t)(10 + 2 * k) * HW + p];
        float mv = eb[(size_t)k * HW + p];
        float mk = 1.f / (1.f + __expf(-mv));
        float py = (float)(yy + (k / 3) - 1) + oy;
        float qx = (float)(xx + (k % 3) - 1) + ox;
        float fy0 = floorf(py), fx0 = floorf(qx);
        float wy = py - fy0, wx = qx - fx0;
        int y0 = (int)fy0, x0 = (int)fx0;
        int y1 = y0 + 1, x1 = x0 + 1;
        bool yv0 = (y0 >= 0) && (y0 < H), yv1 = (y1 >= 0) && (y1 < H);
        bool xv0 = (x0 >= 0) && (x0 < W), xv1 = (x1 >= 0) && (x1 < W);
        int y0c = min(max(y0, 0), H - 1), y1c = min(max(y1, 0), H - 1);
        int x0c = min(max(x0, 0), W - 1), x1c = min(max(x1, 0), W - 1);
        float4 w4;
        w4.x = (yv0 && xv0) ? (1.f - wy) * (1.f - wx) * mk : 0.f;
        w4.y = (yv0 && xv1) ? (1.f - wy) * wx * mk : 0.f;
        w4.z = (yv1 && xv0) ? wy * (1.f - wx) * mk : 0.f;
        w4.w = (yv1 && xv1) ? wy * wx * mk : 0.f;
        sW[i] = w4;
        uint_t o00 = (uint_t)(y0c * W + x0c), o01 = (uint_t)(y0c * W + x1c);
        uint_t o10 = (uint_t)(y1c * W + x0c), o11 = (uint_t)(y1c * W + x1c);
        sO[i] = (uint2){ o00 | (o01 << 16), o10 | (o11 << 16) };
    }

    int wave = tid >> 6, lane = tid & 63;
    int co_base = wave * 32;
    int lrow = lane & 15, lkg = lane >> 4;

    f32x4 acc[2][4];
    #pragma unroll
    for (int m2 = 0; m2 < 2; ++m2)
        #pragma unroll
        for (int n2 = 0; n2 < 4; ++n2) acc[m2][n2] = (f32x4){0.f, 0.f, 0.f, 0.f};

    const f32x4* xb4 = (const f32x4*)(xT + (size_t)b * HW * 128);

    for (int cc = 0; cc < 128; cc += 32) {
        __syncthreads();
        #pragma unroll 2
        for (int it = 0; it < 18; ++it) {
            int task = it * 256 + tid;
            int cg = task & 7;
            int si = task >> 3;
            float4 w4 = sW[si];
            uint2 o4 = sO[si];
            int chv = (cc >> 2) + cg;
            f32x4 c00 = xb4[(o4.x & 0xFFFFu) * 32 + chv];
            f32x4 c01 = xb4[(o4.x >> 16) * 32 + chv];
            f32x4 c10 = xb4[(o4.y & 0xFFFFu) * 32 + chv];
            f32x4 c11 = xb4[(o4.y >> 16) * 32 + chv];
            f32x4 v;
            #pragma unroll
            for (int j = 0; j < 4; ++j)
                v[j] = w4.x * c00[j] + w4.y * c01[j] + w4.z * c10[j] + w4.w * c11[j];
            int pxl = si & 63, tap = si >> 6;
            uint2 pk;
            pk.x = pack_bf16(v[0], v[1]);
            pk.y = pack_bf16(v[2], v[3]);
            *(uint2*)&sB[pxl * BS + tap * 32 + cg * 4] = pk;
        }
        __syncthreads();
        int kbase = cc * 9;
        #pragma unroll
        for (int ks = 0; ks < 9; ++ks) {
            bf16x8 afr[2], bfr[4];
            #pragma unroll
            for (int m2 = 0; m2 < 2; ++m2)
                afr[m2] = *reinterpret_cast<const bf16x8*>(
                    wbf + (size_t)(co_base + m2 * 16 + lrow) * 1152 + kbase + ks * 32 + lkg * 8);
            #pragma unroll
            for (int n2 = 0; n2 < 4; ++n2)
                bfr[n2] = *reinterpret_cast<const bf16x8*>(
                    &sB[(n2 * 16 + lrow) * BS + ks * 32 + lkg * 8]);
            #pragma unroll
            for (int m2 = 0; m2 < 2; ++m2)
                #pragma unroll
                for (int n2 = 0; n2 < 4; ++n2)
                    acc[m2][n2] = __builtin_amdgcn_mfma_f32_16x16x32_bf16(
                        afr[m2], bfr[n2], acc[m2][n2], 0, 0, 0);
        }
    }

    #pragma unroll
    for (int m2 = 0; m2 < 2; ++m2) {
        #pragma unroll
        for (int j = 0; j < 4; ++j) {
            int co = co_base + m2 * 16 + lkg * 4 + j;
            float bb = bias[co];
            #pragma unroll
            for (int n2 = 0; n2 < 4; ++n2) {
                int px = p0 + n2 * 16 + lrow;
                out[((size_t)(b * 128 + co)) * HW + px] = acc[m2][n2][j] + bb;
            }
        }
    }
}

extern "C" void kernel_launch(void* const* d_in, const int* in_sizes, int n_in,
                              void* d_out, int out_size, void* d_ws, size_t ws_size,
                              hipStream_t stream)
{
    const float* x_all     = (const float*)d_in[0];
    const float* ms_fine   = (const float*)d_in[1];
    const float* ms_coarse = (const float*)d_in[2];
    const float* enc_w0 = (const float*)d_in[3];
    const float* enc_b0 = (const float*)d_in[4];
    const float* enc_w1 = (const float*)d_in[5];
    const float* enc_b1 = (const float*)d_in[6];
    const float* nl_tw[2] = { (const float*)d_in[7],  (const float*)d_in[15] };
    const float* nl_tb[2] = { (const float*)d_in[8],  (const float*)d_in[16] };
    const float* nl_pw[2] = { (const float*)d_in[9],  (const float*)d_in[17] };
    const float* nl_pb[2] = { (const float*)d_in[10], (const float*)d_in[18] };
    const float* nl_gw[2] = { (const float*)d_in[11], (const float*)d_in[19] };
    const float* nl_gb[2] = { (const float*)d_in[12], (const float*)d_in[20] };
    const float* nl_ww[2] = { (const float*)d_in[13], (const float*)d_in[21] };
    const float* nl_wb[2] = { (const float*)d_in[14], (const float*)d_in[22] };
    const float* dec_w0 = (const float*)d_in[23];
    const float* dec_b0 = (const float*)d_in[24];
    const float* dec_w1 = (const float*)d_in[25];
    const float* dec_b1 = (const float*)d_in[26];
    const float* off_w  = (const float*)d_in[27];
    const float* off_b  = (const float*)d_in[28];
    const float* dcn_w  = (const float*)d_in[29];
    const float* dcn_b  = (const float*)d_in[30];

    float* ws  = (float*)d_ws;
    float* e0  = ws;
    float* th0 = e0 + 131072;
    float* ph0 = th0 + 65536;
    float* g0  = ph0 + 65536;
    float* y0  = g0 + 65536;
    float* m0  = y0 + 65536;
    float* u0  = m0 + 131072;
    float* e1  = u0 + 524288;
    float* th1 = e1 + 524288;
    float* ph1 = th1 + 262144;
    float* g1  = ph1 + 262144;
    float* y1  = g1 + 262144;
    float* m1  = y1 + 262144;
    float* mot = m1 + 524288;
    float* est = mot + 2097152;
    float* P   = est + 884736;
    float* partial = P + 2163200;
    ushort_t* wbf     = (ushort_t*)(partial + 2097152);
    ushort_t* w2_enc0 = wbf + 147456;
    ushort_t* w2_enc1 = w2_enc0 + 294912;
    ushort_t* w2_dec0 = w2_enc1 + 147456;
    ushort_t* w2_dec1 = w2_dec0 + 36864;
    ushort_t* w2_est  = w2_dec1 + 36864;
    float* partML = (float*)(w2_est + 36864);
    float* xT = P;

    ushort_t* thT0 = (ushort_t*)th0;
    ushort_t* phT0 = (ushort_t*)ph0;
    ushort_t* gT0  = (ushort_t*)g0;
    ushort_t* thT1 = (ushort_t*)th1;
    ushort_t* phT1 = (ushort_t*)ph1;
    ushort_t* gT1  = (ushort_t*)g1;

    float* out = (float*)d_out;
    const size_t frame = (size_t)2 * 128 * 128 * 128;

    hipMemcpyAsync(out, x_all, frame * sizeof(float), hipMemcpyDeviceToDevice, stream);

    castw_perm_kernel<<<(147456 + 255) / 256, 256, 0, stream>>>(dcn_w, wbf);
    castw2_kernel<<<(64 * 4608 + 255) / 256, 256, 0, stream>>>(enc_w0, w2_enc0, 64, 512, 4608, 0);
    castw2_kernel<<<(64 * 2304 + 255) / 256, 256, 0, stream>>>(enc_w1, w2_enc1, 64, 256, 2304, 0);
    castw2_kernel<<<(64 * 576 + 255) / 256, 256, 0, stream>>>(dec_w0, w2_dec0, 64, 64, 576, 1);
    castw2_kernel<<<(64 * 576 + 255) / 256, 256, 0, stream>>>(dec_w1, w2_dec1, 64, 64, 576, 1);
    castw2_kernel<<<(64 * 576 + 255) / 256, 256, 0, stream>>>(off_w, w2_est, 27, 64, 576, 0);

    for (int s = 1; s < 3; ++s) {
        const float* pc = ms_coarse + (size_t)s * 2 * 256 * 64 * 64;
        const float* cc = ms_coarse;
        const float* pf = ms_fine + (size_t)s * frame;
        const float* cf = ms_fine;

        // ---- e0 = lrelu(conv3x3 s2 (pc||cc; 512->64)) : (2,64,32,32)
        conv3x3_mfma<2, 1><<<2 * 16 * 16, 256, 0, stream>>>(
            pc, cc, 256, 64, 64, 512, w2_enc0, 4608, 32, 1024, 16, 16, 9, partial,
            nullptr, 0, 0, nullptr);
        reduce_bias_act<<<512, 256, 0, stream>>>(partial, enc_b0, e0, 64, 64, 1024, 16, 1);

        // ---- non-local 0 (N=1024, KVS=4)
        conv1x1x3_bf16<<<24, 256, 0, stream>>>(e0, 1024,
            nl_tw[0], nl_tb[0], nl_pw[0], nl_pb[0], nl_gw[0], nl_gb[0], thT0, phT0, gT0);
        attn_flash<<<2 * 16 * 4, 256, 0, stream>>>(thT0, phT0, gT0, partial, partML, 1024, 4);
        nl_merge_fused<<<32, 256, 0, stream>>>(e0, partial, partML, nullptr,
            nl_ww[0], nl_wb[0], m0, 1024, 4);

        // ---- u0 = lrelu(deconv(m0)) : (2,64,64,64)
        {
            int total = 128 * 66 * 66;
            dilate_kernel<<<(total + 255) / 256, 256, 0, stream>>>(m0, P, 32, 32, 128, total);
            conv3x3_mfma<1, 0><<<2 * 64 * 3, 256, 0, stream>>>(
                P, P, 64, 66, 66, 64, w2_dec0, 576, 64, 4096, 64, 3, 6, partial,
                nullptr, 0, 0, nullptr);
            reduce_bias_act<<<2048, 256, 0, stream>>>(partial, dec_b0, u0, 64, 64, 4096, 3, 1);
        }

        // ---- e1 = lrelu(conv3x3 s2 (pf||cf; 256->64)) : (2,64,64,64)
        conv3x3_mfma<2, 1><<<2 * 64 * 4, 256, 0, stream>>>(
            pf, cf, 128, 128, 128, 256, w2_enc1, 2304, 64, 4096, 64, 4, 18, partial,
            nullptr, 0, 0, nullptr);
        reduce_bias_act<<<2048, 256, 0, stream>>>(partial, enc_b1, e1, 64, 64, 4096, 4, 1);

        // ---- non-local 1 (N=4096, KVS=8)
        conv1x1x3_bf16<<<96, 256, 0, stream>>>(e1, 4096,
            nl_tw[1], nl_tb[1], nl_pw[1], nl_pb[1], nl_gw[1], nl_gb[1], thT1, phT1, gT1);
        attn_flash<<<2 * 64 * 8, 256, 0, stream>>>(thT1, phT1, gT1, partial, partML, 4096, 8);
        nl_merge_fused<<<128, 256, 0, stream>>>(e1, partial, partML, u0,
            nl_ww[1], nl_wb[1], m1, 4096, 8);

        // ---- mot = lrelu(deconv(m1)) : (2,64,128,128)  [fused epilogue]
        {
            int total = 128 * 130 * 130;
            dilate_kernel<<<(total + 255) / 256, 256, 0, stream>>>(m1, P, 64, 64, 128, total);
            conv3x3_mfma<1, 0><<<2 * 256, 256, 0, stream>>>(
                P, P, 64, 130, 130, 64, w2_dec1, 576, 128, 16384, 256, 1, 18, partial,
                dec_b1, 1, 64, mot);
        }

        // ---- est = conv3x3 s1 (mot; 64->27) : (2,27,128,128)  [fused epilogue]
        conv3x3_mfma<1, 1><<<2 * 256, 256, 0, stream>>>(
            mot, mot, 64, 128, 128, 64, w2_est, 576, 128, 16384, 256, 1, 18, partial,
            off_b, 0, 27, est);

        // ---- xT = NHWC(x_all[s]), then deform
        transpose_nhwc_kernel<<<4096, 256, 0, stream>>>(x_all + (size_t)s * frame, xT);
        deform_mfma3<<<512, 256, 0, stream>>>(xT, est, wbf, dcn_b, out + (size_t)s * frame);
    }
}

// Round 9
// 395.960 us; speedup vs baseline: 13.2388x; 1.3875x over previous
//
#include <hip/hip_runtime.h>
#include <math.h>

typedef __attribute__((ext_vector_type(8))) short bf16x8;
typedef __attribute__((ext_vector_type(4))) float f32x4;
typedef unsigned short ushort_t;
typedef unsigned int uint_t;

__device__ __forceinline__ float lrelu_f(float x) { return x >= 0.f ? x : 0.01f * x; }

__device__ __forceinline__ ushort_t f2bf(float f) {
    uint_t x = __float_as_uint(f);
    uint_t r = (x + 0x7fffu + ((x >> 16) & 1u)) >> 16;
    return (ushort_t)r;
}

__device__ __forceinline__ uint_t pack_bf16(float lo, float hi) {
    uint_t out;
    asm("v_cvt_pk_bf16_f32 %0, %1, %2" : "=v"(out) : "v"(lo), "v"(hi));
    return out;
}

// ===========================================================================
// Weight prep: w2[co64][K'=tap*Cin+ci] bf16, co padded to 64 with zeros.
// ===========================================================================
__global__ __launch_bounds__(256) void castw2_kernel(const float* __restrict__ w,
    ushort_t* __restrict__ w2, int Cout, int Cin, int K, int deconv)
{
    int idx = blockIdx.x * 256 + threadIdx.x;
    if (idx >= 64 * K) return;
    int co = idx / K, kp = idx % K;
    int tap = kp / Cin, ci = kp % Cin;
    float val = 0.f;
    if (co < Cout)
        val = deconv ? w[(size_t)(ci * Cout + co) * 9 + (8 - tap)]
                     : w[(size_t)(co * Cin + ci) * 9 + tap];
    w2[idx] = f2bf(val);
}

// ===========================================================================
// bf16 MFMA implicit-GEMM 3x3 conv over 4-batch (2 s-iters x 2 b).
// MODE 0: stride-STRIDE conv pad 1 (masked clamp).
// MODE 1: stride-2 transposed conv (parity-masked direct reads; no dilation
//         buffer): valid tap iff (oy+ky) odd & (oy+ky-1)/2 < Hin (same for x).
// Input may be channel-concat inA(s-dependent, stride sStrideA)||inB(shared).
// bias!=nullptr (requires ksplit==1): fused act(acc+bias) -> outDirect.
// ===========================================================================
template<int STRIDE, int MODE>
__global__ __launch_bounds__(256) void conv3x3_mfma(
    const float* __restrict__ inA, const float* __restrict__ inB, int CinA,
    size_t sStrideA, int Hin, int Win, int Cin,
    const ushort_t* __restrict__ w2, int K,
    int Wout, int Npx, int tilesPerMap, int ksplit, int chunksPerKs,
    float* __restrict__ part,
    const float* __restrict__ bias, int act, int CoutStore, float* __restrict__ outDirect)
{
    __shared__ ushort_t sB[64 * 40];
    int tile = blockIdx.x % tilesPerMap;
    int ks   = (blockIdx.x / tilesPerMap) % ksplit;
    int b4   = blockIdx.x / (tilesPerMap * ksplit);
    int s_idx = b4 >> 1, bb = b4 & 1;
    int tid  = threadIdx.x;
    int wave = tid >> 6, lane = tid & 63;
    int lrow = lane & 15, lkg = lane >> 4;
    int px  = tid & 63;
    int cio = wave * 8;
    int p   = tile * 64 + px;
    int oy  = p / Wout, ox = p - oy * Wout;
    int HWin = Hin * Win;
    int CinB = Cin - CinA;

    f32x4 acc[4];
    #pragma unroll
    for (int n2 = 0; n2 < 4; ++n2) acc[n2] = (f32x4){0.f, 0.f, 0.f, 0.f};

    for (int cch = 0; cch < chunksPerKs; ++cch) {
        int kk  = (ks * chunksPerKs + cch) * 32;
        int tap = kk / Cin;
        int cib = kk - tap * Cin;
        int ky = tap / 3, kx = tap - ky * 3;
        float msk;
        int offp;
        if (MODE == 0) {
            int iy = oy * STRIDE - 1 + ky;
            int ix = ox * STRIDE - 1 + kx;
            bool vld = (iy >= 0) && (iy < Hin) && (ix >= 0) && (ix < Win);
            msk = vld ? 1.f : 0.f;
            offp = min(max(iy, 0), Hin - 1) * Win + min(max(ix, 0), Win - 1);
        } else {
            int uy = oy + ky, ux = ox + kx;
            int r = (uy - 1) >> 1, q = (ux - 1) >> 1;
            bool vld = (uy & 1) && (ux & 1) && (r < Hin) && (q < Win);
            msk = vld ? 1.f : 0.f;
            offp = min(max(r, 0), Hin - 1) * Win + min(max(q, 0), Win - 1);
        }
        int c = cib + cio;
        const float* src = (c < CinA)
            ? inA + s_idx * sStrideA + (size_t)(bb * CinA + c) * HWin
            : inB + (size_t)(bb * CinB + (c - CinA)) * HWin;
        float v[8];
        #pragma unroll
        for (int j = 0; j < 8; ++j) v[j] = src[(size_t)j * HWin + offp] * msk;
        uint4 pk;
        pk.x = pack_bf16(v[0], v[1]);
        pk.y = pack_bf16(v[2], v[3]);
        pk.z = pack_bf16(v[4], v[5]);
        pk.w = pack_bf16(v[6], v[7]);
        __syncthreads();
        *(uint4*)&sB[px * 40 + cio] = pk;
        __syncthreads();

        const ushort_t* wr = w2 + (size_t)(wave * 16 + lrow) * K + kk + lkg * 8;
        bf16x8 afr = *(const bf16x8*)wr;
        #pragma unroll
        for (int n2 = 0; n2 < 4; ++n2) {
            bf16x8 bfr = *(const bf16x8*)&sB[(n2 * 16 + lrow) * 40 + lkg * 8];
            acc[n2] = __builtin_amdgcn_mfma_f32_16x16x32_bf16(afr, bfr, acc[n2], 0, 0, 0);
        }
    }

    if (bias) {
        #pragma unroll
        for (int n2 = 0; n2 < 4; ++n2) {
            #pragma unroll
            for (int j = 0; j < 4; ++j) {
                int co = wave * 16 + lkg * 4 + j;
                if (co < CoutStore) {
                    int pp = tile * 64 + n2 * 16 + lrow;
                    float r = acc[n2][j] + bias[co];
                    if (act) r = lrelu_f(r);
                    outDirect[((size_t)(b4 * CoutStore + co)) * (size_t)Npx + pp] = r;
                }
            }
        }
    } else {
        #pragma unroll
        for (int n2 = 0; n2 < 4; ++n2) {
            #pragma unroll
            for (int j = 0; j < 4; ++j) {
                int co = wave * 16 + lkg * 4 + j;
                int pp = tile * 64 + n2 * 16 + lrow;
                part[((size_t)(ks * 4 + b4) * 64 + co) * (size_t)Npx + pp] = acc[n2][j];
            }
        }
    }
}

// 4-batch: out[b4][co][p] = act(bias[co] + sum_ks part[ks][b4][co][p])
__global__ __launch_bounds__(256) void reduce_bias_act(const float* __restrict__ part,
    const float* __restrict__ bias, float* __restrict__ out,
    int Cout, int Npx, int ksplit, int act)
{
    int idx = blockIdx.x * 256 + threadIdx.x;
    int total = 4 * Cout * Npx;
    if (idx >= total) return;
    int p  = idx % Npx;
    int co = (idx / Npx) % Cout;
    int b4 = idx / (Npx * Cout);
    float s = bias[co];
    for (int ks = 0; ks < ksplit; ++ks)
        s += part[(((size_t)ks * 4 + b4) * 64 + co) * (size_t)Npx + p];
    if (act) s = lrelu_f(s);
    out[((size_t)b4 * Cout + co) * (size_t)Npx + p] = s;
}

__global__ __launch_bounds__(256) void castw_perm_kernel(const float* __restrict__ w,
    ushort_t* __restrict__ wbf)
{
    int idx = blockIdx.x * 256 + threadIdx.x;
    if (idx >= 147456) return;
    int co = idx / 1152;
    int r  = idx % 1152;
    int chunk = r / 288;
    int r2 = r % 288;
    int tap = r2 >> 5;
    int cl  = r2 & 31;
    int ci = chunk * 32 + cl;
    wbf[idx] = f2bf(w[(size_t)co * 1152 + ci * 9 + tap]);
}

// NCHW frame [2][128][16384] -> NHWC [2][16384][128]
__global__ __launch_bounds__(256) void transpose_nhwc_kernel(const float* __restrict__ x,
    float* __restrict__ xT)
{
    __shared__ float t[32][33];
    int cT = blockIdx.x & 3;
    int pT = (blockIdx.x >> 2) & 511;
    int b  = blockIdx.x >> 11;
    int tx = threadIdx.x & 31, ty = threadIdx.x >> 5;
    const float* src = x + ((size_t)b * 128 + cT * 32) * 16384 + (size_t)pT * 32;
    #pragma unroll
    for (int i = 0; i < 4; ++i)
        t[ty + 8 * i][tx] = src[(size_t)(ty + 8 * i) * 16384 + tx];
    __syncthreads();
    float* dst = xT + ((size_t)b * 16384 + (size_t)pT * 32) * 128 + cT * 32;
    #pragma unroll
    for (int i = 0; i < 4; ++i)
        dst[(size_t)(ty + 8 * i) * 128 + tx] = t[tx][ty + 8 * i];
}

// ---------------------------------------------------------------------------
// Fused 1x1 convs -> bf16 attention operands, 4-batch. One thread per
// (slice j, b4, n); j uniform per block.
// ---------------------------------------------------------------------------
__global__ __launch_bounds__(256) void conv1x1x3_bf16(const float* __restrict__ e, int N,
    const float* __restrict__ tw, const float* __restrict__ tb,
    const float* __restrict__ pw, const float* __restrict__ pb,
    const float* __restrict__ gw, const float* __restrict__ gb,
    ushort_t* __restrict__ thT, ushort_t* __restrict__ phT, ushort_t* __restrict__ gT)
{
    __shared__ float sw[32 * 64];
    __shared__ float sb[32];
    int tid = threadIdx.x;
    int idx = blockIdx.x * 256 + tid;
    int j = idx / (4 * N);
    const float* wsel = (j == 0) ? tw : (j == 1) ? pw : gw;
    const float* bsel = (j == 0) ? tb : (j == 1) ? pb : gb;
    for (int i = tid; i < 2048; i += 256) sw[i] = wsel[i];
    if (tid < 32) sb[tid] = bsel[tid];
    __syncthreads();
    int rem = idx - j * 4 * N;
    int n = rem % N, b4 = rem / N;
    float ein[64];
    const float* ep = e + (size_t)b4 * 64 * N + n;
    #pragma unroll
    for (int ci = 0; ci < 64; ++ci) ein[ci] = ep[(size_t)ci * N];

    float val[32];
    #pragma unroll
    for (int cc = 0; cc < 32; ++cc) {
        float acc = sb[cc];
        const float* wr = &sw[cc * 64];
        #pragma unroll
        for (int ci = 0; ci < 64; ++ci) acc = fmaf(wr[ci], ein[ci], acc);
        val[cc] = acc;
    }
    if (j < 2) {
        ushort_t* row = (j == 0 ? thT : phT) + ((size_t)b4 * N + n) * 32;
        #pragma unroll
        for (int w4 = 0; w4 < 4; ++w4) {
            uint4 pk;
            pk.x = pack_bf16(val[8 * w4 + 0], val[8 * w4 + 1]);
            pk.y = pack_bf16(val[8 * w4 + 2], val[8 * w4 + 3]);
            pk.z = pack_bf16(val[8 * w4 + 4], val[8 * w4 + 5]);
            pk.w = pack_bf16(val[8 * w4 + 6], val[8 * w4 + 7]);
            *(uint4*)(row + 8 * w4) = pk;
        }
    } else {
        #pragma unroll
        for (int cc = 0; cc < 32; ++cc)
            gT[((size_t)b4 * 32 + cc) * N + n] = f2bf(val[cc]);
    }
}

// ===========================================================================
// Flash split-K MFMA attention, 4-batch, fragments direct from global.
// ===========================================================================
__global__ __launch_bounds__(256) void attn_flash(const ushort_t* __restrict__ thT,
    const ushort_t* __restrict__ phT, const ushort_t* __restrict__ gT,
    float* __restrict__ partO, float* __restrict__ partML, int N, int KVS)
{
    __shared__ ushort_t sP[4][16 * 40];
    int tid  = threadIdx.x;
    int wave = tid >> 6, lane = tid & 63;
    int lq = lane & 15, lkg = lane >> 4;
    int nqb = N / 64;
    int ks = blockIdx.x % KVS;
    int qb = (blockIdx.x / KVS) % nqb;
    int b4 = blockIdx.x / (KVS * nqb);
    int q0w = qb * 64 + wave * 16;
    int chunk = N / KVS;
    int m_start = ks * chunk;

    bf16x8 qf = *(const bf16x8*)(thT + ((size_t)b4 * N + q0w + lq) * 32 + 8 * lkg);

    float m_run = -1e30f, l_run = 0.f;
    f32x4 acc[2];
    acc[0] = (f32x4){0.f, 0.f, 0.f, 0.f};
    acc[1] = (f32x4){0.f, 0.f, 0.f, 0.f};

    for (int m0 = m_start; m0 < m_start + chunk; m0 += 64) {
        f32x4 tf[4];
        #pragma unroll
        for (int f = 0; f < 4; ++f) {
            bf16x8 kf = *(const bf16x8*)(phT + ((size_t)b4 * N + m0 + f * 16 + lq) * 32 + 8 * lkg);
            tf[f] = __builtin_amdgcn_mfma_f32_16x16x32_bf16(kf, qf,
                        (f32x4){0.f, 0.f, 0.f, 0.f}, 0, 0, 0);
        }

        float mx = -1e30f;
        #pragma unroll
        for (int f = 0; f < 4; ++f)
            #pragma unroll
            for (int r = 0; r < 4; ++r) mx = fmaxf(mx, tf[f][r]);
        mx = fmaxf(mx, __shfl_xor(mx, 16));
        mx = fmaxf(mx, __shfl_xor(mx, 32));
        float m_new = fmaxf(m_run, mx);
        float scale = __expf(m_run - m_new);
        float rs = 0.f;
        #pragma unroll
        for (int f = 0; f < 4; ++f)
            #pragma unroll
            for (int r = 0; r < 4; ++r) {
                float pv = __expf(tf[f][r] - m_new);
                tf[f][r] = pv;
                rs += pv;
            }
        rs += __shfl_xor(rs, 16);
        rs += __shfl_xor(rs, 32);
        l_run = l_run * scale + rs;
        m_run = m_new;

        float sc[4];
        #pragma unroll
        for (int r = 0; r < 4; ++r) sc[r] = __shfl(scale, 4 * lkg + r);
        #pragma unroll
        for (int h = 0; h < 2; ++h)
            #pragma unroll
            for (int r = 0; r < 4; ++r) acc[h][r] *= sc[r];

        #pragma unroll
        for (int f = 0; f < 4; ++f) {
            *(uint_t*)&sP[wave][lq * 40 + f * 16 + 4 * lkg]     = pack_bf16(tf[f][0], tf[f][1]);
            *(uint_t*)&sP[wave][lq * 40 + f * 16 + 4 * lkg + 2] = pack_bf16(tf[f][2], tf[f][3]);
        }

        #pragma unroll
        for (int mc = 0; mc < 2; ++mc) {
            bf16x8 pf = *(const bf16x8*)&sP[wave][lq * 40 + mc * 32 + 8 * lkg];
            #pragma unroll
            for (int h = 0; h < 2; ++h) {
                bf16x8 vf = *(const bf16x8*)(gT + ((size_t)b4 * 32 + h * 16 + lq) * N
                                             + m0 + mc * 32 + 8 * lkg);
                acc[h] = __builtin_amdgcn_mfma_f32_16x16x32_bf16(pf, vf, acc[h], 0, 0, 0);
            }
        }
    }

    #pragma unroll
    for (int h = 0; h < 2; ++h) {
        #pragma unroll
        for (int r = 0; r < 4; ++r) {
            int q = q0w + 4 * lkg + r;
            partO[(((size_t)ks * 4 + b4) * N + q) * 32 + h * 16 + lq] = acc[h][r];
        }
    }
    if (lane < 16) {
        size_t mlo = (((size_t)ks * 4 + b4) * N + q0w + lq) * 2;
        partML[mlo]     = m_run;
        partML[mlo + 1] = l_run;
    }
}

// ===========================================================================
// Fused flash-combine + non-local merge (4-batch):
// out = 2*e + W*(softmax-combined y) [+ u]. Thread per (b4, 16-co group, n).
// ===========================================================================
__global__ __launch_bounds__(256) void nl_merge_fused(const float* __restrict__ e,
    const float* __restrict__ partO, const float* __restrict__ partML,
    const float* __restrict__ u,
    const float* __restrict__ ww, const float* __restrict__ wb,
    float* __restrict__ out, int N, int KVS)
{
    __shared__ float sw[64 * 32];
    __shared__ float sb[64];
    int tid = threadIdx.x;
    for (int i = tid; i < 2048; i += 256) sw[i] = ww[i];
    if (tid < 64) sb[tid] = wb[tid];
    __syncthreads();
    int idx = blockIdx.x * 256 + tid;
    int n = idx % N;
    int cog = (idx / N) & 3;
    int b4 = idx / (4 * N);

    float mstar = -1e30f;
    for (int ks = 0; ks < KVS; ++ks)
        mstar = fmaxf(mstar, partML[(((size_t)ks * 4 + b4) * N + n) * 2]);
    float denom = 0.f;
    float yv[32];
    #pragma unroll
    for (int c = 0; c < 32; ++c) yv[c] = 0.f;
    for (int ks = 0; ks < KVS; ++ks) {
        size_t mlo = (((size_t)ks * 4 + b4) * N + n) * 2;
        float w = __expf(partML[mlo] - mstar);
        denom += w * partML[mlo + 1];
        const f32x4* op = (const f32x4*)(partO + (((size_t)ks * 4 + b4) * N + n) * 32);
        #pragma unroll
        for (int jj = 0; jj < 8; ++jj) {
            f32x4 v = op[jj];
            #pragma unroll
            for (int t = 0; t < 4; ++t) yv[4 * jj + t] = fmaf(w, v[t], yv[4 * jj + t]);
        }
    }
    float inv = 1.f / denom;
    #pragma unroll
    for (int i = 0; i < 16; ++i) {
        int co = cog * 16 + i;
        float dot = 0.f;
        const float* wr = &sw[co * 32];
        #pragma unroll
        for (int c = 0; c < 32; ++c) dot = fmaf(wr[c], yv[c], dot);
        size_t o = (size_t)b4 * 64 * N + (size_t)co * N + n;
        float r = sb[co] + inv * dot + 2.f * e[o];
        if (u) r += u[o];
        out[o] = r;
    }
}

// ===========================================================================
// Deformable conv (NHWC input, precomputed sampling params, bf16 MFMA).
// Per-s launch: b in {0,1}. Unchanged from round 7.
// ===========================================================================
__global__ __launch_bounds__(256) void deform_mfma3(const float* __restrict__ xT,
    const float* __restrict__ est, const ushort_t* __restrict__ wbf,
    const float* __restrict__ bias, float* __restrict__ out)
{
    const int H = 128, W = 128, HW = 16384;
    const int BS = 296;
    __shared__ ushort_t sB[64 * BS];
    __shared__ float4 sW[576];
    __shared__ uint2  sO[576];
    int tile = blockIdx.x & 255;
    int b    = blockIdx.x >> 8;
    int p0   = tile * 64;
    int tid  = threadIdx.x;

    const float* eb = est + (size_t)b * 27 * HW;
    for (int i = tid; i < 576; i += 256) {
        int k = i >> 6, j = i & 63;
        int p = p0 + j;
        int yy = p >> 7, xx = p & 127;
        float oy = eb[(size_t)(9 + 2 * k) * HW + p];
        float ox = eb[(size_t)(10 + 2 * k) * HW + p];
        float mv = eb[(size_t)k * HW + p];
        float mk = 1.f / (1.f + __expf(-mv));
        float py = (float)(yy + (k / 3) - 1) + oy;
        float qx = (float)(xx + (k % 3) - 1) + ox;
        float fy0 = floorf(py), fx0 = floorf(qx);
        float wy = py - fy0, wx = qx - fx0;
        int y0 = (int)fy0, x0 = (int)fx0;
        int y1 = y0 + 1, x1 = x0 + 1;
        bool yv0 = (y0 >= 0) && (y0 < H), yv1 = (y1 >= 0) && (y1 < H);
        bool xv0 = (x0 >= 0) && (x0 < W), xv1 = (x1 >= 0) && (x1 < W);
        int y0c = min(max(y0, 0), H - 1), y1c = min(max(y1, 0), H - 1);
        int x0c = min(max(x0, 0), W - 1), x1c = min(max(x1, 0), W - 1);
        float4 w4;
        w4.x = (yv0 && xv0) ? (1.f - wy) * (1.f - wx) * mk : 0.f;
        w4.y = (yv0 && xv1) ? (1.f - wy) * wx * mk : 0.f;
        w4.z = (yv1 && xv0) ? wy * (1.f - wx) * mk : 0.f;
        w4.w = (yv1 && xv1) ? wy * wx * mk : 0.f;
        sW[i] = w4;
        uint_t o00 = (uint_t)(y0c * W + x0c), o01 = (uint_t)(y0c * W + x1c);
        uint_t o10 = (uint_t)(y1c * W + x0c), o11 = (uint_t)(y1c * W + x1c);
        sO[i] = (uint2){ o00 | (o01 << 16), o10 | (o11 << 16) };
    }

    int wave = tid >> 6, lane = tid & 63;
    int co_base = wave * 32;
    int lrow = lane & 15, lkg = lane >> 4;

    f32x4 acc[2][4];
    #pragma unroll
    for (int m2 = 0; m2 < 2; ++m2)
        #pragma unroll
        for (int n2 = 0; n2 < 4; ++n2) acc[m2][n2] = (f32x4){0.f, 0.f, 0.f, 0.f};

    const f32x4* xb4 = (const f32x4*)(xT + (size_t)b * HW * 128);

    for (int cc = 0; cc < 128; cc += 32) {
        __syncthreads();
        #pragma unroll 2
        for (int it = 0; it < 18; ++it) {
            int task = it * 256 + tid;
            int cg = task & 7;
            int si = task >> 3;
            float4 w4 = sW[si];
            uint2 o4 = sO[si];
            int chv = (cc >> 2) + cg;
            f32x4 c00 = xb4[(o4.x & 0xFFFFu) * 32 + chv];
            f32x4 c01 = xb4[(o4.x >> 16) * 32 + chv];
            f32x4 c10 = xb4[(o4.y & 0xFFFFu) * 32 + chv];
            f32x4 c11 = xb4[(o4.y >> 16) * 32 + chv];
            f32x4 v;
            #pragma unroll
            for (int j = 0; j < 4; ++j)
                v[j] = w4.x * c00[j] + w4.y * c01[j] + w4.z * c10[j] + w4.w * c11[j];
            int pxl = si & 63, tap = si >> 6;
            uint2 pk;
            pk.x = pack_bf16(v[0], v[1]);
            pk.y = pack_bf16(v[2], v[3]);
            *(uint2*)&sB[pxl * BS + tap * 32 + cg * 4] = pk;
        }
        __syncthreads();
        int kbase = cc * 9;
        #pragma unroll
        for (int ks = 0; ks < 9; ++ks) {
            bf16x8 afr[2], bfr[4];
            #pragma unroll
            for (int m2 = 0; m2 < 2; ++m2)
                afr[m2] = *reinterpret_cast<const bf16x8*>(
                    wbf + (size_t)(co_base + m2 * 16 + lrow) * 1152 + kbase + ks * 32 + lkg * 8);
            #pragma unroll
            for (int n2 = 0; n2 < 4; ++n2)
                bfr[n2] = *reinterpret_cast<const bf16x8*>(
                    &sB[(n2 * 16 + lrow) * BS + ks * 32 + lkg * 8]);
            #pragma unroll
            for (int m2 = 0; m2 < 2; ++m2)
                #pragma unroll
                for (int n2 = 0; n2 < 4; ++n2)
                    acc[m2][n2] = __builtin_amdgcn_mfma_f32_16x16x32_bf16(
                        afr[m2], bfr[n2], acc[m2][n2], 0, 0, 0);
        }
    }

    #pragma unroll
    for (int m2 = 0; m2 < 2; ++m2) {
        #pragma unroll
        for (int j = 0; j < 4; ++j) {
            int co = co_base + m2 * 16 + lkg * 4 + j;
            float bb = bias[co];
            #pragma unroll
            for (int n2 = 0; n2 < 4; ++n2) {
                int px = p0 + n2 * 16 + lrow;
                out[((size_t)(b * 128 + co)) * HW + px] = acc[m2][n2][j] + bb;
            }
        }
    }
}

extern "C" void kernel_launch(void* const* d_in, const int* in_sizes, int n_in,
                              void* d_out, int out_size, void* d_ws, size_t ws_size,
                              hipStream_t stream)
{
    const float* x_all     = (const float*)d_in[0];
    const float* ms_fine   = (const float*)d_in[1];
    const float* ms_coarse = (const float*)d_in[2];
    const float* enc_w0 = (const float*)d_in[3];
    const float* enc_b0 = (const float*)d_in[4];
    const float* enc_w1 = (const float*)d_in[5];
    const float* enc_b1 = (const float*)d_in[6];
    const float* nl_tw[2] = { (const float*)d_in[7],  (const float*)d_in[15] };
    const float* nl_tb[2] = { (const float*)d_in[8],  (const float*)d_in[16] };
    const float* nl_pw[2] = { (const float*)d_in[9],  (const float*)d_in[17] };
    const float* nl_pb[2] = { (const float*)d_in[10], (const float*)d_in[18] };
    const float* nl_gw[2] = { (const float*)d_in[11], (const float*)d_in[19] };
    const float* nl_gb[2] = { (const float*)d_in[12], (const float*)d_in[20] };
    const float* nl_ww[2] = { (const float*)d_in[13], (const float*)d_in[21] };
    const float* nl_wb[2] = { (const float*)d_in[14], (const float*)d_in[22] };
    const float* dec_w0 = (const float*)d_in[23];
    const float* dec_b0 = (const float*)d_in[24];
    const float* dec_w1 = (const float*)d_in[25];
    const float* dec_b1 = (const float*)d_in[26];
    const float* off_w  = (const float*)d_in[27];
    const float* off_b  = (const float*)d_in[28];
    const float* dcn_w  = (const float*)d_in[29];
    const float* dcn_b  = (const float*)d_in[30];

    // ---- workspace layout (floats), lifetime-overlaid; total ~9.95M f ≈ 40 MB
    float* ws = (float*)d_ws;
    ushort_t* wbf     = (ushort_t*)ws;            // 147456 u
    ushort_t* w2_enc0 = wbf + 147456;             // 294912 u
    ushort_t* w2_enc1 = w2_enc0 + 294912;         // 147456 u
    ushort_t* w2_dec0 = w2_enc1 + 147456;         // 36864 u
    ushort_t* w2_dec1 = w2_dec0 + 36864;          // 36864 u
    ushort_t* w2_est  = w2_dec1 + 36864;          // 36864 u  (ends 700416 u = 350208 f)
    float* U1      = ws + 350208;                 // 1048576 (e0/th0set/m0 | th1set | m1)
    float* u0      = U1 + 1048576;                // 1048576
    float* e1      = u0 + 1048576;                // 1048576
    float* partML  = e1 + 1048576;                // 163840
    float* regPart = partML + 163840;             // 2097152 (partial | partO0 | partO1 | est)
    float* regMot  = regPart + 2097152;           // 4194304 (mot | xT)

    float* e0 = U1;                               // [4][64][1024]
    ushort_t* thT0 = (ushort_t*)(U1 + 262144);    // [4][1024][32]
    ushort_t* phT0 = thT0 + 131072;
    ushort_t* gT0  = phT0 + 131072;
    float* m0 = U1 + 458752;                      // [4][64][1024]
    ushort_t* thT1 = (ushort_t*)U1;               // [4][4096][32]
    ushort_t* phT1 = thT1 + 524288;
    ushort_t* gT1  = phT1 + 524288;
    float* m1  = U1;                              // [4][64][4096]
    float* mot = regMot;                          // [4][64][16384]
    float* xT  = regMot;                          // [2][16384][128] per s
    float* est = regPart;                         // [4][27][16384]

    float* out = (float*)d_out;
    const size_t frame  = (size_t)2 * 128 * 128 * 128;      // fine frame
    const size_t cframe = (size_t)2 * 256 * 64 * 64;        // coarse frame

    hipMemcpyAsync(out, x_all, frame * sizeof(float), hipMemcpyDeviceToDevice, stream);

    // ---- one-time weight prep
    castw_perm_kernel<<<(147456 + 255) / 256, 256, 0, stream>>>(dcn_w, wbf);
    castw2_kernel<<<(64 * 4608 + 255) / 256, 256, 0, stream>>>(enc_w0, w2_enc0, 64, 512, 4608, 0);
    castw2_kernel<<<(64 * 2304 + 255) / 256, 256, 0, stream>>>(enc_w1, w2_enc1, 64, 256, 2304, 0);
    castw2_kernel<<<(64 * 576 + 255) / 256, 256, 0, stream>>>(dec_w0, w2_dec0, 64, 64, 576, 1);
    castw2_kernel<<<(64 * 576 + 255) / 256, 256, 0, stream>>>(dec_w1, w2_dec1, 64, 64, 576, 1);
    castw2_kernel<<<(64 * 576 + 255) / 256, 256, 0, stream>>>(off_w, w2_est, 27, 64, 576, 0);

    // ==== batched motion pipeline: b4 = s_idx*2 + b, s = s_idx+1 ====

    // e0 = lrelu(conv3x3 s2 (pc||cc; 512->64)) : [4][64][1024]
    conv3x3_mfma<2, 0><<<4 * 16 * 8, 256, 0, stream>>>(
        ms_coarse + cframe, ms_coarse, 256, cframe, 64, 64, 512,
        w2_enc0, 4608, 32, 1024, 16, 8, 18, regPart, nullptr, 0, 0, nullptr);
    reduce_bias_act<<<1024, 256, 0, stream>>>(regPart, enc_b0, e0, 64, 1024, 8, 1);

    // non-local 0 (N=1024, KVS=8)
    conv1x1x3_bf16<<<48, 256, 0, stream>>>(e0, 1024,
        nl_tw[0], nl_tb[0], nl_pw[0], nl_pb[0], nl_gw[0], nl_gb[0], thT0, phT0, gT0);
    attn_flash<<<4 * 16 * 8, 256, 0, stream>>>(thT0, phT0, gT0, regPart, partML, 1024, 8);
    nl_merge_fused<<<64, 256, 0, stream>>>(e0, regPart, partML, nullptr,
        nl_ww[0], nl_wb[0], m0, 1024, 8);

    // u0 = lrelu(deconv(m0)) : [4][64][4096]  (direct parity-masked deconv)
    conv3x3_mfma<1, 1><<<4 * 64 * 2, 256, 0, stream>>>(
        m0, m0, 64, (size_t)2 * 64 * 1024, 32, 32, 64,
        w2_dec0, 576, 64, 4096, 64, 2, 9, regPart, nullptr, 0, 0, nullptr);
    reduce_bias_act<<<4096, 256, 0, stream>>>(regPart, dec_b0, u0, 64, 4096, 2, 1);

    // e1 = lrelu(conv3x3 s2 (pf||cf; 256->64)) : [4][64][4096]
    conv3x3_mfma<2, 0><<<4 * 64 * 2, 256, 0, stream>>>(
        ms_fine + frame, ms_fine, 128, frame, 128, 128, 256,
        w2_enc1, 2304, 64, 4096, 64, 2, 36, regPart, nullptr, 0, 0, nullptr);
    reduce_bias_act<<<4096, 256, 0, stream>>>(regPart, enc_b1, e1, 64, 4096, 2, 1);

    // non-local 1 (N=4096, KVS=4)
    conv1x1x3_bf16<<<192, 256, 0, stream>>>(e1, 4096,
        nl_tw[1], nl_tb[1], nl_pw[1], nl_pb[1], nl_gw[1], nl_gb[1], thT1, phT1, gT1);
    attn_flash<<<4 * 64 * 4, 256, 0, stream>>>(thT1, phT1, gT1, regPart, partML, 4096, 4);
    nl_merge_fused<<<256, 256, 0, stream>>>(e1, regPart, partML, u0,
        nl_ww[1], nl_wb[1], m1, 4096, 4);

    // mot = lrelu(deconv(m1)) : [4][64][16384]  (fused epilogue)
    conv3x3_mfma<1, 1><<<4 * 256, 256, 0, stream>>>(
        m1, m1, 64, (size_t)2 * 64 * 4096, 64, 64, 64,
        w2_dec1, 576, 128, 16384, 256, 1, 18, regPart, dec_b1, 1, 64, mot);

    // est = conv3x3 s1 (mot; 64->27) : [4][27][16384]  (fused epilogue)
    conv3x3_mfma<1, 0><<<4 * 256, 256, 0, stream>>>(
        mot, mot, 64, (size_t)2 * 64 * 16384, 128, 128, 64,
        w2_est, 576, 128, 16384, 256, 1, 18, regPart, off_b, 0, 27, est);

    // ==== per-s: transpose + deformable conv ====
    for (int s = 1; s < 3; ++s) {
        transpose_nhwc_kernel<<<4096, 256, 0, stream>>>(x_all + (size_t)s * frame, xT);
        deform_mfma3<<<512, 256, 0, stream>>>(
            xT, est + (size_t)(s - 1) * 2 * 27 * 16384, wbf, dcn_b,
            out + (size_t)s * frame);
    }
}

// Round 10
// 378.793 us; speedup vs baseline: 13.8388x; 1.0453x over previous
//
#include <hip/hip_runtime.h>
#include <math.h>

typedef __attribute__((ext_vector_type(8))) short bf16x8;
typedef __attribute__((ext_vector_type(4))) float f32x4;
typedef unsigned short ushort_t;
typedef unsigned int uint_t;

__device__ __forceinline__ float lrelu_f(float x) { return x >= 0.f ? x : 0.01f * x; }

__device__ __forceinline__ ushort_t f2bf(float f) {
    uint_t x = __float_as_uint(f);
    uint_t r = (x + 0x7fffu + ((x >> 16) & 1u)) >> 16;
    return (ushort_t)r;
}

__device__ __forceinline__ uint_t pack_bf16(float lo, float hi) {
    uint_t out;
    asm("v_cvt_pk_bf16_f32 %0, %1, %2" : "=v"(out) : "v"(lo), "v"(hi));
    return out;
}

// ===========================================================================
// Weight prep: w2[co64][K'] bf16, channel-block-major K ordering:
// K' = cb*288 + tap*32 + cl, ci = cb*32+cl. co padded to 64 with zeros.
// ===========================================================================
__global__ __launch_bounds__(256) void castw2_kernel(const float* __restrict__ w,
    ushort_t* __restrict__ w2, int Cout, int Cin, int K, int deconv)
{
    int idx = blockIdx.x * 256 + threadIdx.x;
    if (idx >= 64 * K) return;
    int co = idx / K, kp = idx % K;
    int cb = kp / 288;
    int r  = kp % 288;
    int tap = r >> 5, cl = r & 31;
    int ci = cb * 32 + cl;
    float val = 0.f;
    if (co < Cout)
        val = deconv ? w[(size_t)(ci * Cout + co) * 9 + (8 - tap)]
                     : w[(size_t)(co * Cin + ci) * 9 + tap];
    w2[idx] = f2bf(val);
}

// ===========================================================================
// bf16 MFMA implicit-GEMM 3x3 conv over 4-batch (2 s-iters x 2 b).
// K is channel-block-major: chunk = (cb, tap) with tap inner -> 9 consecutive
// chunks reuse the same 32 channels' input rows (L1/L2-hot).
// MODE 0: strided conv pad 1 (masked clamp). MODE 1: stride-2 transposed conv
// (parity-masked direct reads). bias!=nullptr (ksplit==1): fused epilogue.
// ===========================================================================
template<int STRIDE, int MODE>
__global__ __launch_bounds__(256) void conv3x3_mfma(
    const float* __restrict__ inA, const float* __restrict__ inB, int CinA,
    size_t sStrideA, int Hin, int Win, int Cin,
    const ushort_t* __restrict__ w2, int K,
    int Wout, int Npx, int tilesPerMap, int ksplit, int chunksPerKs,
    float* __restrict__ part,
    const float* __restrict__ bias, int act, int CoutStore, float* __restrict__ outDirect)
{
    __shared__ ushort_t sB[64 * 40];
    int tile = blockIdx.x % tilesPerMap;
    int ks   = (blockIdx.x / tilesPerMap) % ksplit;
    int b4   = blockIdx.x / (tilesPerMap * ksplit);
    int s_idx = b4 >> 1, bb = b4 & 1;
    int tid  = threadIdx.x;
    int wave = tid >> 6, lane = tid & 63;
    int lrow = lane & 15, lkg = lane >> 4;
    int px  = tid & 63;
    int cio = wave * 8;
    int p   = tile * 64 + px;
    int oy  = p / Wout, ox = p - oy * Wout;
    int HWin = Hin * Win;
    int CinB = Cin - CinA;

    f32x4 acc[4];
    #pragma unroll
    for (int n2 = 0; n2 < 4; ++n2) acc[n2] = (f32x4){0.f, 0.f, 0.f, 0.f};

    for (int cch = 0; cch < chunksPerKs; ++cch) {
        int chunkIdx = ks * chunksPerKs + cch;
        int cb  = chunkIdx / 9;
        int tap = chunkIdx - cb * 9;
        int cib = cb * 32;
        int ky = tap / 3, kx = tap - ky * 3;
        float msk;
        int offp;
        if (MODE == 0) {
            int iy = oy * STRIDE - 1 + ky;
            int ix = ox * STRIDE - 1 + kx;
            bool vld = (iy >= 0) && (iy < Hin) && (ix >= 0) && (ix < Win);
            msk = vld ? 1.f : 0.f;
            offp = min(max(iy, 0), Hin - 1) * Win + min(max(ix, 0), Win - 1);
        } else {
            int uy = oy + ky, ux = ox + kx;
            int r = (uy - 1) >> 1, q = (ux - 1) >> 1;
            bool vld = (uy & 1) && (ux & 1) && (r < Hin) && (q < Win);
            msk = vld ? 1.f : 0.f;
            offp = min(max(r, 0), Hin - 1) * Win + min(max(q, 0), Win - 1);
        }
        int c = cib + cio;
        const float* src = (c < CinA)
            ? inA + s_idx * sStrideA + (size_t)(bb * CinA + c) * HWin
            : inB + (size_t)(bb * CinB + (c - CinA)) * HWin;
        float v[8];
        #pragma unroll
        for (int j = 0; j < 8; ++j) v[j] = src[(size_t)j * HWin + offp] * msk;
        uint4 pk;
        pk.x = pack_bf16(v[0], v[1]);
        pk.y = pack_bf16(v[2], v[3]);
        pk.z = pack_bf16(v[4], v[5]);
        pk.w = pack_bf16(v[6], v[7]);
        __syncthreads();
        *(uint4*)&sB[px * 40 + cio] = pk;
        __syncthreads();

        const ushort_t* wr = w2 + (size_t)(wave * 16 + lrow) * K + chunkIdx * 32 + lkg * 8;
        bf16x8 afr = *(const bf16x8*)wr;
        #pragma unroll
        for (int n2 = 0; n2 < 4; ++n2) {
            bf16x8 bfr = *(const bf16x8*)&sB[(n2 * 16 + lrow) * 40 + lkg * 8];
            acc[n2] = __builtin_amdgcn_mfma_f32_16x16x32_bf16(afr, bfr, acc[n2], 0, 0, 0);
        }
    }

    if (bias) {
        #pragma unroll
        for (int n2 = 0; n2 < 4; ++n2) {
            #pragma unroll
            for (int j = 0; j < 4; ++j) {
                int co = wave * 16 + lkg * 4 + j;
                if (co < CoutStore) {
                    int pp = tile * 64 + n2 * 16 + lrow;
                    float r = acc[n2][j] + bias[co];
                    if (act) r = lrelu_f(r);
                    outDirect[((size_t)(b4 * CoutStore + co)) * (size_t)Npx + pp] = r;
                }
            }
        }
    } else {
        #pragma unroll
        for (int n2 = 0; n2 < 4; ++n2) {
            #pragma unroll
            for (int j = 0; j < 4; ++j) {
                int co = wave * 16 + lkg * 4 + j;
                int pp = tile * 64 + n2 * 16 + lrow;
                part[((size_t)(ks * 4 + b4) * 64 + co) * (size_t)Npx + pp] = acc[n2][j];
            }
        }
    }
}

// 4-batch: out[b4][co][p] = act(bias[co] + sum_ks part[ks][b4][co][p])
__global__ __launch_bounds__(256) void reduce_bias_act(const float* __restrict__ part,
    const float* __restrict__ bias, float* __restrict__ out,
    int Cout, int Npx, int ksplit, int act)
{
    int idx = blockIdx.x * 256 + threadIdx.x;
    int total = 4 * Cout * Npx;
    if (idx >= total) return;
    int p  = idx % Npx;
    int co = (idx / Npx) % Cout;
    int b4 = idx / (Npx * Cout);
    float s = bias[co];
    for (int ks = 0; ks < ksplit; ++ks)
        s += part[(((size_t)ks * 4 + b4) * 64 + co) * (size_t)Npx + p];
    if (act) s = lrelu_f(s);
    out[((size_t)b4 * Cout + co) * (size_t)Npx + p] = s;
}

__global__ __launch_bounds__(256) void castw_perm_kernel(const float* __restrict__ w,
    ushort_t* __restrict__ wbf)
{
    int idx = blockIdx.x * 256 + threadIdx.x;
    if (idx >= 147456) return;
    int co = idx / 1152;
    int r  = idx % 1152;
    int chunk = r / 288;
    int r2 = r % 288;
    int tap = r2 >> 5;
    int cl  = r2 & 31;
    int ci = chunk * 32 + cl;
    wbf[idx] = f2bf(w[(size_t)co * 1152 + ci * 9 + tap]);
}

// NCHW frame [2][128][16384] -> NHWC [2][16384][128]
__global__ __launch_bounds__(256) void transpose_nhwc_kernel(const float* __restrict__ x,
    float* __restrict__ xT)
{
    __shared__ float t[32][33];
    int cT = blockIdx.x & 3;
    int pT = (blockIdx.x >> 2) & 511;
    int b  = blockIdx.x >> 11;
    int tx = threadIdx.x & 31, ty = threadIdx.x >> 5;
    const float* src = x + ((size_t)b * 128 + cT * 32) * 16384 + (size_t)pT * 32;
    #pragma unroll
    for (int i = 0; i < 4; ++i)
        t[ty + 8 * i][tx] = src[(size_t)(ty + 8 * i) * 16384 + tx];
    __syncthreads();
    float* dst = xT + ((size_t)b * 16384 + (size_t)pT * 32) * 128 + cT * 32;
    #pragma unroll
    for (int i = 0; i < 4; ++i)
        dst[(size_t)(ty + 8 * i) * 128 + tx] = t[tx][ty + 8 * i];
}

// ---------------------------------------------------------------------------
// Fused 1x1 convs -> bf16 attention operands, 4-batch. One thread per
// (slice j, b4, n); j uniform per block.
// ---------------------------------------------------------------------------
__global__ __launch_bounds__(256) void conv1x1x3_bf16(const float* __restrict__ e, int N,
    const float* __restrict__ tw, const float* __restrict__ tb,
    const float* __restrict__ pw, const float* __restrict__ pb,
    const float* __restrict__ gw, const float* __restrict__ gb,
    ushort_t* __restrict__ thT, ushort_t* __restrict__ phT, ushort_t* __restrict__ gT)
{
    __shared__ float sw[32 * 64];
    __shared__ float sb[32];
    int tid = threadIdx.x;
    int idx = blockIdx.x * 256 + tid;
    int j = idx / (4 * N);
    const float* wsel = (j == 0) ? tw : (j == 1) ? pw : gw;
    const float* bsel = (j == 0) ? tb : (j == 1) ? pb : gb;
    for (int i = tid; i < 2048; i += 256) sw[i] = wsel[i];
    if (tid < 32) sb[tid] = bsel[tid];
    __syncthreads();
    int rem = idx - j * 4 * N;
    int n = rem % N, b4 = rem / N;
    float ein[64];
    const float* ep = e + (size_t)b4 * 64 * N + n;
    #pragma unroll
    for (int ci = 0; ci < 64; ++ci) ein[ci] = ep[(size_t)ci * N];

    float val[32];
    #pragma unroll
    for (int cc = 0; cc < 32; ++cc) {
        float acc = sb[cc];
        const float* wr = &sw[cc * 64];
        #pragma unroll
        for (int ci = 0; ci < 64; ++ci) acc = fmaf(wr[ci], ein[ci], acc);
        val[cc] = acc;
    }
    if (j < 2) {
        ushort_t* row = (j == 0 ? thT : phT) + ((size_t)b4 * N + n) * 32;
        #pragma unroll
        for (int w4 = 0; w4 < 4; ++w4) {
            uint4 pk;
            pk.x = pack_bf16(val[8 * w4 + 0], val[8 * w4 + 1]);
            pk.y = pack_bf16(val[8 * w4 + 2], val[8 * w4 + 3]);
            pk.z = pack_bf16(val[8 * w4 + 4], val[8 * w4 + 5]);
            pk.w = pack_bf16(val[8 * w4 + 6], val[8 * w4 + 7]);
            *(uint4*)(row + 8 * w4) = pk;
        }
    } else {
        #pragma unroll
        for (int cc = 0; cc < 32; ++cc)
            gT[((size_t)b4 * 32 + cc) * N + n] = f2bf(val[cc]);
    }
}

// ===========================================================================
// Flash split-K MFMA attention, 4-batch, fragments direct from global.
// ===========================================================================
__global__ __launch_bounds__(256) void attn_flash(const ushort_t* __restrict__ thT,
    const ushort_t* __restrict__ phT, const ushort_t* __restrict__ gT,
    float* __restrict__ partO, float* __restrict__ partML, int N, int KVS)
{
    __shared__ ushort_t sP[4][16 * 40];
    int tid  = threadIdx.x;
    int wave = tid >> 6, lane = tid & 63;
    int lq = lane & 15, lkg = lane >> 4;
    int nqb = N / 64;
    int ks = blockIdx.x % KVS;
    int qb = (blockIdx.x / KVS) % nqb;
    int b4 = blockIdx.x / (KVS * nqb);
    int q0w = qb * 64 + wave * 16;
    int chunk = N / KVS;
    int m_start = ks * chunk;

    bf16x8 qf = *(const bf16x8*)(thT + ((size_t)b4 * N + q0w + lq) * 32 + 8 * lkg);

    float m_run = -1e30f, l_run = 0.f;
    f32x4 acc[2];
    acc[0] = (f32x4){0.f, 0.f, 0.f, 0.f};
    acc[1] = (f32x4){0.f, 0.f, 0.f, 0.f};

    for (int m0 = m_start; m0 < m_start + chunk; m0 += 64) {
        f32x4 tf[4];
        #pragma unroll
        for (int f = 0; f < 4; ++f) {
            bf16x8 kf = *(const bf16x8*)(phT + ((size_t)b4 * N + m0 + f * 16 + lq) * 32 + 8 * lkg);
            tf[f] = __builtin_amdgcn_mfma_f32_16x16x32_bf16(kf, qf,
                        (f32x4){0.f, 0.f, 0.f, 0.f}, 0, 0, 0);
        }

        float mx = -1e30f;
        #pragma unroll
        for (int f = 0; f < 4; ++f)
            #pragma unroll
            for (int r = 0; r < 4; ++r) mx = fmaxf(mx, tf[f][r]);
        mx = fmaxf(mx, __shfl_xor(mx, 16));
        mx = fmaxf(mx, __shfl_xor(mx, 32));
        float m_new = fmaxf(m_run, mx);
        float scale = __expf(m_run - m_new);
        float rs = 0.f;
        #pragma unroll
        for (int f = 0; f < 4; ++f)
            #pragma unroll
            for (int r = 0; r < 4; ++r) {
                float pv = __expf(tf[f][r] - m_new);
                tf[f][r] = pv;
                rs += pv;
            }
        rs += __shfl_xor(rs, 16);
        rs += __shfl_xor(rs, 32);
        l_run = l_run * scale + rs;
        m_run = m_new;

        float sc[4];
        #pragma unroll
        for (int r = 0; r < 4; ++r) sc[r] = __shfl(scale, 4 * lkg + r);
        #pragma unroll
        for (int h = 0; h < 2; ++h)
            #pragma unroll
            for (int r = 0; r < 4; ++r) acc[h][r] *= sc[r];

        #pragma unroll
        for (int f = 0; f < 4; ++f) {
            *(uint_t*)&sP[wave][lq * 40 + f * 16 + 4 * lkg]     = pack_bf16(tf[f][0], tf[f][1]);
            *(uint_t*)&sP[wave][lq * 40 + f * 16 + 4 * lkg + 2] = pack_bf16(tf[f][2], tf[f][3]);
        }

        #pragma unroll
        for (int mc = 0; mc < 2; ++mc) {
            bf16x8 pf = *(const bf16x8*)&sP[wave][lq * 40 + mc * 32 + 8 * lkg];
            #pragma unroll
            for (int h = 0; h < 2; ++h) {
                bf16x8 vf = *(const bf16x8*)(gT + ((size_t)b4 * 32 + h * 16 + lq) * N
                                             + m0 + mc * 32 + 8 * lkg);
                acc[h] = __builtin_amdgcn_mfma_f32_16x16x32_bf16(pf, vf, acc[h], 0, 0, 0);
            }
        }
    }

    #pragma unroll
    for (int h = 0; h < 2; ++h) {
        #pragma unroll
        for (int r = 0; r < 4; ++r) {
            int q = q0w + 4 * lkg + r;
            partO[(((size_t)ks * 4 + b4) * N + q) * 32 + h * 16 + lq] = acc[h][r];
        }
    }
    if (lane < 16) {
        size_t mlo = (((size_t)ks * 4 + b4) * N + q0w + lq) * 2;
        partML[mlo]     = m_run;
        partML[mlo + 1] = l_run;
    }
}

// ===========================================================================
// Fused flash-combine + non-local merge (4-batch).
// ===========================================================================
__global__ __launch_bounds__(256) void nl_merge_fused(const float* __restrict__ e,
    const float* __restrict__ partO, const float* __restrict__ partML,
    const float* __restrict__ u,
    const float* __restrict__ ww, const float* __restrict__ wb,
    float* __restrict__ out, int N, int KVS)
{
    __shared__ float sw[64 * 32];
    __shared__ float sb[64];
    int tid = threadIdx.x;
    for (int i = tid; i < 2048; i += 256) sw[i] = ww[i];
    if (tid < 64) sb[tid] = wb[tid];
    __syncthreads();
    int idx = blockIdx.x * 256 + tid;
    int n = idx % N;
    int cog = (idx / N) & 3;
    int b4 = idx / (4 * N);

    float mstar = -1e30f;
    for (int ks = 0; ks < KVS; ++ks)
        mstar = fmaxf(mstar, partML[(((size_t)ks * 4 + b4) * N + n) * 2]);
    float denom = 0.f;
    float yv[32];
    #pragma unroll
    for (int c = 0; c < 32; ++c) yv[c] = 0.f;
    for (int ks = 0; ks < KVS; ++ks) {
        size_t mlo = (((size_t)ks * 4 + b4) * N + n) * 2;
        float w = __expf(partML[mlo] - mstar);
        denom += w * partML[mlo + 1];
        const f32x4* op = (const f32x4*)(partO + (((size_t)ks * 4 + b4) * N + n) * 32);
        #pragma unroll
        for (int jj = 0; jj < 8; ++jj) {
            f32x4 v = op[jj];
            #pragma unroll
            for (int t = 0; t < 4; ++t) yv[4 * jj + t] = fmaf(w, v[t], yv[4 * jj + t]);
        }
    }
    float inv = 1.f / denom;
    #pragma unroll
    for (int i = 0; i < 16; ++i) {
        int co = cog * 16 + i;
        float dot = 0.f;
        const float* wr = &sw[co * 32];
        #pragma unroll
        for (int c = 0; c < 32; ++c) dot = fmaf(wr[c], yv[c], dot);
        size_t o = (size_t)b4 * 64 * N + (size_t)co * N + n;
        float r = sb[co] + inv * dot + 2.f * e[o];
        if (u) r += u[o];
        out[o] = r;
    }
}

// ===========================================================================
// Deformable conv (NHWC input, precomputed sampling params, bf16 MFMA).
// XCD-aware block swizzle (512 blocks, 8 XCDs -> 64 contiguous tiles/XCD).
// ===========================================================================
__global__ __launch_bounds__(256) void deform_mfma3(const float* __restrict__ xT,
    const float* __restrict__ est, const ushort_t* __restrict__ wbf,
    const float* __restrict__ bias, float* __restrict__ out)
{
    const int H = 128, W = 128, HW = 16384;
    const int BS = 296;
    __shared__ ushort_t sB[64 * BS];
    __shared__ float4 sW[576];
    __shared__ uint2  sO[576];
    int id  = blockIdx.x;                       // 512 blocks, 512 % 8 == 0
    int lin = (id & 7) * 64 + (id >> 3);        // bijective XCD-chunked remap
    int tile = lin & 255;
    int b    = lin >> 8;
    int p0   = tile * 64;
    int tid  = threadIdx.x;

    const float* eb = est + (size_t)b * 27 * HW;
    for (int i = tid; i < 576; i += 256) {
        int k = i >> 6, j = i & 63;
        int p = p0 + j;
        int yy = p >> 7, xx = p & 127;
        float oy = eb[(size_t)(9 + 2 * k) * HW + p];
        float ox = eb[(size_t)(10 + 2 * k) * HW + p];
        float mv = eb[(size_t)k * HW + p];
        float mk = 1.f / (1.f + __expf(-mv));
        float py = (float)(yy + (k / 3) - 1) + oy;
        float qx = (float)(xx + (k % 3) - 1) + ox;
        float fy0 = floorf(py), fx0 = floorf(qx);
        float wy = py - fy0, wx = qx - fx0;
        int y0 = (int)fy0, x0 = (int)fx0;
        int y1 = y0 + 1, x1 = x0 + 1;
        bool yv0 = (y0 >= 0) && (y0 < H), yv1 = (y1 >= 0) && (y1 < H);
        bool xv0 = (x0 >= 0) && (x0 < W), xv1 = (x1 >= 0) && (x1 < W);
        int y0c = min(max(y0, 0), H - 1), y1c = min(max(y1, 0), H - 1);
        int x0c = min(max(x0, 0), W - 1), x1c = min(max(x1, 0), W - 1);
        float4 w4;
        w4.x = (yv0 && xv0) ? (1.f - wy) * (1.f - wx) * mk : 0.f;
        w4.y = (yv0 && xv1) ? (1.f - wy) * wx * mk : 0.f;
        w4.z = (yv1 && xv0) ? wy * (1.f - wx) * mk : 0.f;
        w4.w = (yv1 && xv1) ? wy * wx * mk : 0.f;
        sW[i] = w4;
        uint_t o00 = (uint_t)(y0c * W + x0c), o01 = (uint_t)(y0c * W + x1c);
        uint_t o10 = (uint_t)(y1c * W + x0c), o11 = (uint_t)(y1c * W + x1c);
        sO[i] = (uint2){ o00 | (o01 << 16), o10 | (o11 << 16) };
    }

    int wave = tid >> 6, lane = tid & 63;
    int co_base = wave * 32;
    int lrow = lane & 15, lkg = lane >> 4;

    f32x4 acc[2][4];
    #pragma unroll
    for (int m2 = 0; m2 < 2; ++m2)
        #pragma unroll
        for (int n2 = 0; n2 < 4; ++n2) acc[m2][n2] = (f32x4){0.f, 0.f, 0.f, 0.f};

    const f32x4* xb4 = (const f32x4*)(xT + (size_t)b * HW * 128);

    for (int cc = 0; cc < 128; cc += 32) {
        __syncthreads();
        #pragma unroll 2
        for (int it = 0; it < 18; ++it) {
            int task = it * 256 + tid;
            int cg = task & 7;
            int si = task >> 3;
            float4 w4 = sW[si];
            uint2 o4 = sO[si];
            int chv = (cc >> 2) + cg;
            f32x4 c00 = xb4[(o4.x & 0xFFFFu) * 32 + chv];
            f32x4 c01 = xb4[(o4.x >> 16) * 32 + chv];
            f32x4 c10 = xb4[(o4.y & 0xFFFFu) * 32 + chv];
            f32x4 c11 = xb4[(o4.y >> 16) * 32 + chv];
            f32x4 v;
            #pragma unroll
            for (int j = 0; j < 4; ++j)
                v[j] = w4.x * c00[j] + w4.y * c01[j] + w4.z * c10[j] + w4.w * c11[j];
            int pxl = si & 63, tap = si >> 6;
            uint2 pk;
            pk.x = pack_bf16(v[0], v[1]);
            pk.y = pack_bf16(v[2], v[3]);
            *(uint2*)&sB[pxl * BS + tap * 32 + cg * 4] = pk;
        }
        __syncthreads();
        int kbase = cc * 9;
        #pragma unroll
        for (int ks = 0; ks < 9; ++ks) {
            bf16x8 afr[2], bfr[4];
            #pragma unroll
            for (int m2 = 0; m2 < 2; ++m2)
                afr[m2] = *reinterpret_cast<const bf16x8*>(
                    wbf + (size_t)(co_base + m2 * 16 + lrow) * 1152 + kbase + ks * 32 + lkg * 8);
            #pragma unroll
            for (int n2 = 0; n2 < 4; ++n2)
                bfr[n2] = *reinterpret_cast<const bf16x8*>(
                    &sB[(n2 * 16 + lrow) * BS + ks * 32 + lkg * 8]);
            #pragma unroll
            for (int m2 = 0; m2 < 2; ++m2)
                #pragma unroll
                for (int n2 = 0; n2 < 4; ++n2)
                    acc[m2][n2] = __builtin_amdgcn_mfma_f32_16x16x32_bf16(
                        afr[m2], bfr[n2], acc[m2][n2], 0, 0, 0);
        }
    }

    #pragma unroll
    for (int m2 = 0; m2 < 2; ++m2) {
        #pragma unroll
        for (int j = 0; j < 4; ++j) {
            int co = co_base + m2 * 16 + lkg * 4 + j;
            float bb = bias[co];
            #pragma unroll
            for (int n2 = 0; n2 < 4; ++n2) {
                int px = p0 + n2 * 16 + lrow;
                out[((size_t)(b * 128 + co)) * HW + px] = acc[m2][n2][j] + bb;
            }
        }
    }
}

extern "C" void kernel_launch(void* const* d_in, const int* in_sizes, int n_in,
                              void* d_out, int out_size, void* d_ws, size_t ws_size,
                              hipStream_t stream)
{
    const float* x_all     = (const float*)d_in[0];
    const float* ms_fine   = (const float*)d_in[1];
    const float* ms_coarse = (const float*)d_in[2];
    const float* enc_w0 = (const float*)d_in[3];
    const float* enc_b0 = (const float*)d_in[4];
    const float* enc_w1 = (const float*)d_in[5];
    const float* enc_b1 = (const float*)d_in[6];
    const float* nl_tw[2] = { (const float*)d_in[7],  (const float*)d_in[15] };
    const float* nl_tb[2] = { (const float*)d_in[8],  (const float*)d_in[16] };
    const float* nl_pw[2] = { (const float*)d_in[9],  (const float*)d_in[17] };
    const float* nl_pb[2] = { (const float*)d_in[10], (const float*)d_in[18] };
    const float* nl_gw[2] = { (const float*)d_in[11], (const float*)d_in[19] };
    const float* nl_gb[2] = { (const float*)d_in[12], (const float*)d_in[20] };
    const float* nl_ww[2] = { (const float*)d_in[13], (const float*)d_in[21] };
    const float* nl_wb[2] = { (const float*)d_in[14], (const float*)d_in[22] };
    const float* dec_w0 = (const float*)d_in[23];
    const float* dec_b0 = (const float*)d_in[24];
    const float* dec_w1 = (const float*)d_in[25];
    const float* dec_b1 = (const float*)d_in[26];
    const float* off_w  = (const float*)d_in[27];
    const float* off_b  = (const float*)d_in[28];
    const float* dcn_w  = (const float*)d_in[29];
    const float* dcn_b  = (const float*)d_in[30];

    // ---- workspace layout (floats), lifetime-overlaid
    float* ws = (float*)d_ws;
    ushort_t* wbf     = (ushort_t*)ws;            // 147456 u
    ushort_t* w2_enc0 = wbf + 147456;             // 294912 u
    ushort_t* w2_enc1 = w2_enc0 + 294912;         // 147456 u
    ushort_t* w2_dec0 = w2_enc1 + 147456;         // 36864 u
    ushort_t* w2_dec1 = w2_dec0 + 36864;          // 36864 u
    ushort_t* w2_est  = w2_dec1 + 36864;          // 36864 u  (ends 700416 u = 350208 f)
    float* U1      = ws + 350208;                 // 1048576 (e0/th0set/m0 | th1set | m1)
    float* u0      = U1 + 1048576;                // 1048576
    float* e1      = u0 + 1048576;                // 1048576
    float* partML  = e1 + 1048576;                // 163840
    float* regPart = partML + 163840;             // 2097152 (partial | partO | est)
    float* regMot  = regPart + 2097152;           // 4194304 (mot | xT)

    float* e0 = U1;                               // [4][64][1024]
    ushort_t* thT0 = (ushort_t*)(U1 + 262144);    // [4][1024][32]
    ushort_t* phT0 = thT0 + 131072;
    ushort_t* gT0  = phT0 + 131072;
    float* m0 = U1 + 458752;                      // [4][64][1024]
    ushort_t* thT1 = (ushort_t*)U1;               // [4][4096][32]
    ushort_t* phT1 = thT1 + 524288;
    ushort_t* gT1  = phT1 + 524288;
    float* m1  = U1;                              // [4][64][4096]
    float* mot = regMot;                          // [4][64][16384]
    float* xT  = regMot;                          // [2][16384][128] per s
    float* est = regPart;                         // [4][27][16384]

    float* out = (float*)d_out;
    const size_t frame  = (size_t)2 * 128 * 128 * 128;
    const size_t cframe = (size_t)2 * 256 * 64 * 64;

    hipMemcpyAsync(out, x_all, frame * sizeof(float), hipMemcpyDeviceToDevice, stream);

    // ---- one-time weight prep
    castw_perm_kernel<<<(147456 + 255) / 256, 256, 0, stream>>>(dcn_w, wbf);
    castw2_kernel<<<(64 * 4608 + 255) / 256, 256, 0, stream>>>(enc_w0, w2_enc0, 64, 512, 4608, 0);
    castw2_kernel<<<(64 * 2304 + 255) / 256, 256, 0, stream>>>(enc_w1, w2_enc1, 64, 256, 2304, 0);
    castw2_kernel<<<(64 * 576 + 255) / 256, 256, 0, stream>>>(dec_w0, w2_dec0, 64, 64, 576, 1);
    castw2_kernel<<<(64 * 576 + 255) / 256, 256, 0, stream>>>(dec_w1, w2_dec1, 64, 64, 576, 1);
    castw2_kernel<<<(64 * 576 + 255) / 256, 256, 0, stream>>>(off_w, w2_est, 27, 64, 576, 0);

    // ==== batched motion pipeline: b4 = s_idx*2 + b, s = s_idx+1 ====

    // e0 = lrelu(conv3x3 s2 (pc||cc; 512->64)) : [4][64][1024]
    conv3x3_mfma<2, 0><<<4 * 16 * 8, 256, 0, stream>>>(
        ms_coarse + cframe, ms_coarse, 256, cframe, 64, 64, 512,
        w2_enc0, 4608, 32, 1024, 16, 8, 18, regPart, nullptr, 0, 0, nullptr);
    reduce_bias_act<<<1024, 256, 0, stream>>>(regPart, enc_b0, e0, 64, 1024, 8, 1);

    // non-local 0 (N=1024, KVS=8)
    conv1x1x3_bf16<<<48, 256, 0, stream>>>(e0, 1024,
        nl_tw[0], nl_tb[0], nl_pw[0], nl_pb[0], nl_gw[0], nl_gb[0], thT0, phT0, gT0);
    attn_flash<<<4 * 16 * 8, 256, 0, stream>>>(thT0, phT0, gT0, regPart, partML, 1024, 8);
    nl_merge_fused<<<64, 256, 0, stream>>>(e0, regPart, partML, nullptr,
        nl_ww[0], nl_wb[0], m0, 1024, 8);

    // u0 = lrelu(deconv(m0)) : [4][64][4096]
    conv3x3_mfma<1, 1><<<4 * 64 * 2, 256, 0, stream>>>(
        m0, m0, 64, (size_t)2 * 64 * 1024, 32, 32, 64,
        w2_dec0, 576, 64, 4096, 64, 2, 9, regPart, nullptr, 0, 0, nullptr);
    reduce_bias_act<<<4096, 256, 0, stream>>>(regPart, dec_b0, u0, 64, 4096, 2, 1);

    // e1 = lrelu(conv3x3 s2 (pf||cf; 256->64)) : [4][64][4096]
    conv3x3_mfma<2, 0><<<4 * 64 * 2, 256, 0, stream>>>(
        ms_fine + frame, ms_fine, 128, frame, 128, 128, 256,
        w2_enc1, 2304, 64, 4096, 64, 2, 36, regPart, nullptr, 0, 0, nullptr);
    reduce_bias_act<<<4096, 256, 0, stream>>>(regPart, enc_b1, e1, 64, 4096, 2, 1);

    // non-local 1 (N=4096, KVS=4)
    conv1x1x3_bf16<<<192, 256, 0, stream>>>(e1, 4096,
        nl_tw[1], nl_tb[1], nl_pw[1], nl_pb[1], nl_gw[1], nl_gb[1], thT1, phT1, gT1);
    attn_flash<<<4 * 64 * 4, 256, 0, stream>>>(thT1, phT1, gT1, regPart, partML, 4096, 4);
    nl_merge_fused<<<256, 256, 0, stream>>>(e1, regPart, partML, u0,
        nl_ww[1], nl_wb[1], m1, 4096, 4);

    // mot = lrelu(deconv(m1)) : [4][64][16384]  (fused epilogue)
    conv3x3_mfma<1, 1><<<4 * 256, 256, 0, stream>>>(
        m1, m1, 64, (size_t)2 * 64 * 4096, 64, 64, 64,
        w2_dec1, 576, 128, 16384, 256, 1, 18, regPart, dec_b1, 1, 64, mot);

    // est = conv3x3 s1 (mot; 64->27) : [4][27][16384]  (fused epilogue)
    conv3x3_mfma<1, 0><<<4 * 256, 256, 0, stream>>>(
        mot, mot, 64, (size_t)2 * 64 * 16384, 128, 128, 64,
        w2_est, 576, 128, 16384, 256, 1, 18, regPart, off_b, 0, 27, est);

    // ==== per-s: transpose + deformable conv ====
    for (int s = 1; s < 3; ++s) {
        transpose_nhwc_kernel<<<4096, 256, 0, stream>>>(x_all + (size_t)s * frame, xT);
        deform_mfma3<<<512, 256, 0, stream>>>(
            xT, est + (size_t)(s - 1) * 2 * 27 * 16384, wbf, dcn_b,
            out + (size_t)s * frame);
    }
}

// Round 11
// 363.625 us; speedup vs baseline: 14.4161x; 1.0417x over previous
//
#include <hip/hip_runtime.h>
#include <math.h>

typedef __attribute__((ext_vector_type(8))) short bf16x8;
typedef __attribute__((ext_vector_type(4))) float f32x4;
typedef unsigned short ushort_t;
typedef unsigned int uint_t;

__device__ __forceinline__ float lrelu_f(float x) { return x >= 0.f ? x : 0.01f * x; }

__device__ __forceinline__ ushort_t f2bf(float f) {
    uint_t x = __float_as_uint(f);
    uint_t r = (x + 0x7fffu + ((x >> 16) & 1u)) >> 16;
    return (ushort_t)r;
}

__device__ __forceinline__ uint_t pack_bf16(float lo, float hi) {
    uint_t out;
    asm("v_cvt_pk_bf16_f32 %0, %1, %2" : "=v"(out) : "v"(lo), "v"(hi));
    return out;
}

// native 2^x (input already in log2 domain)
__device__ __forceinline__ float fexp2(float x) {
    float r;
    asm("v_exp_f32 %0, %1" : "=v"(r) : "v"(x));
    return r;
}

// ===========================================================================
// Weight prep: w2[co64][K'] bf16, channel-block-major K ordering:
// K' = cb*288 + tap*32 + cl, ci = cb*32+cl. co padded to 64 with zeros.
// ===========================================================================
__global__ __launch_bounds__(256) void castw2_kernel(const float* __restrict__ w,
    ushort_t* __restrict__ w2, int Cout, int Cin, int K, int deconv)
{
    int idx = blockIdx.x * 256 + threadIdx.x;
    if (idx >= 64 * K) return;
    int co = idx / K, kp = idx % K;
    int cb = kp / 288;
    int r  = kp % 288;
    int tap = r >> 5, cl = r & 31;
    int ci = cb * 32 + cl;
    float val = 0.f;
    if (co < Cout)
        val = deconv ? w[(size_t)(ci * Cout + co) * 9 + (8 - tap)]
                     : w[(size_t)(co * Cin + ci) * 9 + tap];
    w2[idx] = f2bf(val);
}

// ===========================================================================
// bf16 MFMA implicit-GEMM 3x3 conv over 4-batch. Unchanged from round 9.
// ===========================================================================
template<int STRIDE, int MODE>
__global__ __launch_bounds__(256) void conv3x3_mfma(
    const float* __restrict__ inA, const float* __restrict__ inB, int CinA,
    size_t sStrideA, int Hin, int Win, int Cin,
    const ushort_t* __restrict__ w2, int K,
    int Wout, int Npx, int tilesPerMap, int ksplit, int chunksPerKs,
    float* __restrict__ part,
    const float* __restrict__ bias, int act, int CoutStore, float* __restrict__ outDirect)
{
    __shared__ ushort_t sB[64 * 40];
    int tile = blockIdx.x % tilesPerMap;
    int ks   = (blockIdx.x / tilesPerMap) % ksplit;
    int b4   = blockIdx.x / (tilesPerMap * ksplit);
    int s_idx = b4 >> 1, bb = b4 & 1;
    int tid  = threadIdx.x;
    int wave = tid >> 6, lane = tid & 63;
    int lrow = lane & 15, lkg = lane >> 4;
    int px  = tid & 63;
    int cio = wave * 8;
    int p   = tile * 64 + px;
    int oy  = p / Wout, ox = p - oy * Wout;
    int HWin = Hin * Win;
    int CinB = Cin - CinA;

    f32x4 acc[4];
    #pragma unroll
    for (int n2 = 0; n2 < 4; ++n2) acc[n2] = (f32x4){0.f, 0.f, 0.f, 0.f};

    for (int cch = 0; cch < chunksPerKs; ++cch) {
        int chunkIdx = ks * chunksPerKs + cch;
        int cb  = chunkIdx / 9;
        int tap = chunkIdx - cb * 9;
        int cib = cb * 32;
        int ky = tap / 3, kx = tap - ky * 3;
        float msk;
        int offp;
        if (MODE == 0) {
            int iy = oy * STRIDE - 1 + ky;
            int ix = ox * STRIDE - 1 + kx;
            bool vld = (iy >= 0) && (iy < Hin) && (ix >= 0) && (ix < Win);
            msk = vld ? 1.f : 0.f;
            offp = min(max(iy, 0), Hin - 1) * Win + min(max(ix, 0), Win - 1);
        } else {
            int uy = oy + ky, ux = ox + kx;
            int r = (uy - 1) >> 1, q = (ux - 1) >> 1;
            bool vld = (uy & 1) && (ux & 1) && (r < Hin) && (q < Win);
            msk = vld ? 1.f : 0.f;
            offp = min(max(r, 0), Hin - 1) * Win + min(max(q, 0), Win - 1);
        }
        int c = cib + cio;
        const float* src = (c < CinA)
            ? inA + s_idx * sStrideA + (size_t)(bb * CinA + c) * HWin
            : inB + (size_t)(bb * CinB + (c - CinA)) * HWin;
        float v[8];
        #pragma unroll
        for (int j = 0; j < 8; ++j) v[j] = src[(size_t)j * HWin + offp] * msk;
        uint4 pk;
        pk.x = pack_bf16(v[0], v[1]);
        pk.y = pack_bf16(v[2], v[3]);
        pk.z = pack_bf16(v[4], v[5]);
        pk.w = pack_bf16(v[6], v[7]);
        __syncthreads();
        *(uint4*)&sB[px * 40 + cio] = pk;
        __syncthreads();

        const ushort_t* wr = w2 + (size_t)(wave * 16 + lrow) * K + chunkIdx * 32 + lkg * 8;
        bf16x8 afr = *(const bf16x8*)wr;
        #pragma unroll
        for (int n2 = 0; n2 < 4; ++n2) {
            bf16x8 bfr = *(const bf16x8*)&sB[(n2 * 16 + lrow) * 40 + lkg * 8];
            acc[n2] = __builtin_amdgcn_mfma_f32_16x16x32_bf16(afr, bfr, acc[n2], 0, 0, 0);
        }
    }

    if (bias) {
        #pragma unroll
        for (int n2 = 0; n2 < 4; ++n2) {
            #pragma unroll
            for (int j = 0; j < 4; ++j) {
                int co = wave * 16 + lkg * 4 + j;
                if (co < CoutStore) {
                    int pp = tile * 64 + n2 * 16 + lrow;
                    float r = acc[n2][j] + bias[co];
                    if (act) r = lrelu_f(r);
                    outDirect[((size_t)(b4 * CoutStore + co)) * (size_t)Npx + pp] = r;
                }
            }
        }
    } else {
        #pragma unroll
        for (int n2 = 0; n2 < 4; ++n2) {
            #pragma unroll
            for (int j = 0; j < 4; ++j) {
                int co = wave * 16 + lkg * 4 + j;
                int pp = tile * 64 + n2 * 16 + lrow;
                part[((size_t)(ks * 4 + b4) * 64 + co) * (size_t)Npx + pp] = acc[n2][j];
            }
        }
    }
}

__global__ __launch_bounds__(256) void reduce_bias_act(const float* __restrict__ part,
    const float* __restrict__ bias, float* __restrict__ out,
    int Cout, int Npx, int ksplit, int act)
{
    int idx = blockIdx.x * 256 + threadIdx.x;
    int total = 4 * Cout * Npx;
    if (idx >= total) return;
    int p  = idx % Npx;
    int co = (idx / Npx) % Cout;
    int b4 = idx / (Npx * Cout);
    float s = bias[co];
    for (int ks = 0; ks < ksplit; ++ks)
        s += part[(((size_t)ks * 4 + b4) * 64 + co) * (size_t)Npx + p];
    if (act) s = lrelu_f(s);
    out[((size_t)b4 * Cout + co) * (size_t)Npx + p] = s;
}

__global__ __launch_bounds__(256) void castw_perm_kernel(const float* __restrict__ w,
    ushort_t* __restrict__ wbf)
{
    int idx = blockIdx.x * 256 + threadIdx.x;
    if (idx >= 147456) return;
    int co = idx / 1152;
    int r  = idx % 1152;
    int chunk = r / 288;
    int r2 = r % 288;
    int tap = r2 >> 5;
    int cl  = r2 & 31;
    int ci = chunk * 32 + cl;
    wbf[idx] = f2bf(w[(size_t)co * 1152 + ci * 9 + tap]);
}

// Batched NCHW frames (s=1,2) -> NHWC bf16 [b4][16384][128]
__global__ __launch_bounds__(256) void transpose_nhwc_bf16(const float* __restrict__ x,
    ushort_t* __restrict__ xT)
{
    __shared__ float t[32][33];
    int cT = blockIdx.x & 3;
    int pT = (blockIdx.x >> 2) & 511;
    int b4 = blockIdx.x >> 11;           // 0..3 -> image b4+2
    int tx = threadIdx.x & 31, ty = threadIdx.x >> 5;
    const float* src = x + ((size_t)((b4 + 2) * 128) + cT * 32) * 16384 + (size_t)pT * 32;
    #pragma unroll
    for (int i = 0; i < 4; ++i)
        t[ty + 8 * i][tx] = src[(size_t)(ty + 8 * i) * 16384 + tx];
    __syncthreads();
    ushort_t* dst = xT + ((size_t)b4 * 16384 + (size_t)pT * 32) * 128 + cT * 32;
    #pragma unroll
    for (int i = 0; i < 4; ++i)
        dst[(size_t)(ty + 8 * i) * 128 + tx] = f2bf(t[tx][ty + 8 * i]);
}

// ---------------------------------------------------------------------------
// Fused 1x1 convs -> bf16 attention operands, 4-batch. thT scaled by log2(e)
// so QK^T scores land directly in the exp2 domain.
// ---------------------------------------------------------------------------
__global__ __launch_bounds__(256) void conv1x1x3_bf16(const float* __restrict__ e, int N,
    const float* __restrict__ tw, const float* __restrict__ tb,
    const float* __restrict__ pw, const float* __restrict__ pb,
    const float* __restrict__ gw, const float* __restrict__ gb,
    ushort_t* __restrict__ thT, ushort_t* __restrict__ phT, ushort_t* __restrict__ gT)
{
    __shared__ float sw[32 * 64];
    __shared__ float sb[32];
    int tid = threadIdx.x;
    int idx = blockIdx.x * 256 + tid;
    int j = idx / (4 * N);
    const float* wsel = (j == 0) ? tw : (j == 1) ? pw : gw;
    const float* bsel = (j == 0) ? tb : (j == 1) ? pb : gb;
    for (int i = tid; i < 2048; i += 256) sw[i] = wsel[i];
    if (tid < 32) sb[tid] = bsel[tid];
    __syncthreads();
    int rem = idx - j * 4 * N;
    int n = rem % N, b4 = rem / N;
    float ein[64];
    const float* ep = e + (size_t)b4 * 64 * N + n;
    #pragma unroll
    for (int ci = 0; ci < 64; ++ci) ein[ci] = ep[(size_t)ci * N];

    float val[32];
    #pragma unroll
    for (int cc = 0; cc < 32; ++cc) {
        float acc = sb[cc];
        const float* wr = &sw[cc * 64];
        #pragma unroll
        for (int ci = 0; ci < 64; ++ci) acc = fmaf(wr[ci], ein[ci], acc);
        val[cc] = acc;
    }
    if (j == 0) {
        #pragma unroll
        for (int cc = 0; cc < 32; ++cc) val[cc] *= 1.44269504f;   // log2(e)
    }
    if (j < 2) {
        ushort_t* row = (j == 0 ? thT : phT) + ((size_t)b4 * N + n) * 32;
        #pragma unroll
        for (int w4 = 0; w4 < 4; ++w4) {
            uint4 pk;
            pk.x = pack_bf16(val[8 * w4 + 0], val[8 * w4 + 1]);
            pk.y = pack_bf16(val[8 * w4 + 2], val[8 * w4 + 3]);
            pk.z = pack_bf16(val[8 * w4 + 4], val[8 * w4 + 5]);
            pk.w = pack_bf16(val[8 * w4 + 6], val[8 * w4 + 7]);
            *(uint4*)(row + 8 * w4) = pk;
        }
    } else {
        #pragma unroll
        for (int cc = 0; cc < 32; ++cc)
            gT[((size_t)b4 * 32 + cc) * N + n] = f2bf(val[cc]);
    }
}

// ===========================================================================
// Flash split-K MFMA attention (exp2 domain, defer-max), 4-batch.
// ===========================================================================
__global__ __launch_bounds__(256) void attn_flash(const ushort_t* __restrict__ thT,
    const ushort_t* __restrict__ phT, const ushort_t* __restrict__ gT,
    float* __restrict__ partO, float* __restrict__ partML, int N, int KVS)
{
    __shared__ ushort_t sP[4][16 * 40];
    int tid  = threadIdx.x;
    int wave = tid >> 6, lane = tid & 63;
    int lq = lane & 15, lkg = lane >> 4;
    int nqb = N / 64;
    int ks = blockIdx.x % KVS;
    int qb = (blockIdx.x / KVS) % nqb;
    int b4 = blockIdx.x / (KVS * nqb);
    int q0w = qb * 64 + wave * 16;
    int chunk = N / KVS;
    int m_start = ks * chunk;

    bf16x8 qf = *(const bf16x8*)(thT + ((size_t)b4 * N + q0w + lq) * 32 + 8 * lkg);

    float m_run = -1e30f, l_run = 0.f;
    f32x4 acc[2];
    acc[0] = (f32x4){0.f, 0.f, 0.f, 0.f};
    acc[1] = (f32x4){0.f, 0.f, 0.f, 0.f};

    for (int m0 = m_start; m0 < m_start + chunk; m0 += 64) {
        f32x4 tf[4];
        #pragma unroll
        for (int f = 0; f < 4; ++f) {
            bf16x8 kf = *(const bf16x8*)(phT + ((size_t)b4 * N + m0 + f * 16 + lq) * 32 + 8 * lkg);
            tf[f] = __builtin_amdgcn_mfma_f32_16x16x32_bf16(kf, qf,
                        (f32x4){0.f, 0.f, 0.f, 0.f}, 0, 0, 0);
        }

        float mx = -1e30f;
        #pragma unroll
        for (int f = 0; f < 4; ++f)
            #pragma unroll
            for (int r = 0; r < 4; ++r) mx = fmaxf(mx, tf[f][r]);
        mx = fmaxf(mx, __shfl_xor(mx, 16));
        mx = fmaxf(mx, __shfl_xor(mx, 32));

        if (__any(mx > m_run)) {                    // defer-max: rescale rarely
            float m_new = fmaxf(m_run, mx);
            float scale = fexp2(m_run - m_new);
            l_run *= scale;
            m_run = m_new;
            float sc[4];
            #pragma unroll
            for (int r = 0; r < 4; ++r) sc[r] = __shfl(scale, 4 * lkg + r);
            #pragma unroll
            for (int h = 0; h < 2; ++h)
                #pragma unroll
                for (int r = 0; r < 4; ++r) acc[h][r] *= sc[r];
        }

        float rs = 0.f;
        #pragma unroll
        for (int f = 0; f < 4; ++f)
            #pragma unroll
            for (int r = 0; r < 4; ++r) {
                float pv = fexp2(tf[f][r] - m_run);
                tf[f][r] = pv;
                rs += pv;
            }
        rs += __shfl_xor(rs, 16);
        rs += __shfl_xor(rs, 32);
        l_run += rs;

        #pragma unroll
        for (int f = 0; f < 4; ++f) {
            *(uint_t*)&sP[wave][lq * 40 + f * 16 + 4 * lkg]     = pack_bf16(tf[f][0], tf[f][1]);
            *(uint_t*)&sP[wave][lq * 40 + f * 16 + 4 * lkg + 2] = pack_bf16(tf[f][2], tf[f][3]);
        }

        #pragma unroll
        for (int mc = 0; mc < 2; ++mc) {
            bf16x8 pf = *(const bf16x8*)&sP[wave][lq * 40 + mc * 32 + 8 * lkg];
            #pragma unroll
            for (int h = 0; h < 2; ++h) {
                bf16x8 vf = *(const bf16x8*)(gT + ((size_t)b4 * 32 + h * 16 + lq) * N
                                             + m0 + mc * 32 + 8 * lkg);
                acc[h] = __builtin_amdgcn_mfma_f32_16x16x32_bf16(pf, vf, acc[h], 0, 0, 0);
            }
        }
    }

    #pragma unroll
    for (int h = 0; h < 2; ++h) {
        #pragma unroll
        for (int r = 0; r < 4; ++r) {
            int q = q0w + 4 * lkg + r;
            partO[(((size_t)ks * 4 + b4) * N + q) * 32 + h * 16 + lq] = acc[h][r];
        }
    }
    if (lane < 16) {
        size_t mlo = (((size_t)ks * 4 + b4) * N + q0w + lq) * 2;
        partML[mlo]     = m_run;
        partML[mlo + 1] = l_run;
    }
}

// ===========================================================================
// Fused flash-combine (exp2 domain) + non-local merge (4-batch).
// ===========================================================================
__global__ __launch_bounds__(256) void nl_merge_fused(const float* __restrict__ e,
    const float* __restrict__ partO, const float* __restrict__ partML,
    const float* __restrict__ u,
    const float* __restrict__ ww, const float* __restrict__ wb,
    float* __restrict__ out, int N, int KVS)
{
    __shared__ float sw[64 * 32];
    __shared__ float sb[64];
    int tid = threadIdx.x;
    for (int i = tid; i < 2048; i += 256) sw[i] = ww[i];
    if (tid < 64) sb[tid] = wb[tid];
    __syncthreads();
    int idx = blockIdx.x * 256 + tid;
    int n = idx % N;
    int cog = (idx / N) & 3;
    int b4 = idx / (4 * N);

    float mstar = -1e30f;
    for (int ks = 0; ks < KVS; ++ks)
        mstar = fmaxf(mstar, partML[(((size_t)ks * 4 + b4) * N + n) * 2]);
    float denom = 0.f;
    float yv[32];
    #pragma unroll
    for (int c = 0; c < 32; ++c) yv[c] = 0.f;
    for (int ks = 0; ks < KVS; ++ks) {
        size_t mlo = (((size_t)ks * 4 + b4) * N + n) * 2;
        float w = fexp2(partML[mlo] - mstar);
        denom += w * partML[mlo + 1];
        const f32x4* op = (const f32x4*)(partO + (((size_t)ks * 4 + b4) * N + n) * 32);
        #pragma unroll
        for (int jj = 0; jj < 8; ++jj) {
            f32x4 v = op[jj];
            #pragma unroll
            for (int t = 0; t < 4; ++t) yv[4 * jj + t] = fmaf(w, v[t], yv[4 * jj + t]);
        }
    }
    float inv = 1.f / denom;
    #pragma unroll
    for (int i = 0; i < 16; ++i) {
        int co = cog * 16 + i;
        float dot = 0.f;
        const float* wr = &sw[co * 32];
        #pragma unroll
        for (int c = 0; c < 32; ++c) dot = fmaf(wr[c], yv[c], dot);
        size_t o = (size_t)b4 * 64 * N + (size_t)co * N + n;
        float r = sb[co] + inv * dot + 2.f * e[o];
        if (u) r += u[o];
        out[o] = r;
    }
}

// ===========================================================================
// Deformable conv v4: bf16 NHWC input, 8-channel 16B gathers (half the gather
// instructions), batched over all 4 images, XCD-swizzled (1024 blocks).
// ===========================================================================
__global__ __launch_bounds__(256) void deform_mfma4(const ushort_t* __restrict__ xT,
    const float* __restrict__ est, const ushort_t* __restrict__ wbf,
    const float* __restrict__ bias, float* __restrict__ out)
{
    const int H = 128, W = 128, HW = 16384;
    const int BS = 296;
    __shared__ ushort_t sB[64 * BS];
    __shared__ float4 sW[576];
    __shared__ uint2  sO[576];
    int id  = blockIdx.x;                       // 1024 blocks, %8==0
    int lin = (id & 7) * 128 + (id >> 3);       // XCD-chunked bijective remap
    int tile = lin & 255;
    int b4   = lin >> 8;                        // 0..3, image = b4+2
    int p0   = tile * 64;
    int tid  = threadIdx.x;

    const float* eb = est + (size_t)b4 * 27 * HW;
    for (int i = tid; i < 576; i += 256) {
        int k = i >> 6, j = i & 63;
        int p = p0 + j;
        int yy = p >> 7, xx = p & 127;
        float oy = eb[(size_t)(9 + 2 * k) * HW + p];
        float ox = eb[(size_t)(10 + 2 * k) * HW + p];
        float mv = eb[(size_t)k * HW + p];
        float mk = 1.f / (1.f + __expf(-mv));
        float py = (float)(yy + (k / 3) - 1) + oy;
        float qx = (float)(xx + (k % 3) - 1) + ox;
        float fy0 = floorf(py), fx0 = floorf(qx);
        float wy = py - fy0, wx = qx - fx0;
        int y0 = (int)fy0, x0 = (int)fx0;
        int y1 = y0 + 1, x1 = x0 + 1;
        bool yv0 = (y0 >= 0) && (y0 < H), yv1 = (y1 >= 0) && (y1 < H);
        bool xv0 = (x0 >= 0) && (x0 < W), xv1 = (x1 >= 0) && (x1 < W);
        int y0c = min(max(y0, 0), H - 1), y1c = min(max(y1, 0), H - 1);
        int x0c = min(max(x0, 0), W - 1), x1c = min(max(x1, 0), W - 1);
        float4 w4;
        w4.x = (yv0 && xv0) ? (1.f - wy) * (1.f - wx) * mk : 0.f;
        w4.y = (yv0 && xv1) ? (1.f - wy) * wx * mk : 0.f;
        w4.z = (yv1 && xv0) ? wy * (1.f - wx) * mk : 0.f;
        w4.w = (yv1 && xv1) ? wy * wx * mk : 0.f;
        sW[i] = w4;
        uint_t o00 = (uint_t)(y0c * W + x0c), o01 = (uint_t)(y0c * W + x1c);
        uint_t o10 = (uint_t)(y1c * W + x0c), o11 = (uint_t)(y1c * W + x1c);
        sO[i] = (uint2){ o00 | (o01 << 16), o10 | (o11 << 16) };
    }

    int wave = tid >> 6, lane = tid & 63;
    int co_base = wave * 32;
    int lrow = lane & 15, lkg = lane >> 4;

    f32x4 acc[2][4];
    #pragma unroll
    for (int m2 = 0; m2 < 2; ++m2)
        #pragma unroll
        for (int n2 = 0; n2 < 4; ++n2) acc[m2][n2] = (f32x4){0.f, 0.f, 0.f, 0.f};

    const ushort_t* xb = xT + (size_t)b4 * HW * 128;

    for (int cc = 0; cc < 128; cc += 32) {
        __syncthreads();
        #pragma unroll 3
        for (int it = 0; it < 9; ++it) {
            int task = it * 256 + tid;
            int cg = task & 3;               // 4 groups of 8 channels
            int si = task >> 2;              // 0..575
            float4 w4 = sW[si];
            uint2 o4 = sO[si];
            int chb = cc + cg * 8;           // ushort offset within 128-ch row
            uint4 u00 = *(const uint4*)(xb + (size_t)(o4.x & 0xFFFFu) * 128 + chb);
            uint4 u01 = *(const uint4*)(xb + (size_t)(o4.x >> 16) * 128 + chb);
            uint4 u10 = *(const uint4*)(xb + (size_t)(o4.y & 0xFFFFu) * 128 + chb);
            uint4 u11 = *(const uint4*)(xb + (size_t)(o4.y >> 16) * 128 + chb);
            float v[8];
            const uint_t* a0 = (const uint_t*)&u00;
            const uint_t* a1 = (const uint_t*)&u01;
            const uint_t* a2 = (const uint_t*)&u10;
            const uint_t* a3 = (const uint_t*)&u11;
            #pragma unroll
            for (int q = 0; q < 4; ++q) {
                float c00l = __uint_as_float(a0[q] << 16), c00h = __uint_as_float(a0[q] & 0xffff0000u);
                float c01l = __uint_as_float(a1[q] << 16), c01h = __uint_as_float(a1[q] & 0xffff0000u);
                float c10l = __uint_as_float(a2[q] << 16), c10h = __uint_as_float(a2[q] & 0xffff0000u);
                float c11l = __uint_as_float(a3[q] << 16), c11h = __uint_as_float(a3[q] & 0xffff0000u);
                v[2 * q]     = w4.x * c00l + w4.y * c01l + w4.z * c10l + w4.w * c11l;
                v[2 * q + 1] = w4.x * c00h + w4.y * c01h + w4.z * c10h + w4.w * c11h;
            }
            int pxl = si & 63, tap = si >> 6;
            uint4 pk;
            pk.x = pack_bf16(v[0], v[1]);
            pk.y = pack_bf16(v[2], v[3]);
            pk.z = pack_bf16(v[4], v[5]);
            pk.w = pack_bf16(v[6], v[7]);
            *(uint4*)&sB[pxl * BS + tap * 32 + cg * 8] = pk;
        }
        __syncthreads();
        int kbase = cc * 9;
        #pragma unroll
        for (int ks = 0; ks < 9; ++ks) {
            bf16x8 afr[2], bfr[4];
            #pragma unroll
            for (int m2 = 0; m2 < 2; ++m2)
                afr[m2] = *reinterpret_cast<const bf16x8*>(
                    wbf + (size_t)(co_base + m2 * 16 + lrow) * 1152 + kbase + ks * 32 + lkg * 8);
            #pragma unroll
            for (int n2 = 0; n2 < 4; ++n2)
                bfr[n2] = *reinterpret_cast<const bf16x8*>(
                    &sB[(n2 * 16 + lrow) * BS + ks * 32 + lkg * 8]);
            #pragma unroll
            for (int m2 = 0; m2 < 2; ++m2)
                #pragma unroll
                for (int n2 = 0; n2 < 4; ++n2)
                    acc[m2][n2] = __builtin_amdgcn_mfma_f32_16x16x32_bf16(
                        afr[m2], bfr[n2], acc[m2][n2], 0, 0, 0);
        }
    }

    #pragma unroll
    for (int m2 = 0; m2 < 2; ++m2) {
        #pragma unroll
        for (int j = 0; j < 4; ++j) {
            int co = co_base + m2 * 16 + lkg * 4 + j;
            float bb = bias[co];
            #pragma unroll
            for (int n2 = 0; n2 < 4; ++n2) {
                int px = p0 + n2 * 16 + lrow;
                out[((size_t)((b4 + 2) * 128 + co)) * HW + px] = acc[m2][n2][j] + bb;
            }
        }
    }
}

extern "C" void kernel_launch(void* const* d_in, const int* in_sizes, int n_in,
                              void* d_out, int out_size, void* d_ws, size_t ws_size,
                              hipStream_t stream)
{
    const float* x_all     = (const float*)d_in[0];
    const float* ms_fine   = (const float*)d_in[1];
    const float* ms_coarse = (const float*)d_in[2];
    const float* enc_w0 = (const float*)d_in[3];
    const float* enc_b0 = (const float*)d_in[4];
    const float* enc_w1 = (const float*)d_in[5];
    const float* enc_b1 = (const float*)d_in[6];
    const float* nl_tw[2] = { (const float*)d_in[7],  (const float*)d_in[15] };
    const float* nl_tb[2] = { (const float*)d_in[8],  (const float*)d_in[16] };
    const float* nl_pw[2] = { (const float*)d_in[9],  (const float*)d_in[17] };
    const float* nl_pb[2] = { (const float*)d_in[10], (const float*)d_in[18] };
    const float* nl_gw[2] = { (const float*)d_in[11], (const float*)d_in[19] };
    const float* nl_gb[2] = { (const float*)d_in[12], (const float*)d_in[20] };
    const float* nl_ww[2] = { (const float*)d_in[13], (const float*)d_in[21] };
    const float* nl_wb[2] = { (const float*)d_in[14], (const float*)d_in[22] };
    const float* dec_w0 = (const float*)d_in[23];
    const float* dec_b0 = (const float*)d_in[24];
    const float* dec_w1 = (const float*)d_in[25];
    const float* dec_b1 = (const float*)d_in[26];
    const float* off_w  = (const float*)d_in[27];
    const float* off_b  = (const float*)d_in[28];
    const float* dcn_w  = (const float*)d_in[29];
    const float* dcn_b  = (const float*)d_in[30];

    // ---- workspace layout (floats), lifetime-overlaid (~40.2 MB)
    float* ws = (float*)d_ws;
    ushort_t* wbf     = (ushort_t*)ws;
    ushort_t* w2_enc0 = wbf + 147456;
    ushort_t* w2_enc1 = w2_enc0 + 294912;
    ushort_t* w2_dec0 = w2_enc1 + 147456;
    ushort_t* w2_dec1 = w2_dec0 + 36864;
    ushort_t* w2_est  = w2_dec1 + 36864;          // ends at 350208 floats
    float* U1      = ws + 350208;                 // 1048576
    float* u0      = U1 + 1048576;                // 1048576
    float* e1      = u0 + 1048576;                // 1048576
    float* partML  = e1 + 1048576;                // 262144 (KVS=8 @ N=4096)
    float* regPart = partML + 262144;             // 2097152 (partial | partO0 | est)
    float* regMot  = regPart + 2097152;           // 4194304 (partO1 | mot | xT bf16)

    float* e0 = U1;                               // [4][64][1024]
    ushort_t* thT0 = (ushort_t*)(U1 + 262144);
    ushort_t* phT0 = thT0 + 131072;
    ushort_t* gT0  = phT0 + 131072;
    float* m0 = U1 + 458752;
    ushort_t* thT1 = (ushort_t*)U1;
    ushort_t* phT1 = thT1 + 524288;
    ushort_t* gT1  = phT1 + 524288;
    float* m1  = U1;
    float* mot = regMot;                          // [4][64][16384]
    ushort_t* xTb = (ushort_t*)regMot;            // [4][16384][128] bf16
    float* est = regPart;                         // [4][27][16384]
    float* partO1 = regMot;                       // [8][4][4096][32]

    float* out = (float*)d_out;
    const size_t frame  = (size_t)2 * 128 * 128 * 128;
    const size_t cframe = (size_t)2 * 256 * 64 * 64;

    hipMemcpyAsync(out, x_all, frame * sizeof(float), hipMemcpyDeviceToDevice, stream);

    // ---- one-time weight prep
    castw_perm_kernel<<<(147456 + 255) / 256, 256, 0, stream>>>(dcn_w, wbf);
    castw2_kernel<<<(64 * 4608 + 255) / 256, 256, 0, stream>>>(enc_w0, w2_enc0, 64, 512, 4608, 0);
    castw2_kernel<<<(64 * 2304 + 255) / 256, 256, 0, stream>>>(enc_w1, w2_enc1, 64, 256, 2304, 0);
    castw2_kernel<<<(64 * 576 + 255) / 256, 256, 0, stream>>>(dec_w0, w2_dec0, 64, 64, 576, 1);
    castw2_kernel<<<(64 * 576 + 255) / 256, 256, 0, stream>>>(dec_w1, w2_dec1, 64, 64, 576, 1);
    castw2_kernel<<<(64 * 576 + 255) / 256, 256, 0, stream>>>(off_w, w2_est, 27, 64, 576, 0);

    // ==== batched motion pipeline ====

    // e0 = lrelu(conv3x3 s2 (pc||cc; 512->64)) : [4][64][1024]
    conv3x3_mfma<2, 0><<<4 * 16 * 8, 256, 0, stream>>>(
        ms_coarse + cframe, ms_coarse, 256, cframe, 64, 64, 512,
        w2_enc0, 4608, 32, 1024, 16, 8, 18, regPart, nullptr, 0, 0, nullptr);
    reduce_bias_act<<<1024, 256, 0, stream>>>(regPart, enc_b0, e0, 64, 1024, 8, 1);

    // non-local 0 (N=1024, KVS=8)
    conv1x1x3_bf16<<<48, 256, 0, stream>>>(e0, 1024,
        nl_tw[0], nl_tb[0], nl_pw[0], nl_pb[0], nl_gw[0], nl_gb[0], thT0, phT0, gT0);
    attn_flash<<<4 * 16 * 8, 256, 0, stream>>>(thT0, phT0, gT0, regPart, partML, 1024, 8);
    nl_merge_fused<<<64, 256, 0, stream>>>(e0, regPart, partML, nullptr,
        nl_ww[0], nl_wb[0], m0, 1024, 8);

    // u0 = lrelu(deconv(m0)) : [4][64][4096]
    conv3x3_mfma<1, 1><<<4 * 64 * 2, 256, 0, stream>>>(
        m0, m0, 64, (size_t)2 * 64 * 1024, 32, 32, 64,
        w2_dec0, 576, 64, 4096, 64, 2, 9, regPart, nullptr, 0, 0, nullptr);
    reduce_bias_act<<<4096, 256, 0, stream>>>(regPart, dec_b0, u0, 64, 4096, 2, 1);

    // e1 = lrelu(conv3x3 s2 (pf||cf; 256->64)) : [4][64][4096]
    conv3x3_mfma<2, 0><<<4 * 64 * 2, 256, 0, stream>>>(
        ms_fine + frame, ms_fine, 128, frame, 128, 128, 256,
        w2_enc1, 2304, 64, 4096, 64, 2, 36, regPart, nullptr, 0, 0, nullptr);
    reduce_bias_act<<<4096, 256, 0, stream>>>(regPart, enc_b1, e1, 64, 4096, 2, 1);

    // non-local 1 (N=4096, KVS=8, partO in regMot)
    conv1x1x3_bf16<<<192, 256, 0, stream>>>(e1, 4096,
        nl_tw[1], nl_tb[1], nl_pw[1], nl_pb[1], nl_gw[1], nl_gb[1], thT1, phT1, gT1);
    attn_flash<<<4 * 64 * 8, 256, 0, stream>>>(thT1, phT1, gT1, partO1, partML, 4096, 8);
    nl_merge_fused<<<256, 256, 0, stream>>>(e1, partO1, partML, u0,
        nl_ww[1], nl_wb[1], m1, 4096, 8);

    // mot = lrelu(deconv(m1)) : [4][64][16384]  (fused epilogue)
    conv3x3_mfma<1, 1><<<4 * 256, 256, 0, stream>>>(
        m1, m1, 64, (size_t)2 * 64 * 4096, 64, 64, 64,
        w2_dec1, 576, 128, 16384, 256, 1, 18, regPart, dec_b1, 1, 64, mot);

    // est = conv3x3 s1 (mot; 64->27) : [4][27][16384]  (fused epilogue)
    conv3x3_mfma<1, 0><<<4 * 256, 256, 0, stream>>>(
        mot, mot, 64, (size_t)2 * 64 * 16384, 128, 128, 64,
        w2_est, 576, 128, 16384, 256, 1, 18, regPart, off_b, 0, 27, est);

    // ==== batched transpose (bf16) + batched deformable conv ====
    transpose_nhwc_bf16<<<8192, 256, 0, stream>>>(x_all, xTb);
    deform_mfma4<<<1024, 256, 0, stream>>>(xTb, est, wbf, dcn_b, out);
}